// Round 12
// baseline (130.356 us; speedup 1.0000x reference)
//
#include <hip/hip_runtime.h>
#include <math.h>

#define EPSV 1e-6f
#define NSL  0.2f
#define BB   2
#define NN   2048
#define HH   8
#define TBP  16   // tokens per block in pre/out kernels (256 threads)

typedef short bf16x8 __attribute__((ext_vector_type(8)));
typedef float f32x4  __attribute__((ext_vector_type(4)));

__device__ __forceinline__ unsigned short f2bf(float x) {
  union { float f; unsigned int u; } v; v.f = x;
  unsigned int r = v.u + 0x7FFF + ((v.u >> 16) & 1);
  return (unsigned short)(r >> 16);
}
__device__ __forceinline__ float bf2f(unsigned short h) {
  union { float f; unsigned int u; } v; v.u = ((unsigned int)h) << 16;
  return v.f;
}
__device__ __forceinline__ unsigned cvt_pk_bf16(float a, float b) {
  unsigned r;
  asm("v_cvt_pk_bf16_f32 %0, %1, %2" : "=v"(r) : "v"(a), "v"(b));
  return r;
}
__device__ __forceinline__ float dot4(float4 x, const float* w) {
  return x.x * w[0] + x.y * w[1] + x.z * w[2] + x.w * w[3];
}
__device__ __forceinline__ float leaky(float a) { return a > 0.f ? a : NSL * a; }

// Workspace fragment layouts (bf16 hi/lo planes):
// QW/KW per (hb, tile16): [hl 2][768]: c0=[lane64][8] @0, c1=[lane<32][8] @512
// VW per (hb, kc32, f):   [hl 2][512]: [lane64][8]

// ---------------------------------------------------------------------------
// pre: merged q/kv (blockIdx.y: 0=q, 1=kv). 16 tokens / 256 threads.
// Thread = 4 channels (c0+32k) x 2 tokens (grp*2, grp*2+1): each 16-load
// weight batch feeds 96-192 FMA cycles -> L2 latency hidden by compute.
// Q scaled by 0.25*log2(e): softmax runs in exp2 domain.
// ---------------------------------------------------------------------------
__global__ __launch_bounds__(256) void pre_kernel(
    const float* __restrict__ qfts, const float* __restrict__ kvfts,
    const float* __restrict__ wq_in, const float* __restrict__ qw1, const float* __restrict__ qb1,
    const float* __restrict__ qw2, const float* __restrict__ qb2,
    const float* __restrict__ wkv_in, const float* __restrict__ kw1, const float* __restrict__ kb1,
    const float* __restrict__ kw2, const float* __restrict__ kb2,
    const float* __restrict__ w_q, const float* __restrict__ w_k, const float* __restrict__ w_v,
    unsigned short* __restrict__ QW, unsigned short* __restrict__ KW, unsigned short* __restrict__ VW)
{
  const bool is_kv = blockIdx.y != 0;
  const float* x_in = is_kv ? kvfts : qfts;
  const float* w_in = is_kv ? wkv_in : wq_in;
  const float* w1   = is_kv ? kw1 : qw1;
  const float* b1   = is_kv ? kb1 : qb1;
  const float* w2   = is_kv ? kw2 : qw2;
  const float* b2   = is_kv ? kb2 : qb2;
  const float* w_p  = is_kv ? w_k : w_q;
  unsigned short* FW = is_kv ? KW : QW;
  const float ln_sc = is_kv ? 1.f : 0.25f * 1.44269504088896f;

  const int t0 = blockIdx.x * TBP;
  const int tid = threadIdx.x;
  const int grp = tid >> 5;            // 0..7: tokens t0+2grp, t0+2grp+1
  const int c0  = tid & 31;            // base channel; owns c0+32k, k=0..3

  __shared__ float xs[TBP][192];
  __shared__ float norm_s[TBP][128];
  __shared__ float h_s[TBP][64];
  __shared__ float f_s[TBP][3][128];

  {
    const float4* src = (const float4*)(x_in + (size_t)t0 * 192);
    float4* dst = (float4*)&xs[0][0];
    dst[tid] = src[tid];
    dst[tid + 256] = src[tid + 256];
    dst[tid + 512] = src[tid + 512];
  }
  __syncthreads();

  // ---- phase 1: input GEMM (K=64) -> p[t][f][k] ----
  float p[2][3][4] = {{{0.f}}};
  #pragma unroll 2
  for (int c = 0; c < 64; c += 4) {
    float w4[4][4];
    #pragma unroll
    for (int i = 0; i < 4; ++i)
      #pragma unroll
      for (int k = 0; k < 4; ++k)
        w4[i][k] = w_in[(c + i) * 128 + c0 + k * 32];
    #pragma unroll
    for (int t = 0; t < 2; ++t)
      #pragma unroll
      for (int f = 0; f < 3; ++f) {
        float4 xv = *(const float4*)&xs[grp * 2 + t][f * 64 + c];
        #pragma unroll
        for (int k = 0; k < 4; ++k)
          p[t][f][k] += xv.x * w4[0][k] + xv.y * w4[1][k] + xv.z * w4[2][k] + xv.w * w4[3][k];
      }
  }

  // ---- phase 2: norms ----
  float np[2][4]; int zm = 0;
  #pragma unroll
  for (int t = 0; t < 2; ++t)
    #pragma unroll
    for (int k = 0; k < 4; ++k) {
      float nn = sqrtf(p[t][0][k] * p[t][0][k] + p[t][1][k] * p[t][1][k] + p[t][2][k] * p[t][2][k]);
      if (nn <= EPSV) zm |= 1 << (t * 4 + k);
      np[t][k] = nn + EPSV;
      norm_s[grp * 2 + t][c0 + k * 32] = np[t][k];
    }
  __syncthreads();

  // ---- phase 3: MLP1 (128->64) ----
  {
    float a[2][2];
    float ba = b1[c0], bb = b1[c0 + 32];
    a[0][0] = ba; a[1][0] = ba; a[0][1] = bb; a[1][1] = bb;
    #pragma unroll 2
    for (int c = 0; c < 128; c += 4) {
      float wa[4], wb[4];
      #pragma unroll
      for (int i = 0; i < 4; ++i) {
        wa[i] = w1[(c + i) * 64 + c0];
        wb[i] = w1[(c + i) * 64 + c0 + 32];
      }
      #pragma unroll
      for (int t = 0; t < 2; ++t) {
        float4 n4 = *(const float4*)&norm_s[grp * 2 + t][c];
        a[t][0] += dot4(n4, wa);
        a[t][1] += dot4(n4, wb);
      }
    }
    #pragma unroll
    for (int t = 0; t < 2; ++t) {
      h_s[grp * 2 + t][c0]      = leaky(a[t][0]);
      h_s[grp * 2 + t][c0 + 32] = leaky(a[t][1]);
    }
  }
  __syncthreads();

  // ---- phase 4: MLP2 (64->128) -> bn[t][k] ----
  float bn[2][4];
  #pragma unroll
  for (int t = 0; t < 2; ++t)
    #pragma unroll
    for (int k = 0; k < 4; ++k) bn[t][k] = b2[c0 + k * 32] + np[t][k];
  #pragma unroll 2
  for (int c = 0; c < 64; c += 4) {
    float w4[4][4];
    #pragma unroll
    for (int i = 0; i < 4; ++i)
      #pragma unroll
      for (int k = 0; k < 4; ++k)
        w4[i][k] = w2[(c + i) * 128 + c0 + k * 32];
    #pragma unroll
    for (int t = 0; t < 2; ++t) {
      float4 h4 = *(const float4*)&h_s[grp * 2 + t][c];
      #pragma unroll
      for (int k = 0; k < 4; ++k)
        bn[t][k] += h4.x * w4[0][k] + h4.y * w4[1][k] + h4.z * w4[2][k] + h4.w * w4[3][k];
    }
  }

  // ---- phase 5: ratio; write f to LDS ----
  #pragma unroll
  for (int t = 0; t < 2; ++t)
    #pragma unroll
    for (int k = 0; k < 4; ++k) {
      float r = (zm >> (t * 4 + k)) & 1 ? 1.f : bn[t][k] / np[t][k];
      #pragma unroll
      for (int f = 0; f < 3; ++f)
        f_s[grp * 2 + t][f][c0 + k * 32] = p[t][f][k] * r;
    }
  __syncthreads();

  // ---- phase 6: projections (K=128) ----
  float q[2][3][4] = {{{0.f}}};
  float v[2][3][4] = {{{0.f}}};
  #pragma unroll 1
  for (int c = 0; c < 128; c += 4) {
    float wk[4][4], wv[4][4];
    #pragma unroll
    for (int i = 0; i < 4; ++i)
      #pragma unroll
      for (int k = 0; k < 4; ++k) {
        wk[i][k] = w_p[(c + i) * 128 + c0 + k * 32];
        if (is_kv) wv[i][k] = w_v[(c + i) * 128 + c0 + k * 32];
      }
    #pragma unroll
    for (int t = 0; t < 2; ++t)
      #pragma unroll
      for (int f = 0; f < 3; ++f) {
        float4 fv = *(const float4*)&f_s[grp * 2 + t][f][c];
        #pragma unroll
        for (int k = 0; k < 4; ++k) {
          q[t][f][k] += fv.x * wk[0][k] + fv.y * wk[1][k] + fv.z * wk[2][k] + fv.w * wk[3][k];
          if (is_kv)
            v[t][f][k] += fv.x * wv[0][k] + fv.y * wv[1][k] + fv.z * wv[2][k] + fv.w * wv[3][k];
        }
      }
  }

  // ---- phase 7: EV layernorm (q/k) + fragment writes ----
  #pragma unroll
  for (int t = 0; t < 2; ++t) {
    const int tok = t0 + grp * 2 + t;
    const int b = tok >> 11, n = tok & (NN - 1);
    const int row = n & 15;
    #pragma unroll
    for (int k = 0; k < 4; ++k) {
      float ss = q[t][0][k] * q[t][0][k] + q[t][1][k] * q[t][1][k] + q[t][2][k] * q[t][2][k];
      ss += __shfl_xor(ss, 1, 16);
      ss += __shfl_xor(ss, 2, 16);
      ss += __shfl_xor(ss, 4, 16);
      ss += __shfl_xor(ss, 8, 16);
      float inv = ln_sc / (sqrtf(ss * (1.f / 16.f)) + EPSV);
      const int ch = c0 + k * 32;
      const int hh = ch >> 4, dd = ch & 15;
      const int hb = hh * BB + b;
      const size_t base = (size_t)(hb * 128 + (n >> 4)) * 1536;
      #pragma unroll
      for (int f = 0; f < 3; ++f) {
        float val = q[t][f][k] * inv;
        int d = f * 16 + dd;
        int off;
        if (d < 32) off = ((d >> 3) * 16 + row) * 8 + (d & 7);
        else        off = 512 + (((d - 32) >> 3) * 16 + row) * 8 + ((d - 32) & 7);
        unsigned short hi = f2bf(val);
        FW[base + off] = hi;
        FW[base + 768 + off] = f2bf(val - bf2f(hi));
      }
      if (is_kv) {
        const int voff = (((n & 31) >> 3) * 16 + dd) * 8 + (n & 7);
        #pragma unroll
        for (int f = 0; f < 3; ++f) {
          const size_t vbase = (size_t)((hb * 64 + (n >> 5)) * 3 + f) * 1024;
          unsigned short hi = f2bf(v[t][f][k]);
          VW[vbase + voff] = hi;
          VW[vbase + 512 + voff] = f2bf(v[t][f][k] - bf2f(hi));
        }
      }
    }
  }
}

// ---------------------------------------------------------------------------
// attention: MFMA flash, 4-way K-split, 32 q per wave (measured-good r7/r10).
// ---------------------------------------------------------------------------
#define THR 10.0f

__global__ __launch_bounds__(512, 4) void attn_kernel(
    const unsigned short* __restrict__ QW, const unsigned short* __restrict__ KW,
    const unsigned short* __restrict__ VW, float* __restrict__ Ob)
{
  const int lane = threadIdx.x & 63;
  const int w = threadIdx.x >> 6;
  const int qt = w & 1;
  const int kq = w >> 1;
  const int hb = blockIdx.y;
  const int tA = blockIdx.x * 4 + qt * 2;
  const int q = lane & 15, g = lane >> 4;

  __shared__ unsigned short plds[8][2][1152];
  float* comb = (float*)plds;

  bf16x8 qh0[2], ql0[2], qh1[2], ql1[2];
  #pragma unroll
  for (int qs = 0; qs < 2; ++qs) {
    const size_t qbase = (size_t)(hb * 128 + tA + qs) * 1536;
    qh0[qs] = *(const bf16x8*)(QW + qbase + lane * 8);
    ql0[qs] = *(const bf16x8*)(QW + qbase + 768 + lane * 8);
    qh1[qs] = (bf16x8){0,0,0,0,0,0,0,0};
    ql1[qs] = (bf16x8){0,0,0,0,0,0,0,0};
    if (lane < 32) {
      qh1[qs] = *(const bf16x8*)(QW + qbase + 512 + lane * 8);
      ql1[qs] = *(const bf16x8*)(QW + qbase + 768 + 512 + lane * 8);
    }
  }

  f32x4 o[2][3];
  #pragma unroll
  for (int qs = 0; qs < 2; ++qs)
    #pragma unroll
    for (int f = 0; f < 3; ++f) o[qs][f] = (f32x4){0.f, 0.f, 0.f, 0.f};
  float m[2] = {-INFINITY, -INFINITY}, l[2] = {0.f, 0.f};

  for (int T = kq * 8; T < kq * 8 + 8; ++T) {
    f32x4 sc[2][4];
    __builtin_amdgcn_s_setprio(1);
    #pragma unroll
    for (int st = 0; st < 4; ++st) {
      const size_t kb = (size_t)(hb * 128 + T * 4 + st) * 1536;
      bf16x8 kh0 = *(const bf16x8*)(KW + kb + lane * 8);
      bf16x8 kl0 = *(const bf16x8*)(KW + kb + 768 + lane * 8);
      bf16x8 kh1 = *(const bf16x8*)(KW + kb + 512 + lane * 8);
      bf16x8 kl1 = *(const bf16x8*)(KW + kb + 768 + 512 + lane * 8);
      #pragma unroll
      for (int qs = 0; qs < 2; ++qs) {
        f32x4 a = {0.f, 0.f, 0.f, 0.f};
        a = __builtin_amdgcn_mfma_f32_16x16x32_bf16(kh0, qh0[qs], a, 0, 0, 0);
        a = __builtin_amdgcn_mfma_f32_16x16x32_bf16(kh0, ql0[qs], a, 0, 0, 0);
        a = __builtin_amdgcn_mfma_f32_16x16x32_bf16(kl0, qh0[qs], a, 0, 0, 0);
        a = __builtin_amdgcn_mfma_f32_16x16x32_bf16(kh1, qh1[qs], a, 0, 0, 0);
        a = __builtin_amdgcn_mfma_f32_16x16x32_bf16(kh1, ql1[qs], a, 0, 0, 0);
        a = __builtin_amdgcn_mfma_f32_16x16x32_bf16(kl1, qh1[qs], a, 0, 0, 0);
        sc[qs][st] = a;
      }
    }
    __builtin_amdgcn_s_setprio(0);

    #pragma unroll
    for (int qs = 0; qs < 2; ++qs) {
      float tm = sc[qs][0][0];
      #pragma unroll
      for (int st = 0; st < 4; ++st)
        #pragma unroll
        for (int r = 0; r < 4; ++r) tm = fmaxf(tm, sc[qs][st][r]);
      tm = fmaxf(tm, __shfl_xor(tm, 16));
      tm = fmaxf(tm, __shfl_xor(tm, 32));
      if (__any(tm > m[qs] + THR)) {
        float mnew = fmaxf(m[qs], tm);
        float scl = __builtin_amdgcn_exp2f(m[qs] - mnew);
        l[qs] *= scl;
        #pragma unroll
        for (int f = 0; f < 3; ++f) {
          o[qs][f][0] *= scl; o[qs][f][1] *= scl;
          o[qs][f][2] *= scl; o[qs][f][3] *= scl;
        }
        m[qs] = mnew;
      }
      float lp = 0.f;
      #pragma unroll
      for (int st = 0; st < 4; ++st) {
        float p0 = __builtin_amdgcn_exp2f(sc[qs][st][0] - m[qs]);
        float p1 = __builtin_amdgcn_exp2f(sc[qs][st][1] - m[qs]);
        float p2 = __builtin_amdgcn_exp2f(sc[qs][st][2] - m[qs]);
        float p3 = __builtin_amdgcn_exp2f(sc[qs][st][3] - m[qs]);
        lp += (p0 + p1) + (p2 + p3);
        uint2 uh = {cvt_pk_bf16(p0, p1), cvt_pk_bf16(p2, p3)};
        *(uint2*)&plds[w][qs][q * 72 + st * 16 + g * 4] = uh;
      }
      lp += __shfl_xor(lp, 16);
      lp += __shfl_xor(lp, 32);
      l[qs] += lp;
    }

    asm volatile("s_waitcnt lgkmcnt(0)" ::: "memory");

    __builtin_amdgcn_s_setprio(1);
    #pragma unroll
    for (int c = 0; c < 2; ++c) {
      const int kc = T * 2 + c;
      bf16x8 pb[2];
      #pragma unroll
      for (int qs = 0; qs < 2; ++qs)
        pb[qs] = *(const bf16x8*)&plds[w][qs][q * 72 + c * 32 + g * 8];
      #pragma unroll
      for (int f = 0; f < 3; ++f) {
        const size_t vb = (size_t)((hb * 64 + kc) * 3 + f) * 1024;
        bf16x8 vh = *(const bf16x8*)(VW + vb + lane * 8);
        bf16x8 vl = *(const bf16x8*)(VW + vb + 512 + lane * 8);
        #pragma unroll
        for (int qs = 0; qs < 2; ++qs) {
          o[qs][f] = __builtin_amdgcn_mfma_f32_16x16x32_bf16(vh, pb[qs], o[qs][f], 0, 0, 0);
          o[qs][f] = __builtin_amdgcn_mfma_f32_16x16x32_bf16(vl, pb[qs], o[qs][f], 0, 0, 0);
        }
      }
    }
    __builtin_amdgcn_s_setprio(0);
  }

  #define SLOT(qt_, qs_, r_) (comb + ((((qt_) * 2 + (qs_)) * 2 + (r_)) * 64 + lane) * 14)
  __syncthreads();
  if (kq & 1) {
    #pragma unroll
    for (int qs = 0; qs < 2; ++qs) {
      float* cb = SLOT(qt, qs, kq >> 1);
      #pragma unroll
      for (int f = 0; f < 3; ++f)
        #pragma unroll
        for (int r = 0; r < 4; ++r) cb[f * 4 + r] = o[qs][f][r];
      cb[12] = m[qs]; cb[13] = l[qs];
    }
  }
  __syncthreads();
  if (!(kq & 1)) {
    #pragma unroll
    for (int qs = 0; qs < 2; ++qs) {
      const float* cb = SLOT(qt, qs, kq >> 1);
      float m1 = cb[12], l1 = cb[13];
      float mn = fmaxf(m[qs], m1);
      float s0 = __builtin_amdgcn_exp2f(m[qs] - mn);
      float s1 = __builtin_amdgcn_exp2f(m1 - mn);
      l[qs] = l[qs] * s0 + l1 * s1;
      #pragma unroll
      for (int f = 0; f < 3; ++f)
        #pragma unroll
        for (int r = 0; r < 4; ++r)
          o[qs][f][r] = o[qs][f][r] * s0 + cb[f * 4 + r] * s1;
      m[qs] = mn;
    }
  }
  __syncthreads();
  if (kq == 2) {
    #pragma unroll
    for (int qs = 0; qs < 2; ++qs) {
      float* cb = SLOT(qt, qs, 1);
      #pragma unroll
      for (int f = 0; f < 3; ++f)
        #pragma unroll
        for (int r = 0; r < 4; ++r) cb[f * 4 + r] = o[qs][f][r];
      cb[12] = m[qs]; cb[13] = l[qs];
    }
  }
  __syncthreads();
  if (kq == 0) {
    const int h_ = hb >> 1, b_ = hb & 1;
    #pragma unroll
    for (int qs = 0; qs < 2; ++qs) {
      const float* cb = SLOT(qt, qs, 1);
      float m1 = cb[12], l1 = cb[13];
      float mn = fmaxf(m[qs], m1);
      float s0 = __builtin_amdgcn_exp2f(m[qs] - mn);
      float s1 = __builtin_amdgcn_exp2f(m1 - mn);
      float invl = 1.f / (l[qs] * s0 + l1 * s1);
      const int n = (tA + qs) * 16 + q;
      #pragma unroll
      for (int f = 0; f < 3; ++f) {
        float4 st4 = {(o[qs][f][0] * s0 + cb[f * 4 + 0] * s1) * invl,
                      (o[qs][f][1] * s0 + cb[f * 4 + 1] * s1) * invl,
                      (o[qs][f][2] * s0 + cb[f * 4 + 2] * s1) * invl,
                      (o[qs][f][3] * s0 + cb[f * 4 + 3] * s1) * invl};
        *(float4*)&Ob[(((size_t)(b_ * NN + n)) * 3 + f) * 128 + h_ * 16 + g * 4] = st4;
      }
    }
  }
  #undef SLOT
}

// ---------------------------------------------------------------------------
// out: ev_nonlin(resi @ w_out). Thread = 4 ch x 2 tok; 16 tok / 256 threads.
// ---------------------------------------------------------------------------
__global__ __launch_bounds__(256) void out_kernel(
    const float* __restrict__ Ob, const float* __restrict__ w_out,
    const float* __restrict__ w1, const float* __restrict__ b1,
    const float* __restrict__ w2, const float* __restrict__ b2,
    float* __restrict__ out)
{
  const int t0 = blockIdx.x * TBP;
  const int tid = threadIdx.x;
  const int grp = tid >> 5;
  const int c0  = tid & 31;

  __shared__ float rs[TBP][384];
  __shared__ float norm_s[TBP][128];
  __shared__ float h_s[TBP][64];

  {
    const float4* src = (const float4*)(Ob + (size_t)t0 * 384);
    float4* dst = (float4*)&rs[0][0];
    #pragma unroll
    for (int i = 0; i < 6; ++i) dst[tid + i * 256] = src[tid + i * 256];
  }
  __syncthreads();

  // proj (K=128)
  float p[2][3][4] = {{{0.f}}};
  #pragma unroll 2
  for (int c = 0; c < 128; c += 4) {
    float w4[4][4];
    #pragma unroll
    for (int i = 0; i < 4; ++i)
      #pragma unroll
      for (int k = 0; k < 4; ++k)
        w4[i][k] = w_out[(c + i) * 128 + c0 + k * 32];
    #pragma unroll
    for (int t = 0; t < 2; ++t)
      #pragma unroll
      for (int f = 0; f < 3; ++f) {
        float4 rv = *(const float4*)&rs[grp * 2 + t][f * 128 + c];
        #pragma unroll
        for (int k = 0; k < 4; ++k)
          p[t][f][k] += rv.x * w4[0][k] + rv.y * w4[1][k] + rv.z * w4[2][k] + rv.w * w4[3][k];
      }
  }

  float np[2][4]; int zm = 0;
  #pragma unroll
  for (int t = 0; t < 2; ++t)
    #pragma unroll
    for (int k = 0; k < 4; ++k) {
      float nn = sqrtf(p[t][0][k] * p[t][0][k] + p[t][1][k] * p[t][1][k] + p[t][2][k] * p[t][2][k]);
      if (nn <= EPSV) zm |= 1 << (t * 4 + k);
      np[t][k] = nn + EPSV;
      norm_s[grp * 2 + t][c0 + k * 32] = np[t][k];
    }
  __syncthreads();

  {
    float a[2][2];
    float ba = b1[c0], bb = b1[c0 + 32];
    a[0][0] = ba; a[1][0] = ba; a[0][1] = bb; a[1][1] = bb;
    #pragma unroll 2
    for (int c = 0; c < 128; c += 4) {
      float wa[4], wb[4];
      #pragma unroll
      for (int i = 0; i < 4; ++i) {
        wa[i] = w1[(c + i) * 64 + c0];
        wb[i] = w1[(c + i) * 64 + c0 + 32];
      }
      #pragma unroll
      for (int t = 0; t < 2; ++t) {
        float4 n4 = *(const float4*)&norm_s[grp * 2 + t][c];
        a[t][0] += dot4(n4, wa);
        a[t][1] += dot4(n4, wb);
      }
    }
    #pragma unroll
    for (int t = 0; t < 2; ++t) {
      h_s[grp * 2 + t][c0]      = leaky(a[t][0]);
      h_s[grp * 2 + t][c0 + 32] = leaky(a[t][1]);
    }
  }
  __syncthreads();

  float bn[2][4];
  #pragma unroll
  for (int t = 0; t < 2; ++t)
    #pragma unroll
    for (int k = 0; k < 4; ++k) bn[t][k] = b2[c0 + k * 32] + np[t][k];
  #pragma unroll 2
  for (int c = 0; c < 64; c += 4) {
    float w4[4][4];
    #pragma unroll
    for (int i = 0; i < 4; ++i)
      #pragma unroll
      for (int k = 0; k < 4; ++k)
        w4[i][k] = w2[(c + i) * 128 + c0 + k * 32];
    #pragma unroll
    for (int t = 0; t < 2; ++t) {
      float4 h4 = *(const float4*)&h_s[grp * 2 + t][c];
      #pragma unroll
      for (int k = 0; k < 4; ++k)
        bn[t][k] += h4.x * w4[0][k] + h4.y * w4[1][k] + h4.z * w4[2][k] + h4.w * w4[3][k];
    }
  }

  #pragma unroll
  for (int t = 0; t < 2; ++t) {
    float* od = out + (size_t)(t0 + grp * 2 + t) * 384;
    #pragma unroll
    for (int k = 0; k < 4; ++k) {
      float r = (zm >> (t * 4 + k)) & 1 ? 1.f : bn[t][k] / np[t][k];
      #pragma unroll
      for (int f = 0; f < 3; ++f)
        od[f * 128 + c0 + k * 32] = p[t][f][k] * r;
    }
  }
}

// ---------------------------------------------------------------------------
extern "C" void kernel_launch(void* const* d_in, const int* in_sizes, int n_in,
                              void* d_out, int out_size, void* d_ws, size_t ws_size,
                              hipStream_t stream) {
  const float* qfts   = (const float*)d_in[0];
  const float* kvfts  = (const float*)d_in[1];
  const float* w_q_in = (const float*)d_in[2];
  const float* q_w1   = (const float*)d_in[3];
  const float* q_b1   = (const float*)d_in[4];
  const float* q_w2   = (const float*)d_in[5];
  const float* q_b2   = (const float*)d_in[6];
  const float* w_kv_in= (const float*)d_in[7];
  const float* kv_w1  = (const float*)d_in[8];
  const float* kv_b1  = (const float*)d_in[9];
  const float* kv_w2  = (const float*)d_in[10];
  const float* kv_b2  = (const float*)d_in[11];
  const float* w_q    = (const float*)d_in[12];
  const float* w_k    = (const float*)d_in[13];
  const float* w_v    = (const float*)d_in[14];
  const float* w_out  = (const float*)d_in[15];
  const float* o_w1   = (const float*)d_in[16];
  const float* o_b1   = (const float*)d_in[17];
  const float* o_w2   = (const float*)d_in[18];
  const float* o_b2   = (const float*)d_in[19];

  unsigned short* QW = (unsigned short*)d_ws;
  unsigned short* KW = QW + 3145728;
  unsigned short* VW = KW + 3145728;
  float* Obuf = (float*)(VW + 3145728);

  dim3 pg(BB * NN / TBP, 2);
  pre_kernel<<<pg, 256, 0, stream>>>(qfts, kvfts,
                                     w_q_in, q_w1, q_b1, q_w2, q_b2,
                                     w_kv_in, kv_w1, kv_b1, kv_w2, kv_b2,
                                     w_q, w_k, w_v, QW, KW, VW);
  dim3 ag(32, 16);
  attn_kernel<<<ag, 512, 0, stream>>>(QW, KW, VW, Obuf);
  out_kernel<<<BB * NN / TBP, 256, 0, stream>>>(Obuf, w_out, o_w1, o_b1, o_w2, o_b2, (float*)d_out);
}

// Round 13
// 129.579 us; speedup vs baseline: 1.0060x; 1.0060x over previous
//
#include <hip/hip_runtime.h>
#include <math.h>

#define EPSV 1e-6f
#define NSL  0.2f
#define BB   2
#define NN   2048
#define HH   8
#define TBP  16   // tokens per block in pre/out kernels (256 threads)

typedef short bf16x8 __attribute__((ext_vector_type(8)));
typedef float f32x4  __attribute__((ext_vector_type(4)));

__device__ __forceinline__ unsigned short f2bf(float x) {
  union { float f; unsigned int u; } v; v.f = x;
  unsigned int r = v.u + 0x7FFF + ((v.u >> 16) & 1);
  return (unsigned short)(r >> 16);
}
__device__ __forceinline__ float bf2f(unsigned short h) {
  union { float f; unsigned int u; } v; v.u = ((unsigned int)h) << 16;
  return v.f;
}
__device__ __forceinline__ unsigned cvt_pk_bf16(float a, float b) {
  unsigned r;
  asm("v_cvt_pk_bf16_f32 %0, %1, %2" : "=v"(r) : "v"(a), "v"(b));
  return r;   // lo16 = bf16(a), hi16 = bf16(b), RNE
}
__device__ __forceinline__ float u2f(unsigned u) {
  union { unsigned u; float f; } v; v.u = u; return v.f;
}
__device__ __forceinline__ float dot4(float4 x, const float* w) {
  return x.x * w[0] + x.y * w[1] + x.z * w[2] + x.w * w[3];
}
__device__ __forceinline__ float leaky(float a) { return a > 0.f ? a : NSL * a; }

// pack 8 f32 -> hi uint4 and lo uint4 (hi = bf16(v), lo = bf16(v - bf2f(hi)))
__device__ __forceinline__ void pack8(float4 a, float4 b, uint4& hi, uint4& lo) {
  hi.x = cvt_pk_bf16(a.x, a.y);
  hi.y = cvt_pk_bf16(a.z, a.w);
  hi.z = cvt_pk_bf16(b.x, b.y);
  hi.w = cvt_pk_bf16(b.z, b.w);
  float d0 = a.x - u2f(hi.x << 16), d1 = a.y - u2f(hi.x & 0xffff0000u);
  float d2 = a.z - u2f(hi.y << 16), d3 = a.w - u2f(hi.y & 0xffff0000u);
  float d4 = b.x - u2f(hi.z << 16), d5 = b.y - u2f(hi.z & 0xffff0000u);
  float d6 = b.z - u2f(hi.w << 16), d7 = b.w - u2f(hi.w & 0xffff0000u);
  lo.x = cvt_pk_bf16(d0, d1);
  lo.y = cvt_pk_bf16(d2, d3);
  lo.z = cvt_pk_bf16(d4, d5);
  lo.w = cvt_pk_bf16(d6, d7);
}

// Workspace fragment layouts (bf16 hi/lo planes):
// QW/KW per (hb, tile16): [hl 2][768]: c0=[lane64][8] @0, c1=[lane<32][8] @512
// VW per (hb, kc32, f):   [hl 2][512]: [lane64][8]

// ---------------------------------------------------------------------------
// pre: merged q/kv (blockIdx.y: 0=q, 1=kv). 16 tokens / 256 threads (4 waves).
// Compute: thread = 4 channels (c0+32k) x 2 tokens.  Epilogue: results staged
// in LDS, then wave-cooperative COALESCED b128 fragment stores (cvt_pk pack).
// Q scaled by 0.25*log2(e): softmax runs in exp2 domain.
// ---------------------------------------------------------------------------
__global__ __launch_bounds__(256) void pre_kernel(
    const float* __restrict__ qfts, const float* __restrict__ kvfts,
    const float* __restrict__ wq_in, const float* __restrict__ qw1, const float* __restrict__ qb1,
    const float* __restrict__ qw2, const float* __restrict__ qb2,
    const float* __restrict__ wkv_in, const float* __restrict__ kw1, const float* __restrict__ kb1,
    const float* __restrict__ kw2, const float* __restrict__ kb2,
    const float* __restrict__ w_q, const float* __restrict__ w_k, const float* __restrict__ w_v,
    unsigned short* __restrict__ QW, unsigned short* __restrict__ KW, unsigned short* __restrict__ VW)
{
  const bool is_kv = blockIdx.y != 0;
  const float* x_in = is_kv ? kvfts : qfts;
  const float* w_in = is_kv ? wkv_in : wq_in;
  const float* w1   = is_kv ? kw1 : qw1;
  const float* b1   = is_kv ? kb1 : qb1;
  const float* w2   = is_kv ? kw2 : qw2;
  const float* b2   = is_kv ? kb2 : qb2;
  const float* w_p  = is_kv ? w_k : w_q;
  unsigned short* FW = is_kv ? KW : QW;
  const float ln_sc = is_kv ? 1.f : 0.25f * 1.44269504088896f;

  const int t0 = blockIdx.x * TBP;
  const int tid = threadIdx.x;
  const int grp = tid >> 5;            // 0..7: tokens t0+2grp, t0+2grp+1
  const int c0  = tid & 31;            // base channel; owns c0+32k, k=0..3
  const int n0  = t0 & (NN - 1);
  const int bsel = t0 >> 11;

  // smem layout: xs[12288] | norm[8192] | h[4096] | fs[24576]  = 49152 B
  // stage region (epilogue) overlays h+fs @ offset 20480, 28672 B:
  //   stage_q: idx(tl,f,ch) = tl*388 + f*128 + ch          (24832 B)
  //   stage_v: idx(f,tl,ch) = f*2112 + tl*132 + ch         (25344 B)
  __shared__ __align__(16) char smem[49152];
  float (*xs)[192]       = (float(*)[192])smem;
  float (*norm_s)[128]   = (float(*)[128])(smem + 12288);
  float (*h_s)[64]       = (float(*)[64])(smem + 20480);
  float (*f_s)[3][128]   = (float(*)[3][128])(smem + 24576);
  float* stage           = (float*)(smem + 20480);

  {
    const float4* src = (const float4*)(x_in + (size_t)t0 * 192);
    float4* dst = (float4*)&xs[0][0];
    dst[tid] = src[tid];
    dst[tid + 256] = src[tid + 256];
    dst[tid + 512] = src[tid + 512];
  }
  __syncthreads();

  // ---- phase 1: input GEMM (K=64) -> p[t][f][k] ----
  float p[2][3][4] = {{{0.f}}};
  #pragma unroll 2
  for (int c = 0; c < 64; c += 4) {
    float w4[4][4];
    #pragma unroll
    for (int i = 0; i < 4; ++i)
      #pragma unroll
      for (int k = 0; k < 4; ++k)
        w4[i][k] = w_in[(c + i) * 128 + c0 + k * 32];
    #pragma unroll
    for (int t = 0; t < 2; ++t)
      #pragma unroll
      for (int f = 0; f < 3; ++f) {
        float4 xv = *(const float4*)&xs[grp * 2 + t][f * 64 + c];
        #pragma unroll
        for (int k = 0; k < 4; ++k)
          p[t][f][k] += xv.x * w4[0][k] + xv.y * w4[1][k] + xv.z * w4[2][k] + xv.w * w4[3][k];
      }
  }

  // ---- phase 2: norms ----
  float np[2][4]; int zm = 0;
  #pragma unroll
  for (int t = 0; t < 2; ++t)
    #pragma unroll
    for (int k = 0; k < 4; ++k) {
      float nn = sqrtf(p[t][0][k] * p[t][0][k] + p[t][1][k] * p[t][1][k] + p[t][2][k] * p[t][2][k]);
      if (nn <= EPSV) zm |= 1 << (t * 4 + k);
      np[t][k] = nn + EPSV;
      norm_s[grp * 2 + t][c0 + k * 32] = np[t][k];
    }
  __syncthreads();

  // ---- phase 3: MLP1 (128->64) ----
  {
    float a[2][2];
    float ba = b1[c0], bb = b1[c0 + 32];
    a[0][0] = ba; a[1][0] = ba; a[0][1] = bb; a[1][1] = bb;
    #pragma unroll 2
    for (int c = 0; c < 128; c += 4) {
      float wa[4], wb[4];
      #pragma unroll
      for (int i = 0; i < 4; ++i) {
        wa[i] = w1[(c + i) * 64 + c0];
        wb[i] = w1[(c + i) * 64 + c0 + 32];
      }
      #pragma unroll
      for (int t = 0; t < 2; ++t) {
        float4 n4 = *(const float4*)&norm_s[grp * 2 + t][c];
        a[t][0] += dot4(n4, wa);
        a[t][1] += dot4(n4, wb);
      }
    }
    #pragma unroll
    for (int t = 0; t < 2; ++t) {
      h_s[grp * 2 + t][c0]      = leaky(a[t][0]);
      h_s[grp * 2 + t][c0 + 32] = leaky(a[t][1]);
    }
  }
  __syncthreads();

  // ---- phase 4: MLP2 (64->128) -> bn[t][k] ----
  float bn[2][4];
  #pragma unroll
  for (int t = 0; t < 2; ++t)
    #pragma unroll
    for (int k = 0; k < 4; ++k) bn[t][k] = b2[c0 + k * 32] + np[t][k];
  #pragma unroll 2
  for (int c = 0; c < 64; c += 4) {
    float w4[4][4];
    #pragma unroll
    for (int i = 0; i < 4; ++i)
      #pragma unroll
      for (int k = 0; k < 4; ++k)
        w4[i][k] = w2[(c + i) * 128 + c0 + k * 32];
    #pragma unroll
    for (int t = 0; t < 2; ++t) {
      float4 h4 = *(const float4*)&h_s[grp * 2 + t][c];
      #pragma unroll
      for (int k = 0; k < 4; ++k)
        bn[t][k] += h4.x * w4[0][k] + h4.y * w4[1][k] + h4.z * w4[2][k] + h4.w * w4[3][k];
    }
  }

  // ---- phase 5: ratio; write f to LDS ----
  #pragma unroll
  for (int t = 0; t < 2; ++t)
    #pragma unroll
    for (int k = 0; k < 4; ++k) {
      float r = (zm >> (t * 4 + k)) & 1 ? 1.f : bn[t][k] / np[t][k];
      #pragma unroll
      for (int f = 0; f < 3; ++f)
        f_s[grp * 2 + t][f][c0 + k * 32] = p[t][f][k] * r;
    }
  __syncthreads();

  // ---- phase 6: projections (K=128) ----
  float q[2][3][4] = {{{0.f}}};
  float v[2][3][4] = {{{0.f}}};
  #pragma unroll 1
  for (int c = 0; c < 128; c += 4) {
    float wk[4][4], wv[4][4];
    #pragma unroll
    for (int i = 0; i < 4; ++i)
      #pragma unroll
      for (int k = 0; k < 4; ++k) {
        wk[i][k] = w_p[(c + i) * 128 + c0 + k * 32];
        if (is_kv) wv[i][k] = w_v[(c + i) * 128 + c0 + k * 32];
      }
    #pragma unroll
    for (int t = 0; t < 2; ++t)
      #pragma unroll
      for (int f = 0; f < 3; ++f) {
        float4 fv = *(const float4*)&f_s[grp * 2 + t][f][c];
        #pragma unroll
        for (int k = 0; k < 4; ++k) {
          q[t][f][k] += fv.x * wk[0][k] + fv.y * wk[1][k] + fv.z * wk[2][k] + fv.w * wk[3][k];
          if (is_kv)
            v[t][f][k] += fv.x * wv[0][k] + fv.y * wv[1][k] + fv.z * wv[2][k] + fv.w * wv[3][k];
        }
      }
  }
  __syncthreads();   // f_s reads done before stage overwrite

  // ---- phase 7a: EV layernorm; stage q*inv (f32) into LDS ----
  #pragma unroll
  for (int t = 0; t < 2; ++t) {
    const int tl = grp * 2 + t;
    #pragma unroll
    for (int k = 0; k < 4; ++k) {
      float ss = q[t][0][k] * q[t][0][k] + q[t][1][k] * q[t][1][k] + q[t][2][k] * q[t][2][k];
      ss += __shfl_xor(ss, 1, 16);
      ss += __shfl_xor(ss, 2, 16);
      ss += __shfl_xor(ss, 4, 16);
      ss += __shfl_xor(ss, 8, 16);
      float inv = ln_sc / (sqrtf(ss * (1.f / 16.f)) + EPSV);
      const int ch = c0 + k * 32;
      #pragma unroll
      for (int f = 0; f < 3; ++f)
        stage[tl * 388 + f * 128 + ch] = q[t][f][k] * inv;
    }
  }
  __syncthreads();

  // ---- phase 7b: wave-cooperative coalesced FW stores (2 head-tiles/wave) ----
  {
    const int wv = tid >> 6;
    const int lane = tid & 63;
    const int f0 = lane >> 5;                    // 0,1
    const int ddb = ((lane >> 4) & 1) * 8;       // 0,8
    const int row = lane & 15;
    #pragma unroll
    for (int h2 = 0; h2 < 2; ++h2) {
      const int hh = wv * 2 + h2;
      const int hbw = hh * BB + bsel;
      const size_t basew = (size_t)(hbw * 128 + (n0 >> 4)) * 1536;
      // c0 plane (all 64 lanes)
      {
        const float* p0 = stage + row * 388 + f0 * 128 + hh * 16 + ddb;
        float4 a = *(const float4*)p0;
        float4 b = *(const float4*)(p0 + 4);
        uint4 hi, lo;
        pack8(a, b, hi, lo);
        *(uint4*)(FW + basew + lane * 8) = hi;
        *(uint4*)(FW + basew + 768 + lane * 8) = lo;
      }
      // c1 plane (lanes < 32): f=2
      if (lane < 32) {
        const int ddb1 = ((lane >> 4) & 1) * 8;
        const float* p1 = stage + row * 388 + 2 * 128 + hh * 16 + ddb1;
        float4 a = *(const float4*)p1;
        float4 b = *(const float4*)(p1 + 4);
        uint4 hi, lo;
        pack8(a, b, hi, lo);
        *(uint4*)(FW + basew + 512 + lane * 8) = hi;
        *(uint4*)(FW + basew + 768 + 512 + lane * 8) = lo;
      }
    }
  }

  if (is_kv) {
    __syncthreads();   // FW stage reads done before stage_v overwrite

    // ---- phase 7c: stage v into LDS: idx = f*2112 + tl*132 + ch ----
    #pragma unroll
    for (int t = 0; t < 2; ++t) {
      const int tl = grp * 2 + t;
      #pragma unroll
      for (int f = 0; f < 3; ++f)
        #pragma unroll
        for (int k = 0; k < 4; ++k)
          stage[f * 2112 + tl * 132 + c0 + k * 32] = v[t][f][k];
    }
    __syncthreads();

    // ---- phase 7d: wave-cooperative coalesced VW stores ----
    const int wv = tid >> 6;
    const int lane = tid & 63;
    const int s0 = (n0 >> 3) & 3;   // (n0&31)>>3; 16-aligned -> {0,2}
    if (lane < 32) {
      const int seg = lane;
      const int tlb = (seg >> 4) * 8;
      const int dd = seg & 15;
      #pragma unroll
      for (int h2 = 0; h2 < 2; ++h2) {
        const int hh = wv * 2 + h2;
        const int hbw = hh * BB + bsel;
        #pragma unroll
        for (int f = 0; f < 3; ++f) {
          const size_t vbase = (size_t)((hbw * 64 + (n0 >> 5)) * 3 + f) * 1024;
          const float* pv = stage + f * 2112 + (size_t)0 + (tlb + 0) * 132 + hh * 16 + dd;
          float vals[8];
          #pragma unroll
          for (int j = 0; j < 8; ++j)
            vals[j] = stage[f * 2112 + (tlb + j) * 132 + hh * 16 + dd];
          (void)pv;
          float4 a = {vals[0], vals[1], vals[2], vals[3]};
          float4 b = {vals[4], vals[5], vals[6], vals[7]};
          uint4 hi, lo;
          pack8(a, b, hi, lo);
          *(uint4*)(VW + vbase + (size_t)(s0 * 16 + seg) * 8) = hi;
          *(uint4*)(VW + vbase + 512 + (size_t)(s0 * 16 + seg) * 8) = lo;
        }
      }
    }
  }
}

// ---------------------------------------------------------------------------
// attention: MFMA flash, 4-way K-split, 32 q per wave (measured-good r7/r10).
// ---------------------------------------------------------------------------
#define THR 10.0f

__global__ __launch_bounds__(512, 4) void attn_kernel(
    const unsigned short* __restrict__ QW, const unsigned short* __restrict__ KW,
    const unsigned short* __restrict__ VW, float* __restrict__ Ob)
{
  const int lane = threadIdx.x & 63;
  const int w = threadIdx.x >> 6;
  const int qt = w & 1;
  const int kq = w >> 1;
  const int hb = blockIdx.y;
  const int tA = blockIdx.x * 4 + qt * 2;
  const int q = lane & 15, g = lane >> 4;

  __shared__ unsigned short plds[8][2][1152];
  float* comb = (float*)plds;

  bf16x8 qh0[2], ql0[2], qh1[2], ql1[2];
  #pragma unroll
  for (int qs = 0; qs < 2; ++qs) {
    const size_t qbase = (size_t)(hb * 128 + tA + qs) * 1536;
    qh0[qs] = *(const bf16x8*)(QW + qbase + lane * 8);
    ql0[qs] = *(const bf16x8*)(QW + qbase + 768 + lane * 8);
    qh1[qs] = (bf16x8){0,0,0,0,0,0,0,0};
    ql1[qs] = (bf16x8){0,0,0,0,0,0,0,0};
    if (lane < 32) {
      qh1[qs] = *(const bf16x8*)(QW + qbase + 512 + lane * 8);
      ql1[qs] = *(const bf16x8*)(QW + qbase + 768 + 512 + lane * 8);
    }
  }

  f32x4 o[2][3];
  #pragma unroll
  for (int qs = 0; qs < 2; ++qs)
    #pragma unroll
    for (int f = 0; f < 3; ++f) o[qs][f] = (f32x4){0.f, 0.f, 0.f, 0.f};
  float m[2] = {-INFINITY, -INFINITY}, l[2] = {0.f, 0.f};

  for (int T = kq * 8; T < kq * 8 + 8; ++T) {
    f32x4 sc[2][4];
    __builtin_amdgcn_s_setprio(1);
    #pragma unroll
    for (int st = 0; st < 4; ++st) {
      const size_t kb = (size_t)(hb * 128 + T * 4 + st) * 1536;
      bf16x8 kh0 = *(const bf16x8*)(KW + kb + lane * 8);
      bf16x8 kl0 = *(const bf16x8*)(KW + kb + 768 + lane * 8);
      bf16x8 kh1 = *(const bf16x8*)(KW + kb + 512 + lane * 8);
      bf16x8 kl1 = *(const bf16x8*)(KW + kb + 768 + 512 + lane * 8);
      #pragma unroll
      for (int qs = 0; qs < 2; ++qs) {
        f32x4 a = {0.f, 0.f, 0.f, 0.f};
        a = __builtin_amdgcn_mfma_f32_16x16x32_bf16(kh0, qh0[qs], a, 0, 0, 0);
        a = __builtin_amdgcn_mfma_f32_16x16x32_bf16(kh0, ql0[qs], a, 0, 0, 0);
        a = __builtin_amdgcn_mfma_f32_16x16x32_bf16(kl0, qh0[qs], a, 0, 0, 0);
        a = __builtin_amdgcn_mfma_f32_16x16x32_bf16(kh1, qh1[qs], a, 0, 0, 0);
        a = __builtin_amdgcn_mfma_f32_16x16x32_bf16(kh1, ql1[qs], a, 0, 0, 0);
        a = __builtin_amdgcn_mfma_f32_16x16x32_bf16(kl1, qh1[qs], a, 0, 0, 0);
        sc[qs][st] = a;
      }
    }
    __builtin_amdgcn_s_setprio(0);

    #pragma unroll
    for (int qs = 0; qs < 2; ++qs) {
      float tm = sc[qs][0][0];
      #pragma unroll
      for (int st = 0; st < 4; ++st)
        #pragma unroll
        for (int r = 0; r < 4; ++r) tm = fmaxf(tm, sc[qs][st][r]);
      tm = fmaxf(tm, __shfl_xor(tm, 16));
      tm = fmaxf(tm, __shfl_xor(tm, 32));
      if (__any(tm > m[qs] + THR)) {
        float mnew = fmaxf(m[qs], tm);
        float scl = __builtin_amdgcn_exp2f(m[qs] - mnew);
        l[qs] *= scl;
        #pragma unroll
        for (int f = 0; f < 3; ++f) {
          o[qs][f][0] *= scl; o[qs][f][1] *= scl;
          o[qs][f][2] *= scl; o[qs][f][3] *= scl;
        }
        m[qs] = mnew;
      }
      float lp = 0.f;
      #pragma unroll
      for (int st = 0; st < 4; ++st) {
        float p0 = __builtin_amdgcn_exp2f(sc[qs][st][0] - m[qs]);
        float p1 = __builtin_amdgcn_exp2f(sc[qs][st][1] - m[qs]);
        float p2 = __builtin_amdgcn_exp2f(sc[qs][st][2] - m[qs]);
        float p3 = __builtin_amdgcn_exp2f(sc[qs][st][3] - m[qs]);
        lp += (p0 + p1) + (p2 + p3);
        uint2 uh = {cvt_pk_bf16(p0, p1), cvt_pk_bf16(p2, p3)};
        *(uint2*)&plds[w][qs][q * 72 + st * 16 + g * 4] = uh;
      }
      lp += __shfl_xor(lp, 16);
      lp += __shfl_xor(lp, 32);
      l[qs] += lp;
    }

    asm volatile("s_waitcnt lgkmcnt(0)" ::: "memory");

    __builtin_amdgcn_s_setprio(1);
    #pragma unroll
    for (int c = 0; c < 2; ++c) {
      const int kc = T * 2 + c;
      bf16x8 pb[2];
      #pragma unroll
      for (int qs = 0; qs < 2; ++qs)
        pb[qs] = *(const bf16x8*)&plds[w][qs][q * 72 + c * 32 + g * 8];
      #pragma unroll
      for (int f = 0; f < 3; ++f) {
        const size_t vb = (size_t)((hb * 64 + kc) * 3 + f) * 1024;
        bf16x8 vh = *(const bf16x8*)(VW + vb + lane * 8);
        bf16x8 vl = *(const bf16x8*)(VW + vb + 512 + lane * 8);
        #pragma unroll
        for (int qs = 0; qs < 2; ++qs) {
          o[qs][f] = __builtin_amdgcn_mfma_f32_16x16x32_bf16(vh, pb[qs], o[qs][f], 0, 0, 0);
          o[qs][f] = __builtin_amdgcn_mfma_f32_16x16x32_bf16(vl, pb[qs], o[qs][f], 0, 0, 0);
        }
      }
    }
    __builtin_amdgcn_s_setprio(0);
  }

  #define SLOT(qt_, qs_, r_) (comb + ((((qt_) * 2 + (qs_)) * 2 + (r_)) * 64 + lane) * 14)
  __syncthreads();
  if (kq & 1) {
    #pragma unroll
    for (int qs = 0; qs < 2; ++qs) {
      float* cb = SLOT(qt, qs, kq >> 1);
      #pragma unroll
      for (int f = 0; f < 3; ++f)
        #pragma unroll
        for (int r = 0; r < 4; ++r) cb[f * 4 + r] = o[qs][f][r];
      cb[12] = m[qs]; cb[13] = l[qs];
    }
  }
  __syncthreads();
  if (!(kq & 1)) {
    #pragma unroll
    for (int qs = 0; qs < 2; ++qs) {
      const float* cb = SLOT(qt, qs, kq >> 1);
      float m1 = cb[12], l1 = cb[13];
      float mn = fmaxf(m[qs], m1);
      float s0 = __builtin_amdgcn_exp2f(m[qs] - mn);
      float s1 = __builtin_amdgcn_exp2f(m1 - mn);
      l[qs] = l[qs] * s0 + l1 * s1;
      #pragma unroll
      for (int f = 0; f < 3; ++f)
        #pragma unroll
        for (int r = 0; r < 4; ++r)
          o[qs][f][r] = o[qs][f][r] * s0 + cb[f * 4 + r] * s1;
      m[qs] = mn;
    }
  }
  __syncthreads();
  if (kq == 2) {
    #pragma unroll
    for (int qs = 0; qs < 2; ++qs) {
      float* cb = SLOT(qt, qs, 1);
      #pragma unroll
      for (int f = 0; f < 3; ++f)
        #pragma unroll
        for (int r = 0; r < 4; ++r) cb[f * 4 + r] = o[qs][f][r];
      cb[12] = m[qs]; cb[13] = l[qs];
    }
  }
  __syncthreads();
  if (kq == 0) {
    const int h_ = hb >> 1, b_ = hb & 1;
    #pragma unroll
    for (int qs = 0; qs < 2; ++qs) {
      const float* cb = SLOT(qt, qs, 1);
      float m1 = cb[12], l1 = cb[13];
      float mn = fmaxf(m[qs], m1);
      float s0 = __builtin_amdgcn_exp2f(m[qs] - mn);
      float s1 = __builtin_amdgcn_exp2f(m1 - mn);
      float invl = 1.f / (l[qs] * s0 + l1 * s1);
      const int n = (tA + qs) * 16 + q;
      #pragma unroll
      for (int f = 0; f < 3; ++f) {
        float4 st4 = {(o[qs][f][0] * s0 + cb[f * 4 + 0] * s1) * invl,
                      (o[qs][f][1] * s0 + cb[f * 4 + 1] * s1) * invl,
                      (o[qs][f][2] * s0 + cb[f * 4 + 2] * s1) * invl,
                      (o[qs][f][3] * s0 + cb[f * 4 + 3] * s1) * invl};
        *(float4*)&Ob[(((size_t)(b_ * NN + n)) * 3 + f) * 128 + h_ * 16 + g * 4] = st4;
      }
    }
  }
  #undef SLOT
}

// ---------------------------------------------------------------------------
// out: ev_nonlin(resi @ w_out). Thread = 4 ch x 2 tok; 16 tok / 256 threads.
// ---------------------------------------------------------------------------
__global__ __launch_bounds__(256) void out_kernel(
    const float* __restrict__ Ob, const float* __restrict__ w_out,
    const float* __restrict__ w1, const float* __restrict__ b1,
    const float* __restrict__ w2, const float* __restrict__ b2,
    float* __restrict__ out)
{
  const int t0 = blockIdx.x * TBP;
  const int tid = threadIdx.x;
  const int grp = tid >> 5;
  const int c0  = tid & 31;

  __shared__ float rs[TBP][384];
  __shared__ float norm_s[TBP][128];
  __shared__ float h_s[TBP][64];

  {
    const float4* src = (const float4*)(Ob + (size_t)t0 * 384);
    float4* dst = (float4*)&rs[0][0];
    #pragma unroll
    for (int i = 0; i < 6; ++i) dst[tid + i * 256] = src[tid + i * 256];
  }
  __syncthreads();

  // proj (K=128)
  float p[2][3][4] = {{{0.f}}};
  #pragma unroll 2
  for (int c = 0; c < 128; c += 4) {
    float w4[4][4];
    #pragma unroll
    for (int i = 0; i < 4; ++i)
      #pragma unroll
      for (int k = 0; k < 4; ++k)
        w4[i][k] = w_out[(c + i) * 128 + c0 + k * 32];
    #pragma unroll
    for (int t = 0; t < 2; ++t)
      #pragma unroll
      for (int f = 0; f < 3; ++f) {
        float4 rv = *(const float4*)&rs[grp * 2 + t][f * 128 + c];
        #pragma unroll
        for (int k = 0; k < 4; ++k)
          p[t][f][k] += rv.x * w4[0][k] + rv.y * w4[1][k] + rv.z * w4[2][k] + rv.w * w4[3][k];
      }
  }

  float np[2][4]; int zm = 0;
  #pragma unroll
  for (int t = 0; t < 2; ++t)
    #pragma unroll
    for (int k = 0; k < 4; ++k) {
      float nn = sqrtf(p[t][0][k] * p[t][0][k] + p[t][1][k] * p[t][1][k] + p[t][2][k] * p[t][2][k]);
      if (nn <= EPSV) zm |= 1 << (t * 4 + k);
      np[t][k] = nn + EPSV;
      norm_s[grp * 2 + t][c0 + k * 32] = np[t][k];
    }
  __syncthreads();

  {
    float a[2][2];
    float ba = b1[c0], bb = b1[c0 + 32];
    a[0][0] = ba; a[1][0] = ba; a[0][1] = bb; a[1][1] = bb;
    #pragma unroll 2
    for (int c = 0; c < 128; c += 4) {
      float wa[4], wb[4];
      #pragma unroll
      for (int i = 0; i < 4; ++i) {
        wa[i] = w1[(c + i) * 64 + c0];
        wb[i] = w1[(c + i) * 64 + c0 + 32];
      }
      #pragma unroll
      for (int t = 0; t < 2; ++t) {
        float4 n4 = *(const float4*)&norm_s[grp * 2 + t][c];
        a[t][0] += dot4(n4, wa);
        a[t][1] += dot4(n4, wb);
      }
    }
    #pragma unroll
    for (int t = 0; t < 2; ++t) {
      h_s[grp * 2 + t][c0]      = leaky(a[t][0]);
      h_s[grp * 2 + t][c0 + 32] = leaky(a[t][1]);
    }
  }
  __syncthreads();

  float bn[2][4];
  #pragma unroll
  for (int t = 0; t < 2; ++t)
    #pragma unroll
    for (int k = 0; k < 4; ++k) bn[t][k] = b2[c0 + k * 32] + np[t][k];
  #pragma unroll 2
  for (int c = 0; c < 64; c += 4) {
    float w4[4][4];
    #pragma unroll
    for (int i = 0; i < 4; ++i)
      #pragma unroll
      for (int k = 0; k < 4; ++k)
        w4[i][k] = w2[(c + i) * 128 + c0 + k * 32];
    #pragma unroll
    for (int t = 0; t < 2; ++t) {
      float4 h4 = *(const float4*)&h_s[grp * 2 + t][c];
      #pragma unroll
      for (int k = 0; k < 4; ++k)
        bn[t][k] += h4.x * w4[0][k] + h4.y * w4[1][k] + h4.z * w4[2][k] + h4.w * w4[3][k];
    }
  }

  #pragma unroll
  for (int t = 0; t < 2; ++t) {
    float* od = out + (size_t)(t0 + grp * 2 + t) * 384;
    #pragma unroll
    for (int k = 0; k < 4; ++k) {
      float r = (zm >> (t * 4 + k)) & 1 ? 1.f : bn[t][k] / np[t][k];
      #pragma unroll
      for (int f = 0; f < 3; ++f)
        od[f * 128 + c0 + k * 32] = p[t][f][k] * r;
    }
  }
}

// ---------------------------------------------------------------------------
extern "C" void kernel_launch(void* const* d_in, const int* in_sizes, int n_in,
                              void* d_out, int out_size, void* d_ws, size_t ws_size,
                              hipStream_t stream) {
  const float* qfts   = (const float*)d_in[0];
  const float* kvfts  = (const float*)d_in[1];
  const float* w_q_in = (const float*)d_in[2];
  const float* q_w1   = (const float*)d_in[3];
  const float* q_b1   = (const float*)d_in[4];
  const float* q_w2   = (const float*)d_in[5];
  const float* q_b2   = (const float*)d_in[6];
  const float* w_kv_in= (const float*)d_in[7];
  const float* kv_w1  = (const float*)d_in[8];
  const float* kv_b1  = (const float*)d_in[9];
  const float* kv_w2  = (const float*)d_in[10];
  const float* kv_b2  = (const float*)d_in[11];
  const float* w_q    = (const float*)d_in[12];
  const float* w_k    = (const float*)d_in[13];
  const float* w_v    = (const float*)d_in[14];
  const float* w_out  = (const float*)d_in[15];
  const float* o_w1   = (const float*)d_in[16];
  const float* o_b1   = (const float*)d_in[17];
  const float* o_w2   = (const float*)d_in[18];
  const float* o_b2   = (const float*)d_in[19];

  unsigned short* QW = (unsigned short*)d_ws;
  unsigned short* KW = QW + 3145728;
  unsigned short* VW = KW + 3145728;
  float* Obuf = (float*)(VW + 3145728);

  dim3 pg(BB * NN / TBP, 2);
  pre_kernel<<<pg, 256, 0, stream>>>(qfts, kvfts,
                                     w_q_in, q_w1, q_b1, q_w2, q_b2,
                                     w_kv_in, kv_w1, kv_b1, kv_w2, kv_b2,
                                     w_q, w_k, w_v, QW, KW, VW);
  dim3 ag(32, 16);
  attn_kernel<<<ag, 512, 0, stream>>>(QW, KW, VW, Obuf);
  out_kernel<<<BB * NN / TBP, 256, 0, stream>>>(Obuf, w_out, o_w1, o_b1, o_w2, o_b2, (float*)d_out);
}

// Round 14
// 127.131 us; speedup vs baseline: 1.0254x; 1.0193x over previous
//
#include <hip/hip_runtime.h>
#include <math.h>

#define EPSV 1e-6f
#define NSL  0.2f
#define BB   2
#define NN   2048
#define HH   8
#define TBP  16   // tokens per block in pre/out kernels (256 threads)

typedef short bf16x8 __attribute__((ext_vector_type(8)));
typedef float f32x4  __attribute__((ext_vector_type(4)));

__device__ __forceinline__ unsigned cvt_pk_bf16(float a, float b) {
  unsigned r;
  asm("v_cvt_pk_bf16_f32 %0, %1, %2" : "=v"(r) : "v"(a), "v"(b));
  return r;   // lo16 = bf16(a), hi16 = bf16(b), RNE
}
__device__ __forceinline__ float u2f(unsigned u) {
  union { unsigned u; float f; } v; v.u = u; return v.f;
}
__device__ __forceinline__ float leaky(float a) { return a > 0.f ? a : NSL * a; }

// pack 8 f32 -> hi uint4 and lo uint4 (hi = bf16(v), lo = bf16(v - bf2f(hi)))
__device__ __forceinline__ void pack8(float4 a, float4 b, uint4& hi, uint4& lo) {
  hi.x = cvt_pk_bf16(a.x, a.y);
  hi.y = cvt_pk_bf16(a.z, a.w);
  hi.z = cvt_pk_bf16(b.x, b.y);
  hi.w = cvt_pk_bf16(b.z, b.w);
  float d0 = a.x - u2f(hi.x << 16), d1 = a.y - u2f(hi.x & 0xffff0000u);
  float d2 = a.z - u2f(hi.y << 16), d3 = a.w - u2f(hi.y & 0xffff0000u);
  float d4 = b.x - u2f(hi.z << 16), d5 = b.y - u2f(hi.z & 0xffff0000u);
  float d6 = b.z - u2f(hi.w << 16), d7 = b.w - u2f(hi.w & 0xffff0000u);
  lo.x = cvt_pk_bf16(d0, d1);
  lo.y = cvt_pk_bf16(d2, d3);
  lo.z = cvt_pk_bf16(d4, d5);
  lo.w = cvt_pk_bf16(d6, d7);
}

// Workspace fragment layouts (bf16 hi/lo planes):
// QW/KW per (hb, tile16): [hl 2][768]: c0=[lane64][8] @0, c1=[lane<32][8] @512
// VW per (hb, kc32, f):   [hl 2][512]: [lane64][8]

// ---------------------------------------------------------------------------
// pre: merged q/kv (blockIdx.y: 0=q, 1=kv). 16 tokens / 256 threads (4 waves).
// Thread = 4 CONTIGUOUS channels (c0*4..c0*4+3) x 2 tokens: all weight loads
// are coalesced float4 (4 dwordx4 per c-step vs 16 scalars before).
// Epilogue: LDS stage + wave-cooperative coalesced b128 fragment stores.
// Q scaled by 0.25*log2(e): softmax runs in exp2 domain.
// ---------------------------------------------------------------------------
__global__ __launch_bounds__(256) void pre_kernel(
    const float* __restrict__ qfts, const float* __restrict__ kvfts,
    const float* __restrict__ wq_in, const float* __restrict__ qw1, const float* __restrict__ qb1,
    const float* __restrict__ qw2, const float* __restrict__ qb2,
    const float* __restrict__ wkv_in, const float* __restrict__ kw1, const float* __restrict__ kb1,
    const float* __restrict__ kw2, const float* __restrict__ kb2,
    const float* __restrict__ w_q, const float* __restrict__ w_k, const float* __restrict__ w_v,
    unsigned short* __restrict__ QW, unsigned short* __restrict__ KW, unsigned short* __restrict__ VW)
{
  const bool is_kv = blockIdx.y != 0;
  const float* x_in = is_kv ? kvfts : qfts;
  const float* w_in = is_kv ? wkv_in : wq_in;
  const float* w1   = is_kv ? kw1 : qw1;
  const float* b1   = is_kv ? kb1 : qb1;
  const float* w2   = is_kv ? kw2 : qw2;
  const float* b2   = is_kv ? kb2 : qb2;
  const float* w_p  = is_kv ? w_k : w_q;
  unsigned short* FW = is_kv ? KW : QW;
  const float ln_sc = is_kv ? 1.f : 0.25f * 1.44269504088896f;

  const int t0 = blockIdx.x * TBP;
  const int tid = threadIdx.x;
  const int grp = tid >> 5;            // 0..7: tokens t0+2grp, t0+2grp+1
  const int c0  = tid & 31;            // owns channels c0*4 .. c0*4+3
  const int ch0 = c0 * 4;
  const int n0  = t0 & (NN - 1);
  const int bsel = t0 >> 11;

  // smem layout: xs[12288] | norm[8192] | h[4096] | fs[24576]  = 49152 B
  // stage region (epilogue) overlays h+fs @ offset 20480:
  //   stage_q: idx(tl,f,ch) = tl*388 + f*128 + ch
  //   stage_v: idx(f,tl,ch) = f*2112 + tl*132 + ch
  __shared__ __align__(16) char smem[49152];
  float (*xs)[192]       = (float(*)[192])smem;
  float (*norm_s)[128]   = (float(*)[128])(smem + 12288);
  float (*h_s)[64]       = (float(*)[64])(smem + 20480);
  float (*f_s)[3][128]   = (float(*)[3][128])(smem + 24576);
  float* stage           = (float*)(smem + 20480);

  {
    const float4* src = (const float4*)(x_in + (size_t)t0 * 192);
    float4* dst = (float4*)&xs[0][0];
    dst[tid] = src[tid];
    dst[tid + 256] = src[tid + 256];
    dst[tid + 512] = src[tid + 512];
  }
  __syncthreads();

  // ---- phase 1: input GEMM (K=64) -> p[t][f][j], coalesced f32x4 weights ----
  f32x4 p[2][3];
  #pragma unroll
  for (int t = 0; t < 2; ++t)
    #pragma unroll
    for (int f = 0; f < 3; ++f) p[t][f] = (f32x4){0.f, 0.f, 0.f, 0.f};
  #pragma unroll 2
  for (int c = 0; c < 64; c += 4) {
    f32x4 w4[4];
    #pragma unroll
    for (int i = 0; i < 4; ++i)
      w4[i] = *(const f32x4*)&w_in[(c + i) * 128 + ch0];
    #pragma unroll
    for (int t = 0; t < 2; ++t)
      #pragma unroll
      for (int f = 0; f < 3; ++f) {
        f32x4 xv = *(const f32x4*)&xs[grp * 2 + t][f * 64 + c];
        p[t][f] += xv[0] * w4[0] + xv[1] * w4[1] + xv[2] * w4[2] + xv[3] * w4[3];
      }
  }

  // ---- phase 2: norms (per channel j) ----
  f32x4 np[2]; int zm = 0;
  #pragma unroll
  for (int t = 0; t < 2; ++t) {
    f32x4 ss = p[t][0] * p[t][0] + p[t][1] * p[t][1] + p[t][2] * p[t][2];
    #pragma unroll
    for (int j = 0; j < 4; ++j) {
      float nn = sqrtf(ss[j]);
      if (nn <= EPSV) zm |= 1 << (t * 4 + j);
      np[t][j] = nn + EPSV;
    }
    *(f32x4*)&norm_s[grp * 2 + t][ch0] = np[t];
  }
  __syncthreads();

  // ---- phase 3: MLP1 (128->64), thread owns h channels c0*2, c0*2+1 ----
  {
    float a[2][2];
    {
      float2 bb = *(const float2*)&b1[c0 * 2];
      a[0][0] = bb.x; a[1][0] = bb.x; a[0][1] = bb.y; a[1][1] = bb.y;
    }
    #pragma unroll 2
    for (int c = 0; c < 128; c += 4) {
      float2 wv[4];
      #pragma unroll
      for (int i = 0; i < 4; ++i)
        wv[i] = *(const float2*)&w1[(c + i) * 64 + c0 * 2];
      #pragma unroll
      for (int t = 0; t < 2; ++t) {
        f32x4 n4 = *(const f32x4*)&norm_s[grp * 2 + t][c];
        a[t][0] += n4[0] * wv[0].x + n4[1] * wv[1].x + n4[2] * wv[2].x + n4[3] * wv[3].x;
        a[t][1] += n4[0] * wv[0].y + n4[1] * wv[1].y + n4[2] * wv[2].y + n4[3] * wv[3].y;
      }
    }
    #pragma unroll
    for (int t = 0; t < 2; ++t) {
      float2 hv = {leaky(a[t][0]), leaky(a[t][1])};
      *(float2*)&h_s[grp * 2 + t][c0 * 2] = hv;
    }
  }
  __syncthreads();

  // ---- phase 4: MLP2 (64->128) -> bn[t][j] ----
  f32x4 bn[2];
  {
    f32x4 b2v = *(const f32x4*)&b2[ch0];
    #pragma unroll
    for (int t = 0; t < 2; ++t) bn[t] = b2v + np[t];
  }
  #pragma unroll 2
  for (int c = 0; c < 64; c += 4) {
    f32x4 w4[4];
    #pragma unroll
    for (int i = 0; i < 4; ++i)
      w4[i] = *(const f32x4*)&w2[(c + i) * 128 + ch0];
    #pragma unroll
    for (int t = 0; t < 2; ++t) {
      f32x4 h4 = *(const f32x4*)&h_s[grp * 2 + t][c];
      bn[t] += h4[0] * w4[0] + h4[1] * w4[1] + h4[2] * w4[2] + h4[3] * w4[3];
    }
  }

  // ---- phase 5: ratio; write f to LDS (b128) ----
  #pragma unroll
  for (int t = 0; t < 2; ++t) {
    f32x4 r;
    #pragma unroll
    for (int j = 0; j < 4; ++j)
      r[j] = (zm >> (t * 4 + j)) & 1 ? 1.f : bn[t][j] / np[t][j];
    #pragma unroll
    for (int f = 0; f < 3; ++f)
      *(f32x4*)&f_s[grp * 2 + t][f][ch0] = p[t][f] * r;
  }
  __syncthreads();

  // ---- phase 6: projections (K=128), coalesced f32x4 weights ----
  f32x4 q[2][3], v[2][3];
  #pragma unroll
  for (int t = 0; t < 2; ++t)
    #pragma unroll
    for (int f = 0; f < 3; ++f) {
      q[t][f] = (f32x4){0.f, 0.f, 0.f, 0.f};
      v[t][f] = (f32x4){0.f, 0.f, 0.f, 0.f};
    }
  #pragma unroll 1
  for (int c = 0; c < 128; c += 4) {
    f32x4 wk[4], wv[4];
    #pragma unroll
    for (int i = 0; i < 4; ++i) {
      wk[i] = *(const f32x4*)&w_p[(c + i) * 128 + ch0];
      if (is_kv) wv[i] = *(const f32x4*)&w_v[(c + i) * 128 + ch0];
    }
    #pragma unroll
    for (int t = 0; t < 2; ++t)
      #pragma unroll
      for (int f = 0; f < 3; ++f) {
        f32x4 fv = *(const f32x4*)&f_s[grp * 2 + t][f][c];
        q[t][f] += fv[0] * wk[0] + fv[1] * wk[1] + fv[2] * wk[2] + fv[3] * wk[3];
        if (is_kv)
          v[t][f] += fv[0] * wv[0] + fv[1] * wv[1] + fv[2] * wv[2] + fv[3] * wv[3];
      }
  }
  __syncthreads();   // f_s reads done before stage overwrite

  // ---- phase 7a: EV layernorm (head = c0>>2, width-4 reduce); stage q*inv ----
  #pragma unroll
  for (int t = 0; t < 2; ++t) {
    const int tl = grp * 2 + t;
    f32x4 s4 = q[t][0] * q[t][0] + q[t][1] * q[t][1] + q[t][2] * q[t][2];
    float ss = (s4[0] + s4[1]) + (s4[2] + s4[3]);
    ss += __shfl_xor(ss, 1, 4);
    ss += __shfl_xor(ss, 2, 4);
    float inv = ln_sc / (sqrtf(ss * (1.f / 16.f)) + EPSV);
    #pragma unroll
    for (int f = 0; f < 3; ++f)
      *(f32x4*)&stage[tl * 388 + f * 128 + ch0] = q[t][f] * inv;
  }
  __syncthreads();

  // ---- phase 7b: wave-cooperative coalesced FW stores (2 head-tiles/wave) ----
  {
    const int wv = tid >> 6;
    const int lane = tid & 63;
    const int f0 = lane >> 5;                    // 0,1
    const int ddb = ((lane >> 4) & 1) * 8;       // 0,8
    const int row = lane & 15;
    #pragma unroll
    for (int h2 = 0; h2 < 2; ++h2) {
      const int hh = wv * 2 + h2;
      const int hbw = hh * BB + bsel;
      const size_t basew = (size_t)(hbw * 128 + (n0 >> 4)) * 1536;
      {
        const float* p0 = stage + row * 388 + f0 * 128 + hh * 16 + ddb;
        float4 a = *(const float4*)p0;
        float4 b = *(const float4*)(p0 + 4);
        uint4 hi, lo;
        pack8(a, b, hi, lo);
        *(uint4*)(FW + basew + lane * 8) = hi;
        *(uint4*)(FW + basew + 768 + lane * 8) = lo;
      }
      if (lane < 32) {
        const int ddb1 = ((lane >> 4) & 1) * 8;
        const float* p1 = stage + row * 388 + 2 * 128 + hh * 16 + ddb1;
        float4 a = *(const float4*)p1;
        float4 b = *(const float4*)(p1 + 4);
        uint4 hi, lo;
        pack8(a, b, hi, lo);
        *(uint4*)(FW + basew + 512 + lane * 8) = hi;
        *(uint4*)(FW + basew + 768 + 512 + lane * 8) = lo;
      }
    }
  }

  if (is_kv) {
    __syncthreads();   // FW stage reads done before stage_v overwrite

    // ---- phase 7c: stage v into LDS: idx = f*2112 + tl*132 + ch (b128) ----
    #pragma unroll
    for (int t = 0; t < 2; ++t) {
      const int tl = grp * 2 + t;
      #pragma unroll
      for (int f = 0; f < 3; ++f)
        *(f32x4*)&stage[f * 2112 + tl * 132 + ch0] = v[t][f];
    }
    __syncthreads();

    // ---- phase 7d: wave-cooperative coalesced VW stores ----
    const int wv = tid >> 6;
    const int lane = tid & 63;
    const int s0 = (n0 >> 3) & 3;
    if (lane < 32) {
      const int seg = lane;
      const int tlb = (seg >> 4) * 8;
      const int dd = seg & 15;
      #pragma unroll
      for (int h2 = 0; h2 < 2; ++h2) {
        const int hh = wv * 2 + h2;
        const int hbw = hh * BB + bsel;
        #pragma unroll
        for (int f = 0; f < 3; ++f) {
          const size_t vbase = (size_t)((hbw * 64 + (n0 >> 5)) * 3 + f) * 1024;
          float vals[8];
          #pragma unroll
          for (int j = 0; j < 8; ++j)
            vals[j] = stage[f * 2112 + (tlb + j) * 132 + hh * 16 + dd];
          float4 a = {vals[0], vals[1], vals[2], vals[3]};
          float4 b = {vals[4], vals[5], vals[6], vals[7]};
          uint4 hi, lo;
          pack8(a, b, hi, lo);
          *(uint4*)(VW + vbase + (size_t)(s0 * 16 + seg) * 8) = hi;
          *(uint4*)(VW + vbase + 512 + (size_t)(s0 * 16 + seg) * 8) = lo;
        }
      }
    }
  }
}

// ---------------------------------------------------------------------------
// attention: MFMA flash, 4-way K-split, 32 q per wave (measured-good r7/r10).
// ---------------------------------------------------------------------------
#define THR 10.0f

__global__ __launch_bounds__(512, 4) void attn_kernel(
    const unsigned short* __restrict__ QW, const unsigned short* __restrict__ KW,
    const unsigned short* __restrict__ VW, float* __restrict__ Ob)
{
  const int lane = threadIdx.x & 63;
  const int w = threadIdx.x >> 6;
  const int qt = w & 1;
  const int kq = w >> 1;
  const int hb = blockIdx.y;
  const int tA = blockIdx.x * 4 + qt * 2;
  const int q = lane & 15, g = lane >> 4;

  __shared__ unsigned short plds[8][2][1152];
  float* comb = (float*)plds;

  bf16x8 qh0[2], ql0[2], qh1[2], ql1[2];
  #pragma unroll
  for (int qs = 0; qs < 2; ++qs) {
    const size_t qbase = (size_t)(hb * 128 + tA + qs) * 1536;
    qh0[qs] = *(const bf16x8*)(QW + qbase + lane * 8);
    ql0[qs] = *(const bf16x8*)(QW + qbase + 768 + lane * 8);
    qh1[qs] = (bf16x8){0,0,0,0,0,0,0,0};
    ql1[qs] = (bf16x8){0,0,0,0,0,0,0,0};
    if (lane < 32) {
      qh1[qs] = *(const bf16x8*)(QW + qbase + 512 + lane * 8);
      ql1[qs] = *(const bf16x8*)(QW + qbase + 768 + 512 + lane * 8);
    }
  }

  f32x4 o[2][3];
  #pragma unroll
  for (int qs = 0; qs < 2; ++qs)
    #pragma unroll
    for (int f = 0; f < 3; ++f) o[qs][f] = (f32x4){0.f, 0.f, 0.f, 0.f};
  float m[2] = {-INFINITY, -INFINITY}, l[2] = {0.f, 0.f};

  for (int T = kq * 8; T < kq * 8 + 8; ++T) {
    f32x4 sc[2][4];
    __builtin_amdgcn_s_setprio(1);
    #pragma unroll
    for (int st = 0; st < 4; ++st) {
      const size_t kb = (size_t)(hb * 128 + T * 4 + st) * 1536;
      bf16x8 kh0 = *(const bf16x8*)(KW + kb + lane * 8);
      bf16x8 kl0 = *(const bf16x8*)(KW + kb + 768 + lane * 8);
      bf16x8 kh1 = *(const bf16x8*)(KW + kb + 512 + lane * 8);
      bf16x8 kl1 = *(const bf16x8*)(KW + kb + 768 + 512 + lane * 8);
      #pragma unroll
      for (int qs = 0; qs < 2; ++qs) {
        f32x4 a = {0.f, 0.f, 0.f, 0.f};
        a = __builtin_amdgcn_mfma_f32_16x16x32_bf16(kh0, qh0[qs], a, 0, 0, 0);
        a = __builtin_amdgcn_mfma_f32_16x16x32_bf16(kh0, ql0[qs], a, 0, 0, 0);
        a = __builtin_amdgcn_mfma_f32_16x16x32_bf16(kl0, qh0[qs], a, 0, 0, 0);
        a = __builtin_amdgcn_mfma_f32_16x16x32_bf16(kh1, qh1[qs], a, 0, 0, 0);
        a = __builtin_amdgcn_mfma_f32_16x16x32_bf16(kh1, ql1[qs], a, 0, 0, 0);
        a = __builtin_amdgcn_mfma_f32_16x16x32_bf16(kl1, qh1[qs], a, 0, 0, 0);
        sc[qs][st] = a;
      }
    }
    __builtin_amdgcn_s_setprio(0);

    #pragma unroll
    for (int qs = 0; qs < 2; ++qs) {
      float tm = sc[qs][0][0];
      #pragma unroll
      for (int st = 0; st < 4; ++st)
        #pragma unroll
        for (int r = 0; r < 4; ++r) tm = fmaxf(tm, sc[qs][st][r]);
      tm = fmaxf(tm, __shfl_xor(tm, 16));
      tm = fmaxf(tm, __shfl_xor(tm, 32));
      if (__any(tm > m[qs] + THR)) {
        float mnew = fmaxf(m[qs], tm);
        float scl = __builtin_amdgcn_exp2f(m[qs] - mnew);
        l[qs] *= scl;
        #pragma unroll
        for (int f = 0; f < 3; ++f) {
          o[qs][f][0] *= scl; o[qs][f][1] *= scl;
          o[qs][f][2] *= scl; o[qs][f][3] *= scl;
        }
        m[qs] = mnew;
      }
      float lp = 0.f;
      #pragma unroll
      for (int st = 0; st < 4; ++st) {
        float p0 = __builtin_amdgcn_exp2f(sc[qs][st][0] - m[qs]);
        float p1 = __builtin_amdgcn_exp2f(sc[qs][st][1] - m[qs]);
        float p2 = __builtin_amdgcn_exp2f(sc[qs][st][2] - m[qs]);
        float p3 = __builtin_amdgcn_exp2f(sc[qs][st][3] - m[qs]);
        lp += (p0 + p1) + (p2 + p3);
        uint2 uh = {cvt_pk_bf16(p0, p1), cvt_pk_bf16(p2, p3)};
        *(uint2*)&plds[w][qs][q * 72 + st * 16 + g * 4] = uh;
      }
      lp += __shfl_xor(lp, 16);
      lp += __shfl_xor(lp, 32);
      l[qs] += lp;
    }

    asm volatile("s_waitcnt lgkmcnt(0)" ::: "memory");

    __builtin_amdgcn_s_setprio(1);
    #pragma unroll
    for (int c = 0; c < 2; ++c) {
      const int kc = T * 2 + c;
      bf16x8 pb[2];
      #pragma unroll
      for (int qs = 0; qs < 2; ++qs)
        pb[qs] = *(const bf16x8*)&plds[w][qs][q * 72 + c * 32 + g * 8];
      #pragma unroll
      for (int f = 0; f < 3; ++f) {
        const size_t vb = (size_t)((hb * 64 + kc) * 3 + f) * 1024;
        bf16x8 vh = *(const bf16x8*)(VW + vb + lane * 8);
        bf16x8 vl = *(const bf16x8*)(VW + vb + 512 + lane * 8);
        #pragma unroll
        for (int qs = 0; qs < 2; ++qs) {
          o[qs][f] = __builtin_amdgcn_mfma_f32_16x16x32_bf16(vh, pb[qs], o[qs][f], 0, 0, 0);
          o[qs][f] = __builtin_amdgcn_mfma_f32_16x16x32_bf16(vl, pb[qs], o[qs][f], 0, 0, 0);
        }
      }
    }
    __builtin_amdgcn_s_setprio(0);
  }

  #define SLOT(qt_, qs_, r_) (comb + ((((qt_) * 2 + (qs_)) * 2 + (r_)) * 64 + lane) * 14)
  __syncthreads();
  if (kq & 1) {
    #pragma unroll
    for (int qs = 0; qs < 2; ++qs) {
      float* cb = SLOT(qt, qs, kq >> 1);
      #pragma unroll
      for (int f = 0; f < 3; ++f)
        #pragma unroll
        for (int r = 0; r < 4; ++r) cb[f * 4 + r] = o[qs][f][r];
      cb[12] = m[qs]; cb[13] = l[qs];
    }
  }
  __syncthreads();
  if (!(kq & 1)) {
    #pragma unroll
    for (int qs = 0; qs < 2; ++qs) {
      const float* cb = SLOT(qt, qs, kq >> 1);
      float m1 = cb[12], l1 = cb[13];
      float mn = fmaxf(m[qs], m1);
      float s0 = __builtin_amdgcn_exp2f(m[qs] - mn);
      float s1 = __builtin_amdgcn_exp2f(m1 - mn);
      l[qs] = l[qs] * s0 + l1 * s1;
      #pragma unroll
      for (int f = 0; f < 3; ++f)
        #pragma unroll
        for (int r = 0; r < 4; ++r)
          o[qs][f][r] = o[qs][f][r] * s0 + cb[f * 4 + r] * s1;
      m[qs] = mn;
    }
  }
  __syncthreads();
  if (kq == 2) {
    #pragma unroll
    for (int qs = 0; qs < 2; ++qs) {
      float* cb = SLOT(qt, qs, 1);
      #pragma unroll
      for (int f = 0; f < 3; ++f)
        #pragma unroll
        for (int r = 0; r < 4; ++r) cb[f * 4 + r] = o[qs][f][r];
      cb[12] = m[qs]; cb[13] = l[qs];
    }
  }
  __syncthreads();
  if (kq == 0) {
    const int h_ = hb >> 1, b_ = hb & 1;
    #pragma unroll
    for (int qs = 0; qs < 2; ++qs) {
      const float* cb = SLOT(qt, qs, 1);
      float m1 = cb[12], l1 = cb[13];
      float mn = fmaxf(m[qs], m1);
      float s0 = __builtin_amdgcn_exp2f(m[qs] - mn);
      float s1 = __builtin_amdgcn_exp2f(m1 - mn);
      float invl = 1.f / (l[qs] * s0 + l1 * s1);
      const int n = (tA + qs) * 16 + q;
      #pragma unroll
      for (int f = 0; f < 3; ++f) {
        float4 st4 = {(o[qs][f][0] * s0 + cb[f * 4 + 0] * s1) * invl,
                      (o[qs][f][1] * s0 + cb[f * 4 + 1] * s1) * invl,
                      (o[qs][f][2] * s0 + cb[f * 4 + 2] * s1) * invl,
                      (o[qs][f][3] * s0 + cb[f * 4 + 3] * s1) * invl};
        *(float4*)&Ob[(((size_t)(b_ * NN + n)) * 3 + f) * 128 + h_ * 16 + g * 4] = st4;
      }
    }
  }
  #undef SLOT
}

// ---------------------------------------------------------------------------
// out: ev_nonlin(resi @ w_out). Thread = 4 contiguous ch x 2 tok.
// ---------------------------------------------------------------------------
__global__ __launch_bounds__(256) void out_kernel(
    const float* __restrict__ Ob, const float* __restrict__ w_out,
    const float* __restrict__ w1, const float* __restrict__ b1,
    const float* __restrict__ w2, const float* __restrict__ b2,
    float* __restrict__ out)
{
  const int t0 = blockIdx.x * TBP;
  const int tid = threadIdx.x;
  const int grp = tid >> 5;
  const int c0  = tid & 31;
  const int ch0 = c0 * 4;

  __shared__ float rs[TBP][384];
  __shared__ float norm_s[TBP][128];
  __shared__ float h_s[TBP][64];

  {
    const float4* src = (const float4*)(Ob + (size_t)t0 * 384);
    float4* dst = (float4*)&rs[0][0];
    #pragma unroll
    for (int i = 0; i < 6; ++i) dst[tid + i * 256] = src[tid + i * 256];
  }
  __syncthreads();

  // proj (K=128), coalesced f32x4 weights
  f32x4 p[2][3];
  #pragma unroll
  for (int t = 0; t < 2; ++t)
    #pragma unroll
    for (int f = 0; f < 3; ++f) p[t][f] = (f32x4){0.f, 0.f, 0.f, 0.f};
  #pragma unroll 2
  for (int c = 0; c < 128; c += 4) {
    f32x4 w4[4];
    #pragma unroll
    for (int i = 0; i < 4; ++i)
      w4[i] = *(const f32x4*)&w_out[(c + i) * 128 + ch0];
    #pragma unroll
    for (int t = 0; t < 2; ++t)
      #pragma unroll
      for (int f = 0; f < 3; ++f) {
        f32x4 rv = *(const f32x4*)&rs[grp * 2 + t][f * 128 + c];
        p[t][f] += rv[0] * w4[0] + rv[1] * w4[1] + rv[2] * w4[2] + rv[3] * w4[3];
      }
  }

  f32x4 np[2]; int zm = 0;
  #pragma unroll
  for (int t = 0; t < 2; ++t) {
    f32x4 ss = p[t][0] * p[t][0] + p[t][1] * p[t][1] + p[t][2] * p[t][2];
    #pragma unroll
    for (int j = 0; j < 4; ++j) {
      float nn = sqrtf(ss[j]);
      if (nn <= EPSV) zm |= 1 << (t * 4 + j);
      np[t][j] = nn + EPSV;
    }
    *(f32x4*)&norm_s[grp * 2 + t][ch0] = np[t];
  }
  __syncthreads();

  {
    float a[2][2];
    {
      float2 bb = *(const float2*)&b1[c0 * 2];
      a[0][0] = bb.x; a[1][0] = bb.x; a[0][1] = bb.y; a[1][1] = bb.y;
    }
    #pragma unroll 2
    for (int c = 0; c < 128; c += 4) {
      float2 wv[4];
      #pragma unroll
      for (int i = 0; i < 4; ++i)
        wv[i] = *(const float2*)&w1[(c + i) * 64 + c0 * 2];
      #pragma unroll
      for (int t = 0; t < 2; ++t) {
        f32x4 n4 = *(const f32x4*)&norm_s[grp * 2 + t][c];
        a[t][0] += n4[0] * wv[0].x + n4[1] * wv[1].x + n4[2] * wv[2].x + n4[3] * wv[3].x;
        a[t][1] += n4[0] * wv[0].y + n4[1] * wv[1].y + n4[2] * wv[2].y + n4[3] * wv[3].y;
      }
    }
    #pragma unroll
    for (int t = 0; t < 2; ++t) {
      float2 hv = {leaky(a[t][0]), leaky(a[t][1])};
      *(float2*)&h_s[grp * 2 + t][c0 * 2] = hv;
    }
  }
  __syncthreads();

  f32x4 bn[2];
  {
    f32x4 b2v = *(const f32x4*)&b2[ch0];
    #pragma unroll
    for (int t = 0; t < 2; ++t) bn[t] = b2v + np[t];
  }
  #pragma unroll 2
  for (int c = 0; c < 64; c += 4) {
    f32x4 w4[4];
    #pragma unroll
    for (int i = 0; i < 4; ++i)
      w4[i] = *(const f32x4*)&w2[(c + i) * 128 + ch0];
    #pragma unroll
    for (int t = 0; t < 2; ++t) {
      f32x4 h4 = *(const f32x4*)&h_s[grp * 2 + t][c];
      bn[t] += h4[0] * w4[0] + h4[1] * w4[1] + h4[2] * w4[2] + h4[3] * w4[3];
    }
  }

  #pragma unroll
  for (int t = 0; t < 2; ++t) {
    float* od = out + (size_t)(t0 + grp * 2 + t) * 384;
    f32x4 r;
    #pragma unroll
    for (int j = 0; j < 4; ++j)
      r[j] = (zm >> (t * 4 + j)) & 1 ? 1.f : bn[t][j] / np[t][j];
    #pragma unroll
    for (int f = 0; f < 3; ++f)
      *(f32x4*)&od[f * 128 + ch0] = p[t][f] * r;
  }
}

// ---------------------------------------------------------------------------
extern "C" void kernel_launch(void* const* d_in, const int* in_sizes, int n_in,
                              void* d_out, int out_size, void* d_ws, size_t ws_size,
                              hipStream_t stream) {
  const float* qfts   = (const float*)d_in[0];
  const float* kvfts  = (const float*)d_in[1];
  const float* w_q_in = (const float*)d_in[2];
  const float* q_w1   = (const float*)d_in[3];
  const float* q_b1   = (const float*)d_in[4];
  const float* q_w2   = (const float*)d_in[5];
  const float* q_b2   = (const float*)d_in[6];
  const float* w_kv_in= (const float*)d_in[7];
  const float* kv_w1  = (const float*)d_in[8];
  const float* kv_b1  = (const float*)d_in[9];
  const float* kv_w2  = (const float*)d_in[10];
  const float* kv_b2  = (const float*)d_in[11];
  const float* w_q    = (const float*)d_in[12];
  const float* w_k    = (const float*)d_in[13];
  const float* w_v    = (const float*)d_in[14];
  const float* w_out  = (const float*)d_in[15];
  const float* o_w1   = (const float*)d_in[16];
  const float* o_b1   = (const float*)d_in[17];
  const float* o_w2   = (const float*)d_in[18];
  const float* o_b2   = (const float*)d_in[19];

  unsigned short* QW = (unsigned short*)d_ws;
  unsigned short* KW = QW + 3145728;
  unsigned short* VW = KW + 3145728;
  float* Obuf = (float*)(VW + 3145728);

  dim3 pg(BB * NN / TBP, 2);
  pre_kernel<<<pg, 256, 0, stream>>>(qfts, kvfts,
                                     w_q_in, q_w1, q_b1, q_w2, q_b2,
                                     w_kv_in, kv_w1, kv_b1, kv_w2, kv_b2,
                                     w_q, w_k, w_v, QW, KW, VW);
  dim3 ag(32, 16);
  attn_kernel<<<ag, 512, 0, stream>>>(QW, KW, VW, Obuf);
  out_kernel<<<BB * NN / TBP, 256, 0, stream>>>(Obuf, w_out, o_w1, o_b1, o_w2, o_b2, (float*)d_out);
}

// Round 16
// 92.418 us; speedup vs baseline: 1.4105x; 1.3756x over previous
//
#include <hip/hip_runtime.h>
#include <math.h>

#define EPSV 1e-6f
#define NSL  0.2f
#define BB   2
#define NN   2048
#define HH   8
#define TBP  16

typedef short bf16x8 __attribute__((ext_vector_type(8)));
typedef float f32x4  __attribute__((ext_vector_type(4)));

__device__ __forceinline__ unsigned cvt_pk_bf16(float a, float b) {
  unsigned r;
  asm("v_cvt_pk_bf16_f32 %0, %1, %2" : "=v"(r) : "v"(a), "v"(b));
  return r;   // lo16 = bf16(a), hi16 = bf16(b), RNE
}
__device__ __forceinline__ float u2f(unsigned u) {
  union { unsigned u; float f; } v; v.u = u; return v.f;
}
__device__ __forceinline__ float leaky(float a) { return a > 0.f ? a : NSL * a; }

__device__ __forceinline__ void pack8(float4 a, float4 b, uint4& hi, uint4& lo) {
  hi.x = cvt_pk_bf16(a.x, a.y);
  hi.y = cvt_pk_bf16(a.z, a.w);
  hi.z = cvt_pk_bf16(b.x, b.y);
  hi.w = cvt_pk_bf16(b.z, b.w);
  float d0 = a.x - u2f(hi.x << 16), d1 = a.y - u2f(hi.x & 0xffff0000u);
  float d2 = a.z - u2f(hi.y << 16), d3 = a.w - u2f(hi.y & 0xffff0000u);
  float d4 = b.x - u2f(hi.z << 16), d5 = b.y - u2f(hi.z & 0xffff0000u);
  float d6 = b.z - u2f(hi.w << 16), d7 = b.w - u2f(hi.w & 0xffff0000u);
  lo.x = cvt_pk_bf16(d0, d1);
  lo.y = cvt_pk_bf16(d2, d3);
  lo.z = cvt_pk_bf16(d4, d5);
  lo.w = cvt_pk_bf16(d6, d7);
}

// ---------------------------------------------------------------------------
// wconv: f32 weights -> bf16 hi/lo B-fragment tiles.
// Tile (kk,nj) of w[K][N]: lane l holds k=kk*32+(l>>4)*8+j, ch=nj*16+(l&15).
// WB[b*1024]: hi @ lane*8, lo @ 512+lane*8 (ushorts).
// Tile table: wq_in 0-15, qw1 16-31, qw2 32-47, wkv_in 48-63, kw1 64-79,
//             kw2 80-95, w_q 96-127, w_k 128-159, w_v 160-191.
// ---------------------------------------------------------------------------
__global__ __launch_bounds__(64) void wconv_kernel(
    const float* __restrict__ wq_in, const float* __restrict__ qw1, const float* __restrict__ qw2,
    const float* __restrict__ wkv_in, const float* __restrict__ kw1, const float* __restrict__ kw2,
    const float* __restrict__ w_q, const float* __restrict__ w_k, const float* __restrict__ w_v,
    unsigned short* __restrict__ WB)
{
  const int b = blockIdx.x;
  const int lane = threadIdx.x;
  const float* src; int N, toff;
  if      (b < 16)  { src = wq_in;  N = 128; toff = b; }
  else if (b < 32)  { src = qw1;    N = 64;  toff = b - 16; }
  else if (b < 48)  { src = qw2;    N = 128; toff = b - 32; }
  else if (b < 64)  { src = wkv_in; N = 128; toff = b - 48; }
  else if (b < 80)  { src = kw1;    N = 64;  toff = b - 64; }
  else if (b < 96)  { src = kw2;    N = 128; toff = b - 80; }
  else if (b < 128) { src = w_q;    N = 128; toff = b - 96; }
  else if (b < 160) { src = w_k;    N = 128; toff = b - 128; }
  else              { src = w_v;    N = 128; toff = b - 160; }
  const int NT = N >> 4;
  const int kk = toff / NT, nj = toff % NT;
  const int k0 = kk * 32 + (lane >> 4) * 8;
  const int ch = nj * 16 + (lane & 15);
  float vals[8];
  #pragma unroll
  for (int j = 0; j < 8; ++j) vals[j] = src[(size_t)(k0 + j) * N + ch];
  float4 a = {vals[0], vals[1], vals[2], vals[3]};
  float4 bb = {vals[4], vals[5], vals[6], vals[7]};
  uint4 hi, lo;
  pack8(a, bb, hi, lo);
  unsigned short* dst = WB + (size_t)b * 1024;
  *(uint4*)(dst + lane * 8) = hi;
  *(uint4*)(dst + 512 + lane * 8) = lo;
}

// Workspace fragment layouts (bf16 hi/lo planes):
// QW/KW per (hb, tile16): [hl 2][768]: c0=[lane64][8] @0, c1=[lane<32][8] @512
// VW per (hb, kc32, f):   [hl 2][512]: [lane64][8]

// ---------------------------------------------------------------------------
// pre (MFMA): merged q/kv. 16 tokens / 256 threads (4 waves).
// All GEMMs on matrix pipe (16x16x32 bf16, 3-term hi/lo). Wave wv owns
// N-cols wv*32..+31 (2 nj tiles; MLP1: nj=wv). Norm/ratio in-lane (D-layout);
// EV-layernorm = 16-wide shuffle (head == nj tile). Epilogue as r13.
// Q scaled by 0.25*log2(e): softmax runs in exp2 domain.
// ---------------------------------------------------------------------------
__global__ __launch_bounds__(256) void pre_kernel(
    const float* __restrict__ qfts, const float* __restrict__ kvfts,
    const float* __restrict__ qb1, const float* __restrict__ qb2,
    const float* __restrict__ kb1, const float* __restrict__ kb2,
    const unsigned short* __restrict__ WB,
    unsigned short* __restrict__ QW, unsigned short* __restrict__ KW, unsigned short* __restrict__ VW)
{
  const bool is_kv = blockIdx.y != 0;
  const float* x_in = is_kv ? kvfts : qfts;
  const float* b1 = is_kv ? kb1 : qb1;
  const float* b2 = is_kv ? kb2 : qb2;
  unsigned short* FW = is_kv ? KW : QW;
  const float ln_sc = is_kv ? 1.f : 0.25f * 1.44269504088896f;
  const int tb_in = is_kv ? 48 : 0;
  const int tb_w1 = is_kv ? 64 : 16;
  const int tb_w2 = is_kv ? 80 : 32;
  const int tb_p  = is_kv ? 128 : 96;

  const int t0 = blockIdx.x * TBP;
  const int tid = threadIdx.x;
  const int wv = tid >> 6, lane = tid & 63;
  const int col = lane & 15, kg = lane >> 4;
  const int nj0 = wv * 2;
  const int n0 = t0 & (NN - 1), bsel = t0 >> 11;

  // xs[16][196] | norm[16][132] | h[16][68] | f[48][132]  (padded strides)
  __shared__ __align__(16) char smem[50688];
  float* xs       = (float*)smem;            // 12544 B
  float* norm_lds = (float*)(smem + 12544);  // 8448 B
  float* h_lds    = (float*)(smem + 20992);  // 4352 B
  float* f_lds    = (float*)(smem + 25344);  // 25344 B
  float* stage    = (float*)smem;            // epilogue overlay (25344 B)

  // ---- phase 0: stage x (row stride 196) ----
  {
    const float4* src = (const float4*)(x_in + (size_t)t0 * 192);
    #pragma unroll
    for (int i = 0; i < 3; ++i) {
      int idx = tid + i * 256;          // 768 float4s
      int row = idx / 48, c4 = idx % 48;
      *(float4*)&xs[row * 196 + c4 * 4] = src[idx];
    }
  }
  __syncthreads();

  // ---- phase 1: p = x @ w_in  (M=48(f,tok), K=64, N=128) ----
  f32x4 pacc[3][2];
  #pragma unroll
  for (int mf = 0; mf < 3; ++mf)
    #pragma unroll
    for (int njl = 0; njl < 2; ++njl) pacc[mf][njl] = (f32x4){0.f, 0.f, 0.f, 0.f};
  {
    bf16x8 axh[3][2], axl[3][2];
    #pragma unroll
    for (int mf = 0; mf < 3; ++mf)
      #pragma unroll
      for (int kk = 0; kk < 2; ++kk) {
        const float* pa = &xs[col * 196 + mf * 64 + kk * 32 + kg * 8];
        uint4 hi, lo;
        pack8(*(const float4*)pa, *(const float4*)(pa + 4), hi, lo);
        axh[mf][kk] = *(bf16x8*)&hi; axl[mf][kk] = *(bf16x8*)&lo;
      }
    #pragma unroll
    for (int kk = 0; kk < 2; ++kk)
      #pragma unroll
      for (int njl = 0; njl < 2; ++njl) {
        const unsigned short* wb = WB + (size_t)(tb_in + kk * 8 + nj0 + njl) * 1024 + lane * 8;
        bf16x8 bh = *(const bf16x8*)wb;
        bf16x8 bl = *(const bf16x8*)(wb + 512);
        #pragma unroll
        for (int mf = 0; mf < 3; ++mf) {
          pacc[mf][njl] = __builtin_amdgcn_mfma_f32_16x16x32_bf16(axh[mf][kk], bh, pacc[mf][njl], 0, 0, 0);
          pacc[mf][njl] = __builtin_amdgcn_mfma_f32_16x16x32_bf16(axh[mf][kk], bl, pacc[mf][njl], 0, 0, 0);
          pacc[mf][njl] = __builtin_amdgcn_mfma_f32_16x16x32_bf16(axl[mf][kk], bh, pacc[mf][njl], 0, 0, 0);
        }
      }
  }

  // ---- phase 2: norms (in-lane over the 3 f-tiles) ----
  f32x4 np4[2]; int zm = 0;
  #pragma unroll
  for (int njl = 0; njl < 2; ++njl) {
    f32x4 ss = pacc[0][njl] * pacc[0][njl] + pacc[1][njl] * pacc[1][njl] + pacc[2][njl] * pacc[2][njl];
    #pragma unroll
    for (int i = 0; i < 4; ++i) {
      float nn = sqrtf(ss[i]);
      if (nn <= EPSV) zm |= 1 << (njl * 4 + i);
      np4[njl][i] = nn + EPSV;
      norm_lds[(kg * 4 + i) * 132 + (nj0 + njl) * 16 + col] = np4[njl][i];
    }
  }
  __syncthreads();

  // ---- phase 3: MLP1 h = leaky(norm @ w1 + b1)  (M=16, K=128, N=64; nj=wv) ----
  {
    f32x4 hacc = {0.f, 0.f, 0.f, 0.f};
    #pragma unroll
    for (int kk = 0; kk < 4; ++kk) {
      const float* pa = &norm_lds[col * 132 + kk * 32 + kg * 8];
      uint4 hi, lo;
      pack8(*(const float4*)pa, *(const float4*)(pa + 4), hi, lo);
      bf16x8 ah = *(bf16x8*)&hi, al = *(bf16x8*)&lo;
      const unsigned short* wb = WB + (size_t)(tb_w1 + kk * 4 + wv) * 1024 + lane * 8;
      bf16x8 bh = *(const bf16x8*)wb, bl = *(const bf16x8*)(wb + 512);
      hacc = __builtin_amdgcn_mfma_f32_16x16x32_bf16(ah, bh, hacc, 0, 0, 0);
      hacc = __builtin_amdgcn_mfma_f32_16x16x32_bf16(ah, bl, hacc, 0, 0, 0);
      hacc = __builtin_amdgcn_mfma_f32_16x16x32_bf16(al, bh, hacc, 0, 0, 0);
    }
    float b1v = b1[wv * 16 + col];
    #pragma unroll
    for (int i = 0; i < 4; ++i)
      h_lds[(kg * 4 + i) * 68 + wv * 16 + col] = leaky(hacc[i] + b1v);
  }
  __syncthreads();

  // ---- phase 4+5: MLP2 bn = h @ w2 + b2 + np; ratio; f -> LDS ----
  {
    f32x4 bna[2] = {{0.f, 0.f, 0.f, 0.f}, {0.f, 0.f, 0.f, 0.f}};
    #pragma unroll
    for (int kk = 0; kk < 2; ++kk) {
      const float* pa = &h_lds[col * 68 + kk * 32 + kg * 8];
      uint4 hi, lo;
      pack8(*(const float4*)pa, *(const float4*)(pa + 4), hi, lo);
      bf16x8 ah = *(bf16x8*)&hi, al = *(bf16x8*)&lo;
      #pragma unroll
      for (int njl = 0; njl < 2; ++njl) {
        const unsigned short* wb = WB + (size_t)(tb_w2 + kk * 8 + nj0 + njl) * 1024 + lane * 8;
        bf16x8 bh = *(const bf16x8*)wb, bl = *(const bf16x8*)(wb + 512);
        bna[njl] = __builtin_amdgcn_mfma_f32_16x16x32_bf16(ah, bh, bna[njl], 0, 0, 0);
        bna[njl] = __builtin_amdgcn_mfma_f32_16x16x32_bf16(ah, bl, bna[njl], 0, 0, 0);
        bna[njl] = __builtin_amdgcn_mfma_f32_16x16x32_bf16(al, bh, bna[njl], 0, 0, 0);
      }
    }
    #pragma unroll
    for (int njl = 0; njl < 2; ++njl) {
      float b2v = b2[(nj0 + njl) * 16 + col];
      #pragma unroll
      for (int i = 0; i < 4; ++i) {
        float r = (zm >> (njl * 4 + i)) & 1 ? 1.f
                 : (bna[njl][i] + b2v + np4[njl][i]) / np4[njl][i];
        #pragma unroll
        for (int mf = 0; mf < 3; ++mf)
          f_lds[(mf * 16 + kg * 4 + i) * 132 + (nj0 + njl) * 16 + col] = pacc[mf][njl][i] * r;
      }
    }
  }
  __syncthreads();

  // ---- phase 6: projections q = f @ w_p, v = f @ w_v  (M=48, K=128, N=128) ----
  f32x4 qacc[3][2], vacc[3][2];
  #pragma unroll
  for (int mf = 0; mf < 3; ++mf)
    #pragma unroll
    for (int njl = 0; njl < 2; ++njl) {
      qacc[mf][njl] = (f32x4){0.f, 0.f, 0.f, 0.f};
      vacc[mf][njl] = (f32x4){0.f, 0.f, 0.f, 0.f};
    }
  #pragma unroll
  for (int kk = 0; kk < 4; ++kk) {
    bf16x8 afh[3], afl[3];
    #pragma unroll
    for (int mf = 0; mf < 3; ++mf) {
      const float* pa = &f_lds[(mf * 16 + col) * 132 + kk * 32 + kg * 8];
      uint4 hi, lo;
      pack8(*(const float4*)pa, *(const float4*)(pa + 4), hi, lo);
      afh[mf] = *(bf16x8*)&hi; afl[mf] = *(bf16x8*)&lo;
    }
    #pragma unroll
    for (int njl = 0; njl < 2; ++njl) {
      const unsigned short* wbq = WB + (size_t)(tb_p + kk * 8 + nj0 + njl) * 1024 + lane * 8;
      bf16x8 qbh = *(const bf16x8*)wbq, qbl = *(const bf16x8*)(wbq + 512);
      #pragma unroll
      for (int mf = 0; mf < 3; ++mf) {
        qacc[mf][njl] = __builtin_amdgcn_mfma_f32_16x16x32_bf16(afh[mf], qbh, qacc[mf][njl], 0, 0, 0);
        qacc[mf][njl] = __builtin_amdgcn_mfma_f32_16x16x32_bf16(afh[mf], qbl, qacc[mf][njl], 0, 0, 0);
        qacc[mf][njl] = __builtin_amdgcn_mfma_f32_16x16x32_bf16(afl[mf], qbh, qacc[mf][njl], 0, 0, 0);
      }
      if (is_kv) {
        const unsigned short* wbv = WB + (size_t)(160 + kk * 8 + nj0 + njl) * 1024 + lane * 8;
        bf16x8 vbh = *(const bf16x8*)wbv, vbl = *(const bf16x8*)(wbv + 512);
        #pragma unroll
        for (int mf = 0; mf < 3; ++mf) {
          vacc[mf][njl] = __builtin_amdgcn_mfma_f32_16x16x32_bf16(afh[mf], vbh, vacc[mf][njl], 0, 0, 0);
          vacc[mf][njl] = __builtin_amdgcn_mfma_f32_16x16x32_bf16(afh[mf], vbl, vacc[mf][njl], 0, 0, 0);
          vacc[mf][njl] = __builtin_amdgcn_mfma_f32_16x16x32_bf16(afl[mf], vbh, vacc[mf][njl], 0, 0, 0);
        }
      }
    }
  }
  __syncthreads();   // all f_lds reads done before stage overlay is written

  // ---- phase 7a: EV layernorm (head == nj tile); stage q*inv ----
  #pragma unroll
  for (int njl = 0; njl < 2; ++njl) {
    #pragma unroll
    for (int i = 0; i < 4; ++i) {
      float ss = qacc[0][njl][i] * qacc[0][njl][i]
               + qacc[1][njl][i] * qacc[1][njl][i]
               + qacc[2][njl][i] * qacc[2][njl][i];
      ss += __shfl_xor(ss, 1, 16);
      ss += __shfl_xor(ss, 2, 16);
      ss += __shfl_xor(ss, 4, 16);
      ss += __shfl_xor(ss, 8, 16);
      float inv = ln_sc / (sqrtf(ss * (1.f / 16.f)) + EPSV);
      const int tl = kg * 4 + i;
      #pragma unroll
      for (int mf = 0; mf < 3; ++mf)
        stage[tl * 388 + mf * 128 + (nj0 + njl) * 16 + col] = qacc[mf][njl][i] * inv;
    }
  }
  __syncthreads();

  // ---- phase 7b: wave-cooperative coalesced FW stores (2 head-tiles/wave) ----
  {
    const int f0 = lane >> 5;
    const int ddb = ((lane >> 4) & 1) * 8;
    const int row = lane & 15;
    #pragma unroll
    for (int h2 = 0; h2 < 2; ++h2) {
      const int hh = wv * 2 + h2;
      const int hbw = hh * BB + bsel;
      const size_t basew = (size_t)(hbw * 128 + (n0 >> 4)) * 1536;
      {
        const float* p0 = stage + row * 388 + f0 * 128 + hh * 16 + ddb;
        uint4 hi, lo;
        pack8(*(const float4*)p0, *(const float4*)(p0 + 4), hi, lo);
        *(uint4*)(FW + basew + lane * 8) = hi;
        *(uint4*)(FW + basew + 768 + lane * 8) = lo;
      }
      if (lane < 32) {
        const float* p1 = stage + row * 388 + 2 * 128 + hh * 16 + ddb;
        uint4 hi, lo;
        pack8(*(const float4*)p1, *(const float4*)(p1 + 4), hi, lo);
        *(uint4*)(FW + basew + 512 + lane * 8) = hi;
        *(uint4*)(FW + basew + 768 + 512 + lane * 8) = lo;
      }
    }
  }

  if (is_kv) {
    __syncthreads();
    // ---- phase 7c: stage v: idx = f*2112 + tl*132 + ch ----
    #pragma unroll
    for (int njl = 0; njl < 2; ++njl)
      #pragma unroll
      for (int mf = 0; mf < 3; ++mf)
        #pragma unroll
        for (int i = 0; i < 4; ++i)
          stage[mf * 2112 + (kg * 4 + i) * 132 + (nj0 + njl) * 16 + col] = vacc[mf][njl][i];
    __syncthreads();

    // ---- phase 7d: wave-cooperative coalesced VW stores ----
    const int s0 = (n0 >> 3) & 3;
    if (lane < 32) {
      const int seg = lane;
      const int tlb = (seg >> 4) * 8;
      const int dd = seg & 15;
      #pragma unroll
      for (int h2 = 0; h2 < 2; ++h2) {
        const int hh = wv * 2 + h2;
        const int hbw = hh * BB + bsel;
        #pragma unroll
        for (int f = 0; f < 3; ++f) {
          const size_t vbase = (size_t)((hbw * 64 + (n0 >> 5)) * 3 + f) * 1024;
          float vals[8];
          #pragma unroll
          for (int j = 0; j < 8; ++j)
            vals[j] = stage[f * 2112 + (tlb + j) * 132 + hh * 16 + dd];
          float4 a = {vals[0], vals[1], vals[2], vals[3]};
          float4 b = {vals[4], vals[5], vals[6], vals[7]};
          uint4 hi, lo;
          pack8(a, b, hi, lo);
          *(uint4*)(VW + vbase + (size_t)(s0 * 16 + seg) * 8) = hi;
          *(uint4*)(VW + vbase + 512 + (size_t)(s0 * 16 + seg) * 8) = lo;
        }
      }
    }
  }
}

// ---------------------------------------------------------------------------
// attention: MFMA flash, 4-way K-split, 32 q per wave (measured-good r7/r10).
// ---------------------------------------------------------------------------
#define THR 10.0f

__global__ __launch_bounds__(512, 4) void attn_kernel(
    const unsigned short* __restrict__ QW, const unsigned short* __restrict__ KW,
    const unsigned short* __restrict__ VW, float* __restrict__ Ob)
{
  const int lane = threadIdx.x & 63;
  const int w = threadIdx.x >> 6;
  const int qt = w & 1;
  const int kq = w >> 1;
  const int hb = blockIdx.y;
  const int tA = blockIdx.x * 4 + qt * 2;
  const int q = lane & 15, g = lane >> 4;

  __shared__ unsigned short plds[8][2][1152];
  float* comb = (float*)plds;

  bf16x8 qh0[2], ql0[2], qh1[2], ql1[2];
  #pragma unroll
  for (int qs = 0; qs < 2; ++qs) {
    const size_t qbase = (size_t)(hb * 128 + tA + qs) * 1536;
    qh0[qs] = *(const bf16x8*)(QW + qbase + lane * 8);
    ql0[qs] = *(const bf16x8*)(QW + qbase + 768 + lane * 8);
    qh1[qs] = (bf16x8){0,0,0,0,0,0,0,0};
    ql1[qs] = (bf16x8){0,0,0,0,0,0,0,0};
    if (lane < 32) {
      qh1[qs] = *(const bf16x8*)(QW + qbase + 512 + lane * 8);
      ql1[qs] = *(const bf16x8*)(QW + qbase + 768 + 512 + lane * 8);
    }
  }

  f32x4 o[2][3];
  #pragma unroll
  for (int qs = 0; qs < 2; ++qs)
    #pragma unroll
    for (int f = 0; f < 3; ++f) o[qs][f] = (f32x4){0.f, 0.f, 0.f, 0.f};
  float m[2] = {-INFINITY, -INFINITY}, l[2] = {0.f, 0.f};

  for (int T = kq * 8; T < kq * 8 + 8; ++T) {
    f32x4 sc[2][4];
    __builtin_amdgcn_s_setprio(1);
    #pragma unroll
    for (int st = 0; st < 4; ++st) {
      const size_t kb = (size_t)(hb * 128 + T * 4 + st) * 1536;
      bf16x8 kh0 = *(const bf16x8*)(KW + kb + lane * 8);
      bf16x8 kl0 = *(const bf16x8*)(KW + kb + 768 + lane * 8);
      bf16x8 kh1 = *(const bf16x8*)(KW + kb + 512 + lane * 8);
      bf16x8 kl1 = *(const bf16x8*)(KW + kb + 768 + 512 + lane * 8);
      #pragma unroll
      for (int qs = 0; qs < 2; ++qs) {
        f32x4 a = {0.f, 0.f, 0.f, 0.f};
        a = __builtin_amdgcn_mfma_f32_16x16x32_bf16(kh0, qh0[qs], a, 0, 0, 0);
        a = __builtin_amdgcn_mfma_f32_16x16x32_bf16(kh0, ql0[qs], a, 0, 0, 0);
        a = __builtin_amdgcn_mfma_f32_16x16x32_bf16(kl0, qh0[qs], a, 0, 0, 0);
        a = __builtin_amdgcn_mfma_f32_16x16x32_bf16(kh1, qh1[qs], a, 0, 0, 0);
        a = __builtin_amdgcn_mfma_f32_16x16x32_bf16(kh1, ql1[qs], a, 0, 0, 0);
        a = __builtin_amdgcn_mfma_f32_16x16x32_bf16(kl1, qh1[qs], a, 0, 0, 0);
        sc[qs][st] = a;
      }
    }
    __builtin_amdgcn_s_setprio(0);

    #pragma unroll
    for (int qs = 0; qs < 2; ++qs) {
      float tm = sc[qs][0][0];
      #pragma unroll
      for (int st = 0; st < 4; ++st)
        #pragma unroll
        for (int r = 0; r < 4; ++r) tm = fmaxf(tm, sc[qs][st][r]);
      tm = fmaxf(tm, __shfl_xor(tm, 16));
      tm = fmaxf(tm, __shfl_xor(tm, 32));
      if (__any(tm > m[qs] + THR)) {
        float mnew = fmaxf(m[qs], tm);
        float scl = __builtin_amdgcn_exp2f(m[qs] - mnew);
        l[qs] *= scl;
        #pragma unroll
        for (int f = 0; f < 3; ++f) {
          o[qs][f][0] *= scl; o[qs][f][1] *= scl;
          o[qs][f][2] *= scl; o[qs][f][3] *= scl;
        }
        m[qs] = mnew;
      }
      float lp = 0.f;
      #pragma unroll
      for (int st = 0; st < 4; ++st) {
        float p0 = __builtin_amdgcn_exp2f(sc[qs][st][0] - m[qs]);
        float p1 = __builtin_amdgcn_exp2f(sc[qs][st][1] - m[qs]);
        float p2 = __builtin_amdgcn_exp2f(sc[qs][st][2] - m[qs]);
        float p3 = __builtin_amdgcn_exp2f(sc[qs][st][3] - m[qs]);
        lp += (p0 + p1) + (p2 + p3);
        uint2 uh = {cvt_pk_bf16(p0, p1), cvt_pk_bf16(p2, p3)};
        *(uint2*)&plds[w][qs][q * 72 + st * 16 + g * 4] = uh;
      }
      lp += __shfl_xor(lp, 16);
      lp += __shfl_xor(lp, 32);
      l[qs] += lp;
    }

    asm volatile("s_waitcnt lgkmcnt(0)" ::: "memory");

    __builtin_amdgcn_s_setprio(1);
    #pragma unroll
    for (int c = 0; c < 2; ++c) {
      const int kc = T * 2 + c;
      bf16x8 pb[2];
      #pragma unroll
      for (int qs = 0; qs < 2; ++qs)
        pb[qs] = *(const bf16x8*)&plds[w][qs][q * 72 + c * 32 + g * 8];
      #pragma unroll
      for (int f = 0; f < 3; ++f) {
        const size_t vb = (size_t)((hb * 64 + kc) * 3 + f) * 1024;
        bf16x8 vh = *(const bf16x8*)(VW + vb + lane * 8);
        bf16x8 vl = *(const bf16x8*)(VW + vb + 512 + lane * 8);
        #pragma unroll
        for (int qs = 0; qs < 2; ++qs) {
          o[qs][f] = __builtin_amdgcn_mfma_f32_16x16x32_bf16(vh, pb[qs], o[qs][f], 0, 0, 0);
          o[qs][f] = __builtin_amdgcn_mfma_f32_16x16x32_bf16(vl, pb[qs], o[qs][f], 0, 0, 0);
        }
      }
    }
    __builtin_amdgcn_s_setprio(0);
  }

  #define SLOT(qt_, qs_, r_) (comb + ((((qt_) * 2 + (qs_)) * 2 + (r_)) * 64 + lane) * 14)
  __syncthreads();
  if (kq & 1) {
    #pragma unroll
    for (int qs = 0; qs < 2; ++qs) {
      float* cb = SLOT(qt, qs, kq >> 1);
      #pragma unroll
      for (int f = 0; f < 3; ++f)
        #pragma unroll
        for (int r = 0; r < 4; ++r) cb[f * 4 + r] = o[qs][f][r];
      cb[12] = m[qs]; cb[13] = l[qs];
    }
  }
  __syncthreads();
  if (!(kq & 1)) {
    #pragma unroll
    for (int qs = 0; qs < 2; ++qs) {
      const float* cb = SLOT(qt, qs, kq >> 1);
      float m1 = cb[12], l1 = cb[13];
      float mn = fmaxf(m[qs], m1);
      float s0 = __builtin_amdgcn_exp2f(m[qs] - mn);
      float s1 = __builtin_amdgcn_exp2f(m1 - mn);
      l[qs] = l[qs] * s0 + l1 * s1;
      #pragma unroll
      for (int f = 0; f < 3; ++f)
        #pragma unroll
        for (int r = 0; r < 4; ++r)
          o[qs][f][r] = o[qs][f][r] * s0 + cb[f * 4 + r] * s1;
      m[qs] = mn;
    }
  }
  __syncthreads();
  if (kq == 2) {
    #pragma unroll
    for (int qs = 0; qs < 2; ++qs) {
      float* cb = SLOT(qt, qs, 1);
      #pragma unroll
      for (int f = 0; f < 3; ++f)
        #pragma unroll
        for (int r = 0; r < 4; ++r) cb[f * 4 + r] = o[qs][f][r];
      cb[12] = m[qs]; cb[13] = l[qs];
    }
  }
  __syncthreads();
  if (kq == 0) {
    const int h_ = hb >> 1, b_ = hb & 1;
    #pragma unroll
    for (int qs = 0; qs < 2; ++qs) {
      const float* cb = SLOT(qt, qs, 1);
      float m1 = cb[12], l1 = cb[13];
      float mn = fmaxf(m[qs], m1);
      float s0 = __builtin_amdgcn_exp2f(m[qs] - mn);
      float s1 = __builtin_amdgcn_exp2f(m1 - mn);
      float invl = 1.f / (l[qs] * s0 + l1 * s1);
      const int n = (tA + qs) * 16 + q;
      #pragma unroll
      for (int f = 0; f < 3; ++f) {
        float4 st4 = {(o[qs][f][0] * s0 + cb[f * 4 + 0] * s1) * invl,
                      (o[qs][f][1] * s0 + cb[f * 4 + 1] * s1) * invl,
                      (o[qs][f][2] * s0 + cb[f * 4 + 2] * s1) * invl,
                      (o[qs][f][3] * s0 + cb[f * 4 + 3] * s1) * invl};
        *(float4*)&Ob[(((size_t)(b_ * NN + n)) * 3 + f) * 128 + h_ * 16 + g * 4] = st4;
      }
    }
  }
  #undef SLOT
}

// ---------------------------------------------------------------------------
// out: ev_nonlin(resi @ w_out). Thread = 4 contiguous ch x 2 tok (r14).
// ---------------------------------------------------------------------------
__global__ __launch_bounds__(256) void out_kernel(
    const float* __restrict__ Ob, const float* __restrict__ w_out,
    const float* __restrict__ w1, const float* __restrict__ b1,
    const float* __restrict__ w2, const float* __restrict__ b2,
    float* __restrict__ out)
{
  const int t0 = blockIdx.x * TBP;
  const int tid = threadIdx.x;
  const int grp = tid >> 5;
  const int c0  = tid & 31;
  const int ch0 = c0 * 4;

  __shared__ float rs[TBP][384];
  __shared__ float norm_s[TBP][128];
  __shared__ float h_s[TBP][64];

  {
    const float4* src = (const float4*)(Ob + (size_t)t0 * 384);
    float4* dst = (float4*)&rs[0][0];
    #pragma unroll
    for (int i = 0; i < 6; ++i) dst[tid + i * 256] = src[tid + i * 256];
  }
  __syncthreads();

  f32x4 p[2][3];
  #pragma unroll
  for (int t = 0; t < 2; ++t)
    #pragma unroll
    for (int f = 0; f < 3; ++f) p[t][f] = (f32x4){0.f, 0.f, 0.f, 0.f};
  #pragma unroll 2
  for (int c = 0; c < 128; c += 4) {
    f32x4 w4[4];
    #pragma unroll
    for (int i = 0; i < 4; ++i)
      w4[i] = *(const f32x4*)&w_out[(c + i) * 128 + ch0];
    #pragma unroll
    for (int t = 0; t < 2; ++t)
      #pragma unroll
      for (int f = 0; f < 3; ++f) {
        f32x4 rv = *(const f32x4*)&rs[grp * 2 + t][f * 128 + c];
        p[t][f] += rv[0] * w4[0] + rv[1] * w4[1] + rv[2] * w4[2] + rv[3] * w4[3];
      }
  }

  f32x4 np[2]; int zm = 0;
  #pragma unroll
  for (int t = 0; t < 2; ++t) {
    f32x4 ss = p[t][0] * p[t][0] + p[t][1] * p[t][1] + p[t][2] * p[t][2];
    #pragma unroll
    for (int j = 0; j < 4; ++j) {
      float nn = sqrtf(ss[j]);
      if (nn <= EPSV) zm |= 1 << (t * 4 + j);
      np[t][j] = nn + EPSV;
    }
    *(f32x4*)&norm_s[grp * 2 + t][ch0] = np[t];
  }
  __syncthreads();

  {
    float a[2][2];
    {
      float2 bb = *(const float2*)&b1[c0 * 2];
      a[0][0] = bb.x; a[1][0] = bb.x; a[0][1] = bb.y; a[1][1] = bb.y;
    }
    #pragma unroll 2
    for (int c = 0; c < 128; c += 4) {
      float2 wv[4];
      #pragma unroll
      for (int i = 0; i < 4; ++i)
        wv[i] = *(const float2*)&w1[(c + i) * 64 + c0 * 2];
      #pragma unroll
      for (int t = 0; t < 2; ++t) {
        f32x4 n4 = *(const f32x4*)&norm_s[grp * 2 + t][c];
        a[t][0] += n4[0] * wv[0].x + n4[1] * wv[1].x + n4[2] * wv[2].x + n4[3] * wv[3].x;
        a[t][1] += n4[0] * wv[0].y + n4[1] * wv[1].y + n4[2] * wv[2].y + n4[3] * wv[3].y;
      }
    }
    #pragma unroll
    for (int t = 0; t < 2; ++t) {
      float2 hv = {leaky(a[t][0]), leaky(a[t][1])};
      *(float2*)&h_s[grp * 2 + t][c0 * 2] = hv;
    }
  }
  __syncthreads();

  f32x4 bn[2];
  {
    f32x4 b2v = *(const f32x4*)&b2[ch0];
    #pragma unroll
    for (int t = 0; t < 2; ++t) bn[t] = b2v + np[t];
  }
  #pragma unroll 2
  for (int c = 0; c < 64; c += 4) {
    f32x4 w4[4];
    #pragma unroll
    for (int i = 0; i < 4; ++i)
      w4[i] = *(const f32x4*)&w2[(c + i) * 128 + ch0];
    #pragma unroll
    for (int t = 0; t < 2; ++t) {
      f32x4 h4 = *(const f32x4*)&h_s[grp * 2 + t][c];
      bn[t] += h4[0] * w4[0] + h4[1] * w4[1] + h4[2] * w4[2] + h4[3] * w4[3];
    }
  }

  #pragma unroll
  for (int t = 0; t < 2; ++t) {
    float* od = out + (size_t)(t0 + grp * 2 + t) * 384;
    f32x4 r;
    #pragma unroll
    for (int j = 0; j < 4; ++j)
      r[j] = (zm >> (t * 4 + j)) & 1 ? 1.f : bn[t][j] / np[t][j];
    #pragma unroll
    for (int f = 0; f < 3; ++f)
      *(f32x4*)&od[f * 128 + ch0] = p[t][f] * r;
  }
}

// ---------------------------------------------------------------------------
extern "C" void kernel_launch(void* const* d_in, const int* in_sizes, int n_in,
                              void* d_out, int out_size, void* d_ws, size_t ws_size,
                              hipStream_t stream) {
  const float* qfts   = (const float*)d_in[0];
  const float* kvfts  = (const float*)d_in[1];
  const float* w_q_in = (const float*)d_in[2];
  const float* q_w1   = (const float*)d_in[3];
  const float* q_b1   = (const float*)d_in[4];
  const float* q_w2   = (const float*)d_in[5];
  const float* q_b2   = (const float*)d_in[6];
  const float* w_kv_in= (const float*)d_in[7];
  const float* kv_w1  = (const float*)d_in[8];
  const float* kv_b1  = (const float*)d_in[9];
  const float* kv_w2  = (const float*)d_in[10];
  const float* kv_b2  = (const float*)d_in[11];
  const float* w_q    = (const float*)d_in[12];
  const float* w_k    = (const float*)d_in[13];
  const float* w_v    = (const float*)d_in[14];
  const float* w_out  = (const float*)d_in[15];
  const float* o_w1   = (const float*)d_in[16];
  const float* o_b1   = (const float*)d_in[17];
  const float* o_w2   = (const float*)d_in[18];
  const float* o_b2   = (const float*)d_in[19];

  unsigned short* QW = (unsigned short*)d_ws;
  unsigned short* KW = QW + 3145728;
  unsigned short* VW = KW + 3145728;
  float* Obuf = (float*)(VW + 3145728);                 // 1572864 floats
  unsigned short* WB = (unsigned short*)(Obuf + 1572864); // 192 KiB-tiles, 393216 B

  wconv_kernel<<<192, 64, 0, stream>>>(w_q_in, q_w1, q_w2, w_kv_in, kv_w1, kv_w2,
                                       w_q, w_k, w_v, WB);
  dim3 pg(BB * NN / TBP, 2);
  pre_kernel<<<pg, 256, 0, stream>>>(qfts, kvfts, q_b1, q_b2, kv_b1, kv_b2,
                                     WB, QW, KW, VW);
  dim3 ag(32, 16);
  attn_kernel<<<ag, 512, 0, stream>>>(QW, KW, VW, Obuf);
  out_kernel<<<BB * NN / TBP, 256, 0, stream>>>(Obuf, w_out, o_w1, o_b1, o_w2, o_b2, (float*)d_out);
}

// Round 17
// 81.632 us; speedup vs baseline: 1.5969x; 1.1321x over previous
//
#include <hip/hip_runtime.h>
#include <math.h>

#define EPSV 1e-6f
#define NSL  0.2f
#define BB   2
#define NN   2048
#define HH   8
#define TBP  16

typedef short bf16x8 __attribute__((ext_vector_type(8)));
typedef float f32x4  __attribute__((ext_vector_type(4)));

__device__ __forceinline__ unsigned cvt_pk_bf16(float a, float b) {
  unsigned r;
  asm("v_cvt_pk_bf16_f32 %0, %1, %2" : "=v"(r) : "v"(a), "v"(b));
  return r;   // lo16 = bf16(a), hi16 = bf16(b), RNE
}
__device__ __forceinline__ float u2f(unsigned u) {
  union { unsigned u; float f; } v; v.u = u; return v.f;
}
__device__ __forceinline__ float leaky(float a) { return a > 0.f ? a : NSL * a; }

__device__ __forceinline__ void pack8(float4 a, float4 b, uint4& hi, uint4& lo) {
  hi.x = cvt_pk_bf16(a.x, a.y);
  hi.y = cvt_pk_bf16(a.z, a.w);
  hi.z = cvt_pk_bf16(b.x, b.y);
  hi.w = cvt_pk_bf16(b.z, b.w);
  float d0 = a.x - u2f(hi.x << 16), d1 = a.y - u2f(hi.x & 0xffff0000u);
  float d2 = a.z - u2f(hi.y << 16), d3 = a.w - u2f(hi.y & 0xffff0000u);
  float d4 = b.x - u2f(hi.z << 16), d5 = b.y - u2f(hi.z & 0xffff0000u);
  float d6 = b.z - u2f(hi.w << 16), d7 = b.w - u2f(hi.w & 0xffff0000u);
  lo.x = cvt_pk_bf16(d0, d1);
  lo.y = cvt_pk_bf16(d2, d3);
  lo.z = cvt_pk_bf16(d4, d5);
  lo.w = cvt_pk_bf16(d6, d7);
}

// ---------------------------------------------------------------------------
// wconv: f32 weights -> bf16 hi/lo B-fragment tiles (256 tiles).
// Tile (kk,nj) of w[K][N]: lane l holds k=kk*32+(l>>4)*8+j, ch=nj*16+(l&15).
// Table: wq_in 0-15, qw1 16-31, qw2 32-47, wkv_in 48-63, kw1 64-79,
//        kw2 80-95, w_q 96-127, w_k 128-159, w_v 160-191,
//        w_out 192-223, o_w1 224-239, o_w2 240-255.
// ---------------------------------------------------------------------------
__global__ __launch_bounds__(64) void wconv_kernel(
    const float* __restrict__ wq_in, const float* __restrict__ qw1, const float* __restrict__ qw2,
    const float* __restrict__ wkv_in, const float* __restrict__ kw1, const float* __restrict__ kw2,
    const float* __restrict__ w_q, const float* __restrict__ w_k, const float* __restrict__ w_v,
    const float* __restrict__ w_out, const float* __restrict__ ow1, const float* __restrict__ ow2,
    unsigned short* __restrict__ WB)
{
  const int b = blockIdx.x;
  const int lane = threadIdx.x;
  const float* src; int N, toff;
  if      (b < 16)  { src = wq_in;  N = 128; toff = b; }
  else if (b < 32)  { src = qw1;    N = 64;  toff = b - 16; }
  else if (b < 48)  { src = qw2;    N = 128; toff = b - 32; }
  else if (b < 64)  { src = wkv_in; N = 128; toff = b - 48; }
  else if (b < 80)  { src = kw1;    N = 64;  toff = b - 64; }
  else if (b < 96)  { src = kw2;    N = 128; toff = b - 80; }
  else if (b < 128) { src = w_q;    N = 128; toff = b - 96; }
  else if (b < 160) { src = w_k;    N = 128; toff = b - 128; }
  else if (b < 192) { src = w_v;    N = 128; toff = b - 160; }
  else if (b < 224) { src = w_out;  N = 128; toff = b - 192; }
  else if (b < 240) { src = ow1;    N = 64;  toff = b - 224; }
  else              { src = ow2;    N = 128; toff = b - 240; }
  const int NT = N >> 4;
  const int kk = toff / NT, nj = toff % NT;
  const int k0 = kk * 32 + (lane >> 4) * 8;
  const int ch = nj * 16 + (lane & 15);
  float vals[8];
  #pragma unroll
  for (int j = 0; j < 8; ++j) vals[j] = src[(size_t)(k0 + j) * N + ch];
  float4 a = {vals[0], vals[1], vals[2], vals[3]};
  float4 bb = {vals[4], vals[5], vals[6], vals[7]};
  uint4 hi, lo;
  pack8(a, bb, hi, lo);
  unsigned short* dst = WB + (size_t)b * 1024;
  *(uint4*)(dst + lane * 8) = hi;
  *(uint4*)(dst + 512 + lane * 8) = lo;
}

// Workspace fragment layouts (bf16 hi/lo planes):
// QW/KW per (hb, tile16): [hl 2][768]: c0=[lane64][8] @0, c1=[lane<32][8] @512
// VW per (hb, kc32, f):   [hl 2][512]: [lane64][8]

// ---------------------------------------------------------------------------
// pre (MFMA): merged q/kv. 16 tokens / 256 threads. (r16, measured-good)
// ---------------------------------------------------------------------------
__global__ __launch_bounds__(256) void pre_kernel(
    const float* __restrict__ qfts, const float* __restrict__ kvfts,
    const float* __restrict__ qb1, const float* __restrict__ qb2,
    const float* __restrict__ kb1, const float* __restrict__ kb2,
    const unsigned short* __restrict__ WB,
    unsigned short* __restrict__ QW, unsigned short* __restrict__ KW, unsigned short* __restrict__ VW)
{
  const bool is_kv = blockIdx.y != 0;
  const float* x_in = is_kv ? kvfts : qfts;
  const float* b1 = is_kv ? kb1 : qb1;
  const float* b2 = is_kv ? kb2 : qb2;
  unsigned short* FW = is_kv ? KW : QW;
  const float ln_sc = is_kv ? 1.f : 0.25f * 1.44269504088896f;
  const int tb_in = is_kv ? 48 : 0;
  const int tb_w1 = is_kv ? 64 : 16;
  const int tb_w2 = is_kv ? 80 : 32;
  const int tb_p  = is_kv ? 128 : 96;

  const int t0 = blockIdx.x * TBP;
  const int tid = threadIdx.x;
  const int wv = tid >> 6, lane = tid & 63;
  const int col = lane & 15, kg = lane >> 4;
  const int nj0 = wv * 2;
  const int n0 = t0 & (NN - 1), bsel = t0 >> 11;

  __shared__ __align__(16) char smem[50688];
  float* xs       = (float*)smem;
  float* norm_lds = (float*)(smem + 12544);
  float* h_lds    = (float*)(smem + 20992);
  float* f_lds    = (float*)(smem + 25344);
  float* stage    = (float*)smem;

  {
    const float4* src = (const float4*)(x_in + (size_t)t0 * 192);
    #pragma unroll
    for (int i = 0; i < 3; ++i) {
      int idx = tid + i * 256;
      int row = idx / 48, c4 = idx % 48;
      *(float4*)&xs[row * 196 + c4 * 4] = src[idx];
    }
  }
  __syncthreads();

  f32x4 pacc[3][2];
  #pragma unroll
  for (int mf = 0; mf < 3; ++mf)
    #pragma unroll
    for (int njl = 0; njl < 2; ++njl) pacc[mf][njl] = (f32x4){0.f, 0.f, 0.f, 0.f};
  {
    bf16x8 axh[3][2], axl[3][2];
    #pragma unroll
    for (int mf = 0; mf < 3; ++mf)
      #pragma unroll
      for (int kk = 0; kk < 2; ++kk) {
        const float* pa = &xs[col * 196 + mf * 64 + kk * 32 + kg * 8];
        uint4 hi, lo;
        pack8(*(const float4*)pa, *(const float4*)(pa + 4), hi, lo);
        axh[mf][kk] = *(bf16x8*)&hi; axl[mf][kk] = *(bf16x8*)&lo;
      }
    #pragma unroll
    for (int kk = 0; kk < 2; ++kk)
      #pragma unroll
      for (int njl = 0; njl < 2; ++njl) {
        const unsigned short* wb = WB + (size_t)(tb_in + kk * 8 + nj0 + njl) * 1024 + lane * 8;
        bf16x8 bh = *(const bf16x8*)wb;
        bf16x8 bl = *(const bf16x8*)(wb + 512);
        #pragma unroll
        for (int mf = 0; mf < 3; ++mf) {
          pacc[mf][njl] = __builtin_amdgcn_mfma_f32_16x16x32_bf16(axh[mf][kk], bh, pacc[mf][njl], 0, 0, 0);
          pacc[mf][njl] = __builtin_amdgcn_mfma_f32_16x16x32_bf16(axh[mf][kk], bl, pacc[mf][njl], 0, 0, 0);
          pacc[mf][njl] = __builtin_amdgcn_mfma_f32_16x16x32_bf16(axl[mf][kk], bh, pacc[mf][njl], 0, 0, 0);
        }
      }
  }

  f32x4 np4[2]; int zm = 0;
  #pragma unroll
  for (int njl = 0; njl < 2; ++njl) {
    f32x4 ss = pacc[0][njl] * pacc[0][njl] + pacc[1][njl] * pacc[1][njl] + pacc[2][njl] * pacc[2][njl];
    #pragma unroll
    for (int i = 0; i < 4; ++i) {
      float nn = sqrtf(ss[i]);
      if (nn <= EPSV) zm |= 1 << (njl * 4 + i);
      np4[njl][i] = nn + EPSV;
      norm_lds[(kg * 4 + i) * 132 + (nj0 + njl) * 16 + col] = np4[njl][i];
    }
  }
  __syncthreads();

  {
    f32x4 hacc = {0.f, 0.f, 0.f, 0.f};
    #pragma unroll
    for (int kk = 0; kk < 4; ++kk) {
      const float* pa = &norm_lds[col * 132 + kk * 32 + kg * 8];
      uint4 hi, lo;
      pack8(*(const float4*)pa, *(const float4*)(pa + 4), hi, lo);
      bf16x8 ah = *(bf16x8*)&hi, al = *(bf16x8*)&lo;
      const unsigned short* wb = WB + (size_t)(tb_w1 + kk * 4 + wv) * 1024 + lane * 8;
      bf16x8 bh = *(const bf16x8*)wb, bl = *(const bf16x8*)(wb + 512);
      hacc = __builtin_amdgcn_mfma_f32_16x16x32_bf16(ah, bh, hacc, 0, 0, 0);
      hacc = __builtin_amdgcn_mfma_f32_16x16x32_bf16(ah, bl, hacc, 0, 0, 0);
      hacc = __builtin_amdgcn_mfma_f32_16x16x32_bf16(al, bh, hacc, 0, 0, 0);
    }
    float b1v = b1[wv * 16 + col];
    #pragma unroll
    for (int i = 0; i < 4; ++i)
      h_lds[(kg * 4 + i) * 68 + wv * 16 + col] = leaky(hacc[i] + b1v);
  }
  __syncthreads();

  {
    f32x4 bna[2] = {{0.f, 0.f, 0.f, 0.f}, {0.f, 0.f, 0.f, 0.f}};
    #pragma unroll
    for (int kk = 0; kk < 2; ++kk) {
      const float* pa = &h_lds[col * 68 + kk * 32 + kg * 8];
      uint4 hi, lo;
      pack8(*(const float4*)pa, *(const float4*)(pa + 4), hi, lo);
      bf16x8 ah = *(bf16x8*)&hi, al = *(bf16x8*)&lo;
      #pragma unroll
      for (int njl = 0; njl < 2; ++njl) {
        const unsigned short* wb = WB + (size_t)(tb_w2 + kk * 8 + nj0 + njl) * 1024 + lane * 8;
        bf16x8 bh = *(const bf16x8*)wb, bl = *(const bf16x8*)(wb + 512);
        bna[njl] = __builtin_amdgcn_mfma_f32_16x16x32_bf16(ah, bh, bna[njl], 0, 0, 0);
        bna[njl] = __builtin_amdgcn_mfma_f32_16x16x32_bf16(ah, bl, bna[njl], 0, 0, 0);
        bna[njl] = __builtin_amdgcn_mfma_f32_16x16x32_bf16(al, bh, bna[njl], 0, 0, 0);
      }
    }
    #pragma unroll
    for (int njl = 0; njl < 2; ++njl) {
      float b2v = b2[(nj0 + njl) * 16 + col];
      #pragma unroll
      for (int i = 0; i < 4; ++i) {
        float r = (zm >> (njl * 4 + i)) & 1 ? 1.f
                 : (bna[njl][i] + b2v + np4[njl][i]) / np4[njl][i];
        #pragma unroll
        for (int mf = 0; mf < 3; ++mf)
          f_lds[(mf * 16 + kg * 4 + i) * 132 + (nj0 + njl) * 16 + col] = pacc[mf][njl][i] * r;
      }
    }
  }
  __syncthreads();

  f32x4 qacc[3][2], vacc[3][2];
  #pragma unroll
  for (int mf = 0; mf < 3; ++mf)
    #pragma unroll
    for (int njl = 0; njl < 2; ++njl) {
      qacc[mf][njl] = (f32x4){0.f, 0.f, 0.f, 0.f};
      vacc[mf][njl] = (f32x4){0.f, 0.f, 0.f, 0.f};
    }
  #pragma unroll
  for (int kk = 0; kk < 4; ++kk) {
    bf16x8 afh[3], afl[3];
    #pragma unroll
    for (int mf = 0; mf < 3; ++mf) {
      const float* pa = &f_lds[(mf * 16 + col) * 132 + kk * 32 + kg * 8];
      uint4 hi, lo;
      pack8(*(const float4*)pa, *(const float4*)(pa + 4), hi, lo);
      afh[mf] = *(bf16x8*)&hi; afl[mf] = *(bf16x8*)&lo;
    }
    #pragma unroll
    for (int njl = 0; njl < 2; ++njl) {
      const unsigned short* wbq = WB + (size_t)(tb_p + kk * 8 + nj0 + njl) * 1024 + lane * 8;
      bf16x8 qbh = *(const bf16x8*)wbq, qbl = *(const bf16x8*)(wbq + 512);
      #pragma unroll
      for (int mf = 0; mf < 3; ++mf) {
        qacc[mf][njl] = __builtin_amdgcn_mfma_f32_16x16x32_bf16(afh[mf], qbh, qacc[mf][njl], 0, 0, 0);
        qacc[mf][njl] = __builtin_amdgcn_mfma_f32_16x16x32_bf16(afh[mf], qbl, qacc[mf][njl], 0, 0, 0);
        qacc[mf][njl] = __builtin_amdgcn_mfma_f32_16x16x32_bf16(afl[mf], qbh, qacc[mf][njl], 0, 0, 0);
      }
      if (is_kv) {
        const unsigned short* wbv = WB + (size_t)(160 + kk * 8 + nj0 + njl) * 1024 + lane * 8;
        bf16x8 vbh = *(const bf16x8*)wbv, vbl = *(const bf16x8*)(wbv + 512);
        #pragma unroll
        for (int mf = 0; mf < 3; ++mf) {
          vacc[mf][njl] = __builtin_amdgcn_mfma_f32_16x16x32_bf16(afh[mf], vbh, vacc[mf][njl], 0, 0, 0);
          vacc[mf][njl] = __builtin_amdgcn_mfma_f32_16x16x32_bf16(afh[mf], vbl, vacc[mf][njl], 0, 0, 0);
          vacc[mf][njl] = __builtin_amdgcn_mfma_f32_16x16x32_bf16(afl[mf], vbh, vacc[mf][njl], 0, 0, 0);
        }
      }
    }
  }
  __syncthreads();

  #pragma unroll
  for (int njl = 0; njl < 2; ++njl) {
    #pragma unroll
    for (int i = 0; i < 4; ++i) {
      float ss = qacc[0][njl][i] * qacc[0][njl][i]
               + qacc[1][njl][i] * qacc[1][njl][i]
               + qacc[2][njl][i] * qacc[2][njl][i];
      ss += __shfl_xor(ss, 1, 16);
      ss += __shfl_xor(ss, 2, 16);
      ss += __shfl_xor(ss, 4, 16);
      ss += __shfl_xor(ss, 8, 16);
      float inv = ln_sc / (sqrtf(ss * (1.f / 16.f)) + EPSV);
      const int tl = kg * 4 + i;
      #pragma unroll
      for (int mf = 0; mf < 3; ++mf)
        stage[tl * 388 + mf * 128 + (nj0 + njl) * 16 + col] = qacc[mf][njl][i] * inv;
    }
  }
  __syncthreads();

  {
    const int f0 = lane >> 5;
    const int ddb = ((lane >> 4) & 1) * 8;
    const int row = lane & 15;
    #pragma unroll
    for (int h2 = 0; h2 < 2; ++h2) {
      const int hh = wv * 2 + h2;
      const int hbw = hh * BB + bsel;
      const size_t basew = (size_t)(hbw * 128 + (n0 >> 4)) * 1536;
      {
        const float* p0 = stage + row * 388 + f0 * 128 + hh * 16 + ddb;
        uint4 hi, lo;
        pack8(*(const float4*)p0, *(const float4*)(p0 + 4), hi, lo);
        *(uint4*)(FW + basew + lane * 8) = hi;
        *(uint4*)(FW + basew + 768 + lane * 8) = lo;
      }
      if (lane < 32) {
        const float* p1 = stage + row * 388 + 2 * 128 + hh * 16 + ddb;
        uint4 hi, lo;
        pack8(*(const float4*)p1, *(const float4*)(p1 + 4), hi, lo);
        *(uint4*)(FW + basew + 512 + lane * 8) = hi;
        *(uint4*)(FW + basew + 768 + 512 + lane * 8) = lo;
      }
    }
  }

  if (is_kv) {
    __syncthreads();
    #pragma unroll
    for (int njl = 0; njl < 2; ++njl)
      #pragma unroll
      for (int mf = 0; mf < 3; ++mf)
        #pragma unroll
        for (int i = 0; i < 4; ++i)
          stage[mf * 2112 + (kg * 4 + i) * 132 + (nj0 + njl) * 16 + col] = vacc[mf][njl][i];
    __syncthreads();

    const int s0 = (n0 >> 3) & 3;
    if (lane < 32) {
      const int seg = lane;
      const int tlb = (seg >> 4) * 8;
      const int dd = seg & 15;
      #pragma unroll
      for (int h2 = 0; h2 < 2; ++h2) {
        const int hh = wv * 2 + h2;
        const int hbw = hh * BB + bsel;
        #pragma unroll
        for (int f = 0; f < 3; ++f) {
          const size_t vbase = (size_t)((hbw * 64 + (n0 >> 5)) * 3 + f) * 1024;
          float vals[8];
          #pragma unroll
          for (int j = 0; j < 8; ++j)
            vals[j] = stage[f * 2112 + (tlb + j) * 132 + hh * 16 + dd];
          float4 a = {vals[0], vals[1], vals[2], vals[3]};
          float4 b = {vals[4], vals[5], vals[6], vals[7]};
          uint4 hi, lo;
          pack8(a, b, hi, lo);
          *(uint4*)(VW + vbase + (size_t)(s0 * 16 + seg) * 8) = hi;
          *(uint4*)(VW + vbase + 512 + (size_t)(s0 * 16 + seg) * 8) = lo;
        }
      }
    }
  }
}

// ---------------------------------------------------------------------------
// attention: MFMA flash, 4-way K-split, 32 q per wave. V(c=0) prefetched
// before softmax so its L2 latency hides under the softmax VALU.
// ---------------------------------------------------------------------------
#define THR 10.0f

__global__ __launch_bounds__(512, 4) void attn_kernel(
    const unsigned short* __restrict__ QW, const unsigned short* __restrict__ KW,
    const unsigned short* __restrict__ VW, float* __restrict__ Ob)
{
  const int lane = threadIdx.x & 63;
  const int w = threadIdx.x >> 6;
  const int qt = w & 1;
  const int kq = w >> 1;
  const int hb = blockIdx.y;
  const int tA = blockIdx.x * 4 + qt * 2;
  const int q = lane & 15, g = lane >> 4;

  __shared__ unsigned short plds[8][2][1152];
  float* comb = (float*)plds;

  bf16x8 qh0[2], ql0[2], qh1[2], ql1[2];
  #pragma unroll
  for (int qs = 0; qs < 2; ++qs) {
    const size_t qbase = (size_t)(hb * 128 + tA + qs) * 1536;
    qh0[qs] = *(const bf16x8*)(QW + qbase + lane * 8);
    ql0[qs] = *(const bf16x8*)(QW + qbase + 768 + lane * 8);
    qh1[qs] = (bf16x8){0,0,0,0,0,0,0,0};
    ql1[qs] = (bf16x8){0,0,0,0,0,0,0,0};
    if (lane < 32) {
      qh1[qs] = *(const bf16x8*)(QW + qbase + 512 + lane * 8);
      ql1[qs] = *(const bf16x8*)(QW + qbase + 768 + 512 + lane * 8);
    }
  }

  f32x4 o[2][3];
  #pragma unroll
  for (int qs = 0; qs < 2; ++qs)
    #pragma unroll
    for (int f = 0; f < 3; ++f) o[qs][f] = (f32x4){0.f, 0.f, 0.f, 0.f};
  float m[2] = {-INFINITY, -INFINITY}, l[2] = {0.f, 0.f};

  for (int T = kq * 8; T < kq * 8 + 8; ++T) {
    f32x4 sc[2][4];
    __builtin_amdgcn_s_setprio(1);
    #pragma unroll
    for (int st = 0; st < 4; ++st) {
      const size_t kb = (size_t)(hb * 128 + T * 4 + st) * 1536;
      bf16x8 kh0 = *(const bf16x8*)(KW + kb + lane * 8);
      bf16x8 kl0 = *(const bf16x8*)(KW + kb + 768 + lane * 8);
      bf16x8 kh1 = *(const bf16x8*)(KW + kb + 512 + lane * 8);
      bf16x8 kl1 = *(const bf16x8*)(KW + kb + 768 + 512 + lane * 8);
      #pragma unroll
      for (int qs = 0; qs < 2; ++qs) {
        f32x4 a = {0.f, 0.f, 0.f, 0.f};
        a = __builtin_amdgcn_mfma_f32_16x16x32_bf16(kh0, qh0[qs], a, 0, 0, 0);
        a = __builtin_amdgcn_mfma_f32_16x16x32_bf16(kh0, ql0[qs], a, 0, 0, 0);
        a = __builtin_amdgcn_mfma_f32_16x16x32_bf16(kl0, qh0[qs], a, 0, 0, 0);
        a = __builtin_amdgcn_mfma_f32_16x16x32_bf16(kh1, qh1[qs], a, 0, 0, 0);
        a = __builtin_amdgcn_mfma_f32_16x16x32_bf16(kh1, ql1[qs], a, 0, 0, 0);
        a = __builtin_amdgcn_mfma_f32_16x16x32_bf16(kl1, qh1[qs], a, 0, 0, 0);
        sc[qs][st] = a;
      }
    }
    __builtin_amdgcn_s_setprio(0);

    // ---- prefetch V (c=0) for this T: latency hides under softmax ----
    bf16x8 v0h[3], v0l[3];
    {
      const int kc0 = T * 2;
      #pragma unroll
      for (int f = 0; f < 3; ++f) {
        const size_t vb = (size_t)((hb * 64 + kc0) * 3 + f) * 1024;
        v0h[f] = *(const bf16x8*)(VW + vb + lane * 8);
        v0l[f] = *(const bf16x8*)(VW + vb + 512 + lane * 8);
      }
    }

    #pragma unroll
    for (int qs = 0; qs < 2; ++qs) {
      float tm = sc[qs][0][0];
      #pragma unroll
      for (int st = 0; st < 4; ++st)
        #pragma unroll
        for (int r = 0; r < 4; ++r) tm = fmaxf(tm, sc[qs][st][r]);
      tm = fmaxf(tm, __shfl_xor(tm, 16));
      tm = fmaxf(tm, __shfl_xor(tm, 32));
      if (__any(tm > m[qs] + THR)) {
        float mnew = fmaxf(m[qs], tm);
        float scl = __builtin_amdgcn_exp2f(m[qs] - mnew);
        l[qs] *= scl;
        #pragma unroll
        for (int f = 0; f < 3; ++f) {
          o[qs][f][0] *= scl; o[qs][f][1] *= scl;
          o[qs][f][2] *= scl; o[qs][f][3] *= scl;
        }
        m[qs] = mnew;
      }
      float lp = 0.f;
      #pragma unroll
      for (int st = 0; st < 4; ++st) {
        float p0 = __builtin_amdgcn_exp2f(sc[qs][st][0] - m[qs]);
        float p1 = __builtin_amdgcn_exp2f(sc[qs][st][1] - m[qs]);
        float p2 = __builtin_amdgcn_exp2f(sc[qs][st][2] - m[qs]);
        float p3 = __builtin_amdgcn_exp2f(sc[qs][st][3] - m[qs]);
        lp += (p0 + p1) + (p2 + p3);
        uint2 uh = {cvt_pk_bf16(p0, p1), cvt_pk_bf16(p2, p3)};
        *(uint2*)&plds[w][qs][q * 72 + st * 16 + g * 4] = uh;
      }
      lp += __shfl_xor(lp, 16);
      lp += __shfl_xor(lp, 32);
      l[qs] += lp;
    }

    asm volatile("s_waitcnt lgkmcnt(0)" ::: "memory");

    __builtin_amdgcn_s_setprio(1);
    // ---- PV c=0: uses prefetched V ----
    {
      bf16x8 pb[2];
      #pragma unroll
      for (int qs = 0; qs < 2; ++qs)
        pb[qs] = *(const bf16x8*)&plds[w][qs][q * 72 + g * 8];
      #pragma unroll
      for (int f = 0; f < 3; ++f)
        #pragma unroll
        for (int qs = 0; qs < 2; ++qs) {
          o[qs][f] = __builtin_amdgcn_mfma_f32_16x16x32_bf16(v0h[f], pb[qs], o[qs][f], 0, 0, 0);
          o[qs][f] = __builtin_amdgcn_mfma_f32_16x16x32_bf16(v0l[f], pb[qs], o[qs][f], 0, 0, 0);
        }
    }
    // ---- PV c=1: demand loads (covered by c=0 MFMAs) ----
    {
      const int kc = T * 2 + 1;
      bf16x8 pb[2];
      #pragma unroll
      for (int qs = 0; qs < 2; ++qs)
        pb[qs] = *(const bf16x8*)&plds[w][qs][q * 72 + 32 + g * 8];
      #pragma unroll
      for (int f = 0; f < 3; ++f) {
        const size_t vb = (size_t)((hb * 64 + kc) * 3 + f) * 1024;
        bf16x8 vh = *(const bf16x8*)(VW + vb + lane * 8);
        bf16x8 vl = *(const bf16x8*)(VW + vb + 512 + lane * 8);
        #pragma unroll
        for (int qs = 0; qs < 2; ++qs) {
          o[qs][f] = __builtin_amdgcn_mfma_f32_16x16x32_bf16(vh, pb[qs], o[qs][f], 0, 0, 0);
          o[qs][f] = __builtin_amdgcn_mfma_f32_16x16x32_bf16(vl, pb[qs], o[qs][f], 0, 0, 0);
        }
      }
    }
    __builtin_amdgcn_s_setprio(0);
  }

  #define SLOT(qt_, qs_, r_) (comb + ((((qt_) * 2 + (qs_)) * 2 + (r_)) * 64 + lane) * 14)
  __syncthreads();
  if (kq & 1) {
    #pragma unroll
    for (int qs = 0; qs < 2; ++qs) {
      float* cb = SLOT(qt, qs, kq >> 1);
      #pragma unroll
      for (int f = 0; f < 3; ++f)
        #pragma unroll
        for (int r = 0; r < 4; ++r) cb[f * 4 + r] = o[qs][f][r];
      cb[12] = m[qs]; cb[13] = l[qs];
    }
  }
  __syncthreads();
  if (!(kq & 1)) {
    #pragma unroll
    for (int qs = 0; qs < 2; ++qs) {
      const float* cb = SLOT(qt, qs, kq >> 1);
      float m1 = cb[12], l1 = cb[13];
      float mn = fmaxf(m[qs], m1);
      float s0 = __builtin_amdgcn_exp2f(m[qs] - mn);
      float s1 = __builtin_amdgcn_exp2f(m1 - mn);
      l[qs] = l[qs] * s0 + l1 * s1;
      #pragma unroll
      for (int f = 0; f < 3; ++f)
        #pragma unroll
        for (int r = 0; r < 4; ++r)
          o[qs][f][r] = o[qs][f][r] * s0 + cb[f * 4 + r] * s1;
      m[qs] = mn;
    }
  }
  __syncthreads();
  if (kq == 2) {
    #pragma unroll
    for (int qs = 0; qs < 2; ++qs) {
      float* cb = SLOT(qt, qs, 1);
      #pragma unroll
      for (int f = 0; f < 3; ++f)
        #pragma unroll
        for (int r = 0; r < 4; ++r) cb[f * 4 + r] = o[qs][f][r];
      cb[12] = m[qs]; cb[13] = l[qs];
    }
  }
  __syncthreads();
  if (kq == 0) {
    const int h_ = hb >> 1, b_ = hb & 1;
    #pragma unroll
    for (int qs = 0; qs < 2; ++qs) {
      const float* cb = SLOT(qt, qs, 1);
      float m1 = cb[12], l1 = cb[13];
      float mn = fmaxf(m[qs], m1);
      float s0 = __builtin_amdgcn_exp2f(m[qs] - mn);
      float s1 = __builtin_amdgcn_exp2f(m1 - mn);
      float invl = 1.f / (l[qs] * s0 + l1 * s1);
      const int n = (tA + qs) * 16 + q;
      #pragma unroll
      for (int f = 0; f < 3; ++f) {
        float4 st4 = {(o[qs][f][0] * s0 + cb[f * 4 + 0] * s1) * invl,
                      (o[qs][f][1] * s0 + cb[f * 4 + 1] * s1) * invl,
                      (o[qs][f][2] * s0 + cb[f * 4 + 2] * s1) * invl,
                      (o[qs][f][3] * s0 + cb[f * 4 + 3] * s1) * invl};
        *(float4*)&Ob[(((size_t)(b_ * NN + n)) * 3 + f) * 128 + h_ * 16 + g * 4] = st4;
      }
    }
  }
  #undef SLOT
}

// ---------------------------------------------------------------------------
// out (MFMA): ev_nonlin(resi @ w_out). 16 tokens / 256 threads.
// Same structure as pre phases 1-5; direct f32 store (no layernorm tail).
// ---------------------------------------------------------------------------
__global__ __launch_bounds__(256) void out_kernel(
    const float* __restrict__ Ob,
    const float* __restrict__ b1, const float* __restrict__ b2,
    const unsigned short* __restrict__ WB,
    float* __restrict__ out)
{
  const int t0 = blockIdx.x * TBP;
  const int tid = threadIdx.x;
  const int wv = tid >> 6, lane = tid & 63;
  const int col = lane & 15, kg = lane >> 4;
  const int nj0 = wv * 2;

  // rs[3][16][132] (25344) | norm[16][132] (8448) | h[16][68] (4352) = 38144 B
  __shared__ __align__(16) char smem[38144];
  float* rs_lds   = (float*)smem;
  float* norm_lds = (float*)(smem + 25344);
  float* h_lds    = (float*)(smem + 33792);
  float* stage    = (float*)smem;   // epilogue overlay (needs 24832 B)

  // phase 0: stage resi as [f][tl][132]
  {
    const float4* src = (const float4*)(Ob + (size_t)t0 * 384);
    #pragma unroll
    for (int i = 0; i < 6; ++i) {
      int idx = tid + i * 256;            // 1536 float4s
      int tok = idx / 96, rem = idx % 96;
      int f = rem / 32, c4 = rem % 32;
      *(float4*)&rs_lds[f * 2112 + tok * 132 + c4 * 4] = src[idx];
    }
  }
  __syncthreads();

  // phase 1: p = resi @ w_out  (M=48, K=128, N=128; tiles 192+kk*8+nj)
  f32x4 pacc[3][2];
  #pragma unroll
  for (int mf = 0; mf < 3; ++mf)
    #pragma unroll
    for (int njl = 0; njl < 2; ++njl) pacc[mf][njl] = (f32x4){0.f, 0.f, 0.f, 0.f};
  #pragma unroll
  for (int kk = 0; kk < 4; ++kk) {
    bf16x8 ah[3], al[3];
    #pragma unroll
    for (int mf = 0; mf < 3; ++mf) {
      const float* pa = &rs_lds[mf * 2112 + col * 132 + kk * 32 + kg * 8];
      uint4 hi, lo;
      pack8(*(const float4*)pa, *(const float4*)(pa + 4), hi, lo);
      ah[mf] = *(bf16x8*)&hi; al[mf] = *(bf16x8*)&lo;
    }
    #pragma unroll
    for (int njl = 0; njl < 2; ++njl) {
      const unsigned short* wb = WB + (size_t)(192 + kk * 8 + nj0 + njl) * 1024 + lane * 8;
      bf16x8 bh = *(const bf16x8*)wb, bl = *(const bf16x8*)(wb + 512);
      #pragma unroll
      for (int mf = 0; mf < 3; ++mf) {
        pacc[mf][njl] = __builtin_amdgcn_mfma_f32_16x16x32_bf16(ah[mf], bh, pacc[mf][njl], 0, 0, 0);
        pacc[mf][njl] = __builtin_amdgcn_mfma_f32_16x16x32_bf16(ah[mf], bl, pacc[mf][njl], 0, 0, 0);
        pacc[mf][njl] = __builtin_amdgcn_mfma_f32_16x16x32_bf16(al[mf], bh, pacc[mf][njl], 0, 0, 0);
      }
    }
  }

  // phase 2: norms (in-lane)
  f32x4 np4[2]; int zm = 0;
  #pragma unroll
  for (int njl = 0; njl < 2; ++njl) {
    f32x4 ss = pacc[0][njl] * pacc[0][njl] + pacc[1][njl] * pacc[1][njl] + pacc[2][njl] * pacc[2][njl];
    #pragma unroll
    for (int i = 0; i < 4; ++i) {
      float nn = sqrtf(ss[i]);
      if (nn <= EPSV) zm |= 1 << (njl * 4 + i);
      np4[njl][i] = nn + EPSV;
      norm_lds[(kg * 4 + i) * 132 + (nj0 + njl) * 16 + col] = np4[njl][i];
    }
  }
  __syncthreads();

  // phase 3: MLP1 (K=128, N=64; tiles 224+kk*4+wv)
  {
    f32x4 hacc = {0.f, 0.f, 0.f, 0.f};
    #pragma unroll
    for (int kk = 0; kk < 4; ++kk) {
      const float* pa = &norm_lds[col * 132 + kk * 32 + kg * 8];
      uint4 hi, lo;
      pack8(*(const float4*)pa, *(const float4*)(pa + 4), hi, lo);
      bf16x8 ah = *(bf16x8*)&hi, al = *(bf16x8*)&lo;
      const unsigned short* wb = WB + (size_t)(224 + kk * 4 + wv) * 1024 + lane * 8;
      bf16x8 bh = *(const bf16x8*)wb, bl = *(const bf16x8*)(wb + 512);
      hacc = __builtin_amdgcn_mfma_f32_16x16x32_bf16(ah, bh, hacc, 0, 0, 0);
      hacc = __builtin_amdgcn_mfma_f32_16x16x32_bf16(ah, bl, hacc, 0, 0, 0);
      hacc = __builtin_amdgcn_mfma_f32_16x16x32_bf16(al, bh, hacc, 0, 0, 0);
    }
    float b1v = b1[wv * 16 + col];
    #pragma unroll
    for (int i = 0; i < 4; ++i)
      h_lds[(kg * 4 + i) * 68 + wv * 16 + col] = leaky(hacc[i] + b1v);
  }
  __syncthreads();

  // phase 4+5: MLP2 (K=64, N=128; tiles 240+kk*8+nj) -> ratio -> stage
  {
    f32x4 bna[2] = {{0.f, 0.f, 0.f, 0.f}, {0.f, 0.f, 0.f, 0.f}};
    #pragma unroll
    for (int kk = 0; kk < 2; ++kk) {
      const float* pa = &h_lds[col * 68 + kk * 32 + kg * 8];
      uint4 hi, lo;
      pack8(*(const float4*)pa, *(const float4*)(pa + 4), hi, lo);
      bf16x8 ah = *(bf16x8*)&hi, al = *(bf16x8*)&lo;
      #pragma unroll
      for (int njl = 0; njl < 2; ++njl) {
        const unsigned short* wb = WB + (size_t)(240 + kk * 8 + nj0 + njl) * 1024 + lane * 8;
        bf16x8 bh = *(const bf16x8*)wb, bl = *(const bf16x8*)(wb + 512);
        bna[njl] = __builtin_amdgcn_mfma_f32_16x16x32_bf16(ah, bh, bna[njl], 0, 0, 0);
        bna[njl] = __builtin_amdgcn_mfma_f32_16x16x32_bf16(ah, bl, bna[njl], 0, 0, 0);
        bna[njl] = __builtin_amdgcn_mfma_f32_16x16x32_bf16(al, bh, bna[njl], 0, 0, 0);
      }
    }
    __syncthreads();   // all norm/h reads done; stage overlays rs
    #pragma unroll
    for (int njl = 0; njl < 2; ++njl) {
      float b2v = b2[(nj0 + njl) * 16 + col];
      #pragma unroll
      for (int i = 0; i < 4; ++i) {
        float r = (zm >> (njl * 4 + i)) & 1 ? 1.f
                 : (bna[njl][i] + b2v + np4[njl][i]) / np4[njl][i];
        #pragma unroll
        for (int mf = 0; mf < 3; ++mf)
          stage[(kg * 4 + i) * 388 + mf * 128 + (nj0 + njl) * 16 + col] = pacc[mf][njl][i] * r;
      }
    }
  }
  __syncthreads();

  // phase 7: cooperative coalesced f32 stores
  {
    float4* dst = (float4*)(out + (size_t)t0 * 384);
    #pragma unroll
    for (int i = 0; i < 6; ++i) {
      int idx = tid + i * 256;
      int tok = idx / 96, rem = idx % 96;
      dst[idx] = *(const float4*)&stage[tok * 388 + rem * 4];
    }
  }
}

// ---------------------------------------------------------------------------
extern "C" void kernel_launch(void* const* d_in, const int* in_sizes, int n_in,
                              void* d_out, int out_size, void* d_ws, size_t ws_size,
                              hipStream_t stream) {
  const float* qfts   = (const float*)d_in[0];
  const float* kvfts  = (const float*)d_in[1];
  const float* w_q_in = (const float*)d_in[2];
  const float* q_w1   = (const float*)d_in[3];
  const float* q_b1   = (const float*)d_in[4];
  const float* q_w2   = (const float*)d_in[5];
  const float* q_b2   = (const float*)d_in[6];
  const float* w_kv_in= (const float*)d_in[7];
  const float* kv_w1  = (const float*)d_in[8];
  const float* kv_b1  = (const float*)d_in[9];
  const float* kv_w2  = (const float*)d_in[10];
  const float* kv_b2  = (const float*)d_in[11];
  const float* w_q    = (const float*)d_in[12];
  const float* w_k    = (const float*)d_in[13];
  const float* w_v    = (const float*)d_in[14];
  const float* w_out  = (const float*)d_in[15];
  const float* o_w1   = (const float*)d_in[16];
  const float* o_b1   = (const float*)d_in[17];
  const float* o_w2   = (const float*)d_in[18];
  const float* o_b2   = (const float*)d_in[19];

  unsigned short* QW = (unsigned short*)d_ws;
  unsigned short* KW = QW + 3145728;
  unsigned short* VW = KW + 3145728;
  float* Obuf = (float*)(VW + 3145728);                   // 1572864 floats
  unsigned short* WB = (unsigned short*)(Obuf + 1572864); // 256 tiles, 524288 B

  wconv_kernel<<<256, 64, 0, stream>>>(w_q_in, q_w1, q_w2, w_kv_in, kv_w1, kv_w2,
                                       w_q, w_k, w_v, w_out, o_w1, o_w2, WB);
  dim3 pg(BB * NN / TBP, 2);
  pre_kernel<<<pg, 256, 0, stream>>>(qfts, kvfts, q_b1, q_b2, kv_b1, kv_b2,
                                     WB, QW, KW, VW);
  dim3 ag(32, 16);
  attn_kernel<<<ag, 512, 0, stream>>>(QW, KW, VW, Obuf);
  out_kernel<<<BB * NN / TBP, 256, 0, stream>>>(Obuf, o_b1, o_b2, WB, (float*)d_out);
}

// Round 18
// 80.764 us; speedup vs baseline: 1.6140x; 1.0107x over previous
//
#include <hip/hip_runtime.h>
#include <math.h>

#define EPSV 1e-6f
#define NSL  0.2f
#define BB   2
#define NN   2048
#define HH   8
#define TBP  16

typedef short bf16x8 __attribute__((ext_vector_type(8)));
typedef float f32x4  __attribute__((ext_vector_type(4)));

__device__ __forceinline__ unsigned cvt_pk_bf16(float a, float b) {
  unsigned r;
  asm("v_cvt_pk_bf16_f32 %0, %1, %2" : "=v"(r) : "v"(a), "v"(b));
  return r;   // lo16 = bf16(a), hi16 = bf16(b), RNE
}
__device__ __forceinline__ float u2f(unsigned u) {
  union { unsigned u; float f; } v; v.u = u; return v.f;
}
__device__ __forceinline__ float leaky(float a) { return a > 0.f ? a : NSL * a; }

__device__ __forceinline__ void pack8(float4 a, float4 b, uint4& hi, uint4& lo) {
  hi.x = cvt_pk_bf16(a.x, a.y);
  hi.y = cvt_pk_bf16(a.z, a.w);
  hi.z = cvt_pk_bf16(b.x, b.y);
  hi.w = cvt_pk_bf16(b.z, b.w);
  float d0 = a.x - u2f(hi.x << 16), d1 = a.y - u2f(hi.x & 0xffff0000u);
  float d2 = a.z - u2f(hi.y << 16), d3 = a.w - u2f(hi.y & 0xffff0000u);
  float d4 = b.x - u2f(hi.z << 16), d5 = b.y - u2f(hi.z & 0xffff0000u);
  float d6 = b.z - u2f(hi.w << 16), d7 = b.w - u2f(hi.w & 0xffff0000u);
  lo.x = cvt_pk_bf16(d0, d1);
  lo.y = cvt_pk_bf16(d2, d3);
  lo.z = cvt_pk_bf16(d4, d5);
  lo.w = cvt_pk_bf16(d6, d7);
}

// ---------------------------------------------------------------------------
// wconv: f32 weights -> bf16 hi/lo B-fragment tiles (256 tiles).
// ---------------------------------------------------------------------------
__global__ __launch_bounds__(64) void wconv_kernel(
    const float* __restrict__ wq_in, const float* __restrict__ qw1, const float* __restrict__ qw2,
    const float* __restrict__ wkv_in, const float* __restrict__ kw1, const float* __restrict__ kw2,
    const float* __restrict__ w_q, const float* __restrict__ w_k, const float* __restrict__ w_v,
    const float* __restrict__ w_out, const float* __restrict__ ow1, const float* __restrict__ ow2,
    unsigned short* __restrict__ WB)
{
  const int b = blockIdx.x;
  const int lane = threadIdx.x;
  const float* src; int N, toff;
  if      (b < 16)  { src = wq_in;  N = 128; toff = b; }
  else if (b < 32)  { src = qw1;    N = 64;  toff = b - 16; }
  else if (b < 48)  { src = qw2;    N = 128; toff = b - 32; }
  else if (b < 64)  { src = wkv_in; N = 128; toff = b - 48; }
  else if (b < 80)  { src = kw1;    N = 64;  toff = b - 64; }
  else if (b < 96)  { src = kw2;    N = 128; toff = b - 80; }
  else if (b < 128) { src = w_q;    N = 128; toff = b - 96; }
  else if (b < 160) { src = w_k;    N = 128; toff = b - 128; }
  else if (b < 192) { src = w_v;    N = 128; toff = b - 160; }
  else if (b < 224) { src = w_out;  N = 128; toff = b - 192; }
  else if (b < 240) { src = ow1;    N = 64;  toff = b - 224; }
  else              { src = ow2;    N = 128; toff = b - 240; }
  const int NT = N >> 4;
  const int kk = toff / NT, nj = toff % NT;
  const int k0 = kk * 32 + (lane >> 4) * 8;
  const int ch = nj * 16 + (lane & 15);
  float vals[8];
  #pragma unroll
  for (int j = 0; j < 8; ++j) vals[j] = src[(size_t)(k0 + j) * N + ch];
  float4 a = {vals[0], vals[1], vals[2], vals[3]};
  float4 bb = {vals[4], vals[5], vals[6], vals[7]};
  uint4 hi, lo;
  pack8(a, bb, hi, lo);
  unsigned short* dst = WB + (size_t)b * 1024;
  *(uint4*)(dst + lane * 8) = hi;
  *(uint4*)(dst + 512 + lane * 8) = lo;
}

// Workspace fragment layouts (bf16 hi/lo planes):
// QW/KW per (hb, tile16): [hl 2][768]: c0=[lane64][8] @0, c1=[lane<32][8] @512
// VW per (hb, kc32, f):   [hl 2][512]: [lane64][8]

// ---------------------------------------------------------------------------
// pre (MFMA): merged q/kv. 16 tokens / 256 threads. (r16, measured-good)
// ---------------------------------------------------------------------------
__global__ __launch_bounds__(256) void pre_kernel(
    const float* __restrict__ qfts, const float* __restrict__ kvfts,
    const float* __restrict__ qb1, const float* __restrict__ qb2,
    const float* __restrict__ kb1, const float* __restrict__ kb2,
    const unsigned short* __restrict__ WB,
    unsigned short* __restrict__ QW, unsigned short* __restrict__ KW, unsigned short* __restrict__ VW)
{
  const bool is_kv = blockIdx.y != 0;
  const float* x_in = is_kv ? kvfts : qfts;
  const float* b1 = is_kv ? kb1 : qb1;
  const float* b2 = is_kv ? kb2 : qb2;
  unsigned short* FW = is_kv ? KW : QW;
  const float ln_sc = is_kv ? 1.f : 0.25f * 1.44269504088896f;
  const int tb_in = is_kv ? 48 : 0;
  const int tb_w1 = is_kv ? 64 : 16;
  const int tb_w2 = is_kv ? 80 : 32;
  const int tb_p  = is_kv ? 128 : 96;

  const int t0 = blockIdx.x * TBP;
  const int tid = threadIdx.x;
  const int wv = tid >> 6, lane = tid & 63;
  const int col = lane & 15, kg = lane >> 4;
  const int nj0 = wv * 2;
  const int n0 = t0 & (NN - 1), bsel = t0 >> 11;

  __shared__ __align__(16) char smem[50688];
  float* xs       = (float*)smem;
  float* norm_lds = (float*)(smem + 12544);
  float* h_lds    = (float*)(smem + 20992);
  float* f_lds    = (float*)(smem + 25344);
  float* stage    = (float*)smem;

  {
    const float4* src = (const float4*)(x_in + (size_t)t0 * 192);
    #pragma unroll
    for (int i = 0; i < 3; ++i) {
      int idx = tid + i * 256;
      int row = idx / 48, c4 = idx % 48;
      *(float4*)&xs[row * 196 + c4 * 4] = src[idx];
    }
  }
  __syncthreads();

  f32x4 pacc[3][2];
  #pragma unroll
  for (int mf = 0; mf < 3; ++mf)
    #pragma unroll
    for (int njl = 0; njl < 2; ++njl) pacc[mf][njl] = (f32x4){0.f, 0.f, 0.f, 0.f};
  {
    bf16x8 axh[3][2], axl[3][2];
    #pragma unroll
    for (int mf = 0; mf < 3; ++mf)
      #pragma unroll
      for (int kk = 0; kk < 2; ++kk) {
        const float* pa = &xs[col * 196 + mf * 64 + kk * 32 + kg * 8];
        uint4 hi, lo;
        pack8(*(const float4*)pa, *(const float4*)(pa + 4), hi, lo);
        axh[mf][kk] = *(bf16x8*)&hi; axl[mf][kk] = *(bf16x8*)&lo;
      }
    #pragma unroll
    for (int kk = 0; kk < 2; ++kk)
      #pragma unroll
      for (int njl = 0; njl < 2; ++njl) {
        const unsigned short* wb = WB + (size_t)(tb_in + kk * 8 + nj0 + njl) * 1024 + lane * 8;
        bf16x8 bh = *(const bf16x8*)wb;
        bf16x8 bl = *(const bf16x8*)(wb + 512);
        #pragma unroll
        for (int mf = 0; mf < 3; ++mf) {
          pacc[mf][njl] = __builtin_amdgcn_mfma_f32_16x16x32_bf16(axh[mf][kk], bh, pacc[mf][njl], 0, 0, 0);
          pacc[mf][njl] = __builtin_amdgcn_mfma_f32_16x16x32_bf16(axh[mf][kk], bl, pacc[mf][njl], 0, 0, 0);
          pacc[mf][njl] = __builtin_amdgcn_mfma_f32_16x16x32_bf16(axl[mf][kk], bh, pacc[mf][njl], 0, 0, 0);
        }
      }
  }

  f32x4 np4[2]; int zm = 0;
  #pragma unroll
  for (int njl = 0; njl < 2; ++njl) {
    f32x4 ss = pacc[0][njl] * pacc[0][njl] + pacc[1][njl] * pacc[1][njl] + pacc[2][njl] * pacc[2][njl];
    #pragma unroll
    for (int i = 0; i < 4; ++i) {
      float nn = sqrtf(ss[i]);
      if (nn <= EPSV) zm |= 1 << (njl * 4 + i);
      np4[njl][i] = nn + EPSV;
      norm_lds[(kg * 4 + i) * 132 + (nj0 + njl) * 16 + col] = np4[njl][i];
    }
  }
  __syncthreads();

  {
    f32x4 hacc = {0.f, 0.f, 0.f, 0.f};
    #pragma unroll
    for (int kk = 0; kk < 4; ++kk) {
      const float* pa = &norm_lds[col * 132 + kk * 32 + kg * 8];
      uint4 hi, lo;
      pack8(*(const float4*)pa, *(const float4*)(pa + 4), hi, lo);
      bf16x8 ah = *(bf16x8*)&hi, al = *(bf16x8*)&lo;
      const unsigned short* wb = WB + (size_t)(tb_w1 + kk * 4 + wv) * 1024 + lane * 8;
      bf16x8 bh = *(const bf16x8*)wb, bl = *(const bf16x8*)(wb + 512);
      hacc = __builtin_amdgcn_mfma_f32_16x16x32_bf16(ah, bh, hacc, 0, 0, 0);
      hacc = __builtin_amdgcn_mfma_f32_16x16x32_bf16(ah, bl, hacc, 0, 0, 0);
      hacc = __builtin_amdgcn_mfma_f32_16x16x32_bf16(al, bh, hacc, 0, 0, 0);
    }
    float b1v = b1[wv * 16 + col];
    #pragma unroll
    for (int i = 0; i < 4; ++i)
      h_lds[(kg * 4 + i) * 68 + wv * 16 + col] = leaky(hacc[i] + b1v);
  }
  __syncthreads();

  {
    f32x4 bna[2] = {{0.f, 0.f, 0.f, 0.f}, {0.f, 0.f, 0.f, 0.f}};
    #pragma unroll
    for (int kk = 0; kk < 2; ++kk) {
      const float* pa = &h_lds[col * 68 + kk * 32 + kg * 8];
      uint4 hi, lo;
      pack8(*(const float4*)pa, *(const float4*)(pa + 4), hi, lo);
      bf16x8 ah = *(bf16x8*)&hi, al = *(bf16x8*)&lo;
      #pragma unroll
      for (int njl = 0; njl < 2; ++njl) {
        const unsigned short* wb = WB + (size_t)(tb_w2 + kk * 8 + nj0 + njl) * 1024 + lane * 8;
        bf16x8 bh = *(const bf16x8*)wb, bl = *(const bf16x8*)(wb + 512);
        bna[njl] = __builtin_amdgcn_mfma_f32_16x16x32_bf16(ah, bh, bna[njl], 0, 0, 0);
        bna[njl] = __builtin_amdgcn_mfma_f32_16x16x32_bf16(ah, bl, bna[njl], 0, 0, 0);
        bna[njl] = __builtin_amdgcn_mfma_f32_16x16x32_bf16(al, bh, bna[njl], 0, 0, 0);
      }
    }
    #pragma unroll
    for (int njl = 0; njl < 2; ++njl) {
      float b2v = b2[(nj0 + njl) * 16 + col];
      #pragma unroll
      for (int i = 0; i < 4; ++i) {
        float r = (zm >> (njl * 4 + i)) & 1 ? 1.f
                 : (bna[njl][i] + b2v + np4[njl][i]) / np4[njl][i];
        #pragma unroll
        for (int mf = 0; mf < 3; ++mf)
          f_lds[(mf * 16 + kg * 4 + i) * 132 + (nj0 + njl) * 16 + col] = pacc[mf][njl][i] * r;
      }
    }
  }
  __syncthreads();

  f32x4 qacc[3][2], vacc[3][2];
  #pragma unroll
  for (int mf = 0; mf < 3; ++mf)
    #pragma unroll
    for (int njl = 0; njl < 2; ++njl) {
      qacc[mf][njl] = (f32x4){0.f, 0.f, 0.f, 0.f};
      vacc[mf][njl] = (f32x4){0.f, 0.f, 0.f, 0.f};
    }
  #pragma unroll
  for (int kk = 0; kk < 4; ++kk) {
    bf16x8 afh[3], afl[3];
    #pragma unroll
    for (int mf = 0; mf < 3; ++mf) {
      const float* pa = &f_lds[(mf * 16 + col) * 132 + kk * 32 + kg * 8];
      uint4 hi, lo;
      pack8(*(const float4*)pa, *(const float4*)(pa + 4), hi, lo);
      afh[mf] = *(bf16x8*)&hi; afl[mf] = *(bf16x8*)&lo;
    }
    #pragma unroll
    for (int njl = 0; njl < 2; ++njl) {
      const unsigned short* wbq = WB + (size_t)(tb_p + kk * 8 + nj0 + njl) * 1024 + lane * 8;
      bf16x8 qbh = *(const bf16x8*)wbq, qbl = *(const bf16x8*)(wbq + 512);
      #pragma unroll
      for (int mf = 0; mf < 3; ++mf) {
        qacc[mf][njl] = __builtin_amdgcn_mfma_f32_16x16x32_bf16(afh[mf], qbh, qacc[mf][njl], 0, 0, 0);
        qacc[mf][njl] = __builtin_amdgcn_mfma_f32_16x16x32_bf16(afh[mf], qbl, qacc[mf][njl], 0, 0, 0);
        qacc[mf][njl] = __builtin_amdgcn_mfma_f32_16x16x32_bf16(afl[mf], qbh, qacc[mf][njl], 0, 0, 0);
      }
      if (is_kv) {
        const unsigned short* wbv = WB + (size_t)(160 + kk * 8 + nj0 + njl) * 1024 + lane * 8;
        bf16x8 vbh = *(const bf16x8*)wbv, vbl = *(const bf16x8*)(wbv + 512);
        #pragma unroll
        for (int mf = 0; mf < 3; ++mf) {
          vacc[mf][njl] = __builtin_amdgcn_mfma_f32_16x16x32_bf16(afh[mf], vbh, vacc[mf][njl], 0, 0, 0);
          vacc[mf][njl] = __builtin_amdgcn_mfma_f32_16x16x32_bf16(afh[mf], vbl, vacc[mf][njl], 0, 0, 0);
          vacc[mf][njl] = __builtin_amdgcn_mfma_f32_16x16x32_bf16(afl[mf], vbh, vacc[mf][njl], 0, 0, 0);
        }
      }
    }
  }
  __syncthreads();

  #pragma unroll
  for (int njl = 0; njl < 2; ++njl) {
    #pragma unroll
    for (int i = 0; i < 4; ++i) {
      float ss = qacc[0][njl][i] * qacc[0][njl][i]
               + qacc[1][njl][i] * qacc[1][njl][i]
               + qacc[2][njl][i] * qacc[2][njl][i];
      ss += __shfl_xor(ss, 1, 16);
      ss += __shfl_xor(ss, 2, 16);
      ss += __shfl_xor(ss, 4, 16);
      ss += __shfl_xor(ss, 8, 16);
      float inv = ln_sc / (sqrtf(ss * (1.f / 16.f)) + EPSV);
      const int tl = kg * 4 + i;
      #pragma unroll
      for (int mf = 0; mf < 3; ++mf)
        stage[tl * 388 + mf * 128 + (nj0 + njl) * 16 + col] = qacc[mf][njl][i] * inv;
    }
  }
  __syncthreads();

  {
    const int f0 = lane >> 5;
    const int ddb = ((lane >> 4) & 1) * 8;
    const int row = lane & 15;
    #pragma unroll
    for (int h2 = 0; h2 < 2; ++h2) {
      const int hh = wv * 2 + h2;
      const int hbw = hh * BB + bsel;
      const size_t basew = (size_t)(hbw * 128 + (n0 >> 4)) * 1536;
      {
        const float* p0 = stage + row * 388 + f0 * 128 + hh * 16 + ddb;
        uint4 hi, lo;
        pack8(*(const float4*)p0, *(const float4*)(p0 + 4), hi, lo);
        *(uint4*)(FW + basew + lane * 8) = hi;
        *(uint4*)(FW + basew + 768 + lane * 8) = lo;
      }
      if (lane < 32) {
        const float* p1 = stage + row * 388 + 2 * 128 + hh * 16 + ddb;
        uint4 hi, lo;
        pack8(*(const float4*)p1, *(const float4*)(p1 + 4), hi, lo);
        *(uint4*)(FW + basew + 512 + lane * 8) = hi;
        *(uint4*)(FW + basew + 768 + 512 + lane * 8) = lo;
      }
    }
  }

  if (is_kv) {
    __syncthreads();
    #pragma unroll
    for (int njl = 0; njl < 2; ++njl)
      #pragma unroll
      for (int mf = 0; mf < 3; ++mf)
        #pragma unroll
        for (int i = 0; i < 4; ++i)
          stage[mf * 2112 + (kg * 4 + i) * 132 + (nj0 + njl) * 16 + col] = vacc[mf][njl][i];
    __syncthreads();

    const int s0 = (n0 >> 3) & 3;
    if (lane < 32) {
      const int seg = lane;
      const int tlb = (seg >> 4) * 8;
      const int dd = seg & 15;
      #pragma unroll
      for (int h2 = 0; h2 < 2; ++h2) {
        const int hh = wv * 2 + h2;
        const int hbw = hh * BB + bsel;
        #pragma unroll
        for (int f = 0; f < 3; ++f) {
          const size_t vbase = (size_t)((hbw * 64 + (n0 >> 5)) * 3 + f) * 1024;
          float vals[8];
          #pragma unroll
          for (int j = 0; j < 8; ++j)
            vals[j] = stage[f * 2112 + (tlb + j) * 132 + hh * 16 + dd];
          float4 a = {vals[0], vals[1], vals[2], vals[3]};
          float4 b = {vals[4], vals[5], vals[6], vals[7]};
          uint4 hi, lo;
          pack8(a, b, hi, lo);
          *(uint4*)(VW + vbase + (size_t)(s0 * 16 + seg) * 8) = hi;
          *(uint4*)(VW + vbase + 512 + (size_t)(s0 * 16 + seg) * 8) = lo;
        }
      }
    }
  }
}

// ---------------------------------------------------------------------------
// attention: MFMA flash, 4-way K-split, 32 q per wave. XCD-aware block
// swizzle: all blocks of an hb-pair land on one XCD (K/V set 1.6MB < 4MB L2).
// ---------------------------------------------------------------------------
#define THR 10.0f

__global__ __launch_bounds__(512, 4) void attn_kernel(
    const unsigned short* __restrict__ QW, const unsigned short* __restrict__ KW,
    const unsigned short* __restrict__ VW, float* __restrict__ Ob)
{
  const int lane = threadIdx.x & 63;
  const int w = threadIdx.x >> 6;
  const int qt = w & 1;
  const int kq = w >> 1;
  // XCD swizzle: fid round-robins over 8 XCDs; give XCD k hb {2k, 2k+1}.
  const int fid = blockIdx.y * 32 + blockIdx.x;
  const int xcd = fid & 7, slot = fid >> 3;
  const int hb = xcd * 2 + (slot >> 5);
  const int bx = slot & 31;
  const int tA = bx * 4 + qt * 2;
  const int q = lane & 15, g = lane >> 4;

  __shared__ unsigned short plds[8][2][1152];
  float* comb = (float*)plds;

  bf16x8 qh0[2], ql0[2], qh1[2], ql1[2];
  #pragma unroll
  for (int qs = 0; qs < 2; ++qs) {
    const size_t qbase = (size_t)(hb * 128 + tA + qs) * 1536;
    qh0[qs] = *(const bf16x8*)(QW + qbase + lane * 8);
    ql0[qs] = *(const bf16x8*)(QW + qbase + 768 + lane * 8);
    qh1[qs] = (bf16x8){0,0,0,0,0,0,0,0};
    ql1[qs] = (bf16x8){0,0,0,0,0,0,0,0};
    if (lane < 32) {
      qh1[qs] = *(const bf16x8*)(QW + qbase + 512 + lane * 8);
      ql1[qs] = *(const bf16x8*)(QW + qbase + 768 + 512 + lane * 8);
    }
  }

  f32x4 o[2][3];
  #pragma unroll
  for (int qs = 0; qs < 2; ++qs)
    #pragma unroll
    for (int f = 0; f < 3; ++f) o[qs][f] = (f32x4){0.f, 0.f, 0.f, 0.f};
  float m[2] = {-INFINITY, -INFINITY}, l[2] = {0.f, 0.f};

  for (int T = kq * 8; T < kq * 8 + 8; ++T) {
    f32x4 sc[2][4];
    __builtin_amdgcn_s_setprio(1);
    #pragma unroll
    for (int st = 0; st < 4; ++st) {
      const size_t kb = (size_t)(hb * 128 + T * 4 + st) * 1536;
      bf16x8 kh0 = *(const bf16x8*)(KW + kb + lane * 8);
      bf16x8 kl0 = *(const bf16x8*)(KW + kb + 768 + lane * 8);
      bf16x8 kh1 = *(const bf16x8*)(KW + kb + 512 + lane * 8);
      bf16x8 kl1 = *(const bf16x8*)(KW + kb + 768 + 512 + lane * 8);
      #pragma unroll
      for (int qs = 0; qs < 2; ++qs) {
        f32x4 a = {0.f, 0.f, 0.f, 0.f};
        a = __builtin_amdgcn_mfma_f32_16x16x32_bf16(kh0, qh0[qs], a, 0, 0, 0);
        a = __builtin_amdgcn_mfma_f32_16x16x32_bf16(kh0, ql0[qs], a, 0, 0, 0);
        a = __builtin_amdgcn_mfma_f32_16x16x32_bf16(kl0, qh0[qs], a, 0, 0, 0);
        a = __builtin_amdgcn_mfma_f32_16x16x32_bf16(kh1, qh1[qs], a, 0, 0, 0);
        a = __builtin_amdgcn_mfma_f32_16x16x32_bf16(kh1, ql1[qs], a, 0, 0, 0);
        a = __builtin_amdgcn_mfma_f32_16x16x32_bf16(kl1, qh1[qs], a, 0, 0, 0);
        sc[qs][st] = a;
      }
    }
    __builtin_amdgcn_s_setprio(0);

    #pragma unroll
    for (int qs = 0; qs < 2; ++qs) {
      float tm = sc[qs][0][0];
      #pragma unroll
      for (int st = 0; st < 4; ++st)
        #pragma unroll
        for (int r = 0; r < 4; ++r) tm = fmaxf(tm, sc[qs][st][r]);
      tm = fmaxf(tm, __shfl_xor(tm, 16));
      tm = fmaxf(tm, __shfl_xor(tm, 32));
      if (__any(tm > m[qs] + THR)) {
        float mnew = fmaxf(m[qs], tm);
        float scl = __builtin_amdgcn_exp2f(m[qs] - mnew);
        l[qs] *= scl;
        #pragma unroll
        for (int f = 0; f < 3; ++f) {
          o[qs][f][0] *= scl; o[qs][f][1] *= scl;
          o[qs][f][2] *= scl; o[qs][f][3] *= scl;
        }
        m[qs] = mnew;
      }
      float lp = 0.f;
      #pragma unroll
      for (int st = 0; st < 4; ++st) {
        float p0 = __builtin_amdgcn_exp2f(sc[qs][st][0] - m[qs]);
        float p1 = __builtin_amdgcn_exp2f(sc[qs][st][1] - m[qs]);
        float p2 = __builtin_amdgcn_exp2f(sc[qs][st][2] - m[qs]);
        float p3 = __builtin_amdgcn_exp2f(sc[qs][st][3] - m[qs]);
        lp += (p0 + p1) + (p2 + p3);
        uint2 uh = {cvt_pk_bf16(p0, p1), cvt_pk_bf16(p2, p3)};
        *(uint2*)&plds[w][qs][q * 72 + st * 16 + g * 4] = uh;
      }
      lp += __shfl_xor(lp, 16);
      lp += __shfl_xor(lp, 32);
      l[qs] += lp;
    }

    asm volatile("s_waitcnt lgkmcnt(0)" ::: "memory");

    __builtin_amdgcn_s_setprio(1);
    #pragma unroll
    for (int c = 0; c < 2; ++c) {
      const int kc = T * 2 + c;
      bf16x8 pb[2];
      #pragma unroll
      for (int qs = 0; qs < 2; ++qs)
        pb[qs] = *(const bf16x8*)&plds[w][qs][q * 72 + c * 32 + g * 8];
      #pragma unroll
      for (int f = 0; f < 3; ++f) {
        const size_t vb = (size_t)((hb * 64 + kc) * 3 + f) * 1024;
        bf16x8 vh = *(const bf16x8*)(VW + vb + lane * 8);
        bf16x8 vl = *(const bf16x8*)(VW + vb + 512 + lane * 8);
        #pragma unroll
        for (int qs = 0; qs < 2; ++qs) {
          o[qs][f] = __builtin_amdgcn_mfma_f32_16x16x32_bf16(vh, pb[qs], o[qs][f], 0, 0, 0);
          o[qs][f] = __builtin_amdgcn_mfma_f32_16x16x32_bf16(vl, pb[qs], o[qs][f], 0, 0, 0);
        }
      }
    }
    __builtin_amdgcn_s_setprio(0);
  }

  #define SLOT(qt_, qs_, r_) (comb + ((((qt_) * 2 + (qs_)) * 2 + (r_)) * 64 + lane) * 14)
  __syncthreads();
  if (kq & 1) {
    #pragma unroll
    for (int qs = 0; qs < 2; ++qs) {
      float* cb = SLOT(qt, qs, kq >> 1);
      #pragma unroll
      for (int f = 0; f < 3; ++f)
        #pragma unroll
        for (int r = 0; r < 4; ++r) cb[f * 4 + r] = o[qs][f][r];
      cb[12] = m[qs]; cb[13] = l[qs];
    }
  }
  __syncthreads();
  if (!(kq & 1)) {
    #pragma unroll
    for (int qs = 0; qs < 2; ++qs) {
      const float* cb = SLOT(qt, qs, kq >> 1);
      float m1 = cb[12], l1 = cb[13];
      float mn = fmaxf(m[qs], m1);
      float s0 = __builtin_amdgcn_exp2f(m[qs] - mn);
      float s1 = __builtin_amdgcn_exp2f(m1 - mn);
      l[qs] = l[qs] * s0 + l1 * s1;
      #pragma unroll
      for (int f = 0; f < 3; ++f)
        #pragma unroll
        for (int r = 0; r < 4; ++r)
          o[qs][f][r] = o[qs][f][r] * s0 + cb[f * 4 + r] * s1;
      m[qs] = mn;
    }
  }
  __syncthreads();
  if (kq == 2) {
    #pragma unroll
    for (int qs = 0; qs < 2; ++qs) {
      float* cb = SLOT(qt, qs, 1);
      #pragma unroll
      for (int f = 0; f < 3; ++f)
        #pragma unroll
        for (int r = 0; r < 4; ++r) cb[f * 4 + r] = o[qs][f][r];
      cb[12] = m[qs]; cb[13] = l[qs];
    }
  }
  __syncthreads();
  if (kq == 0) {
    const int h_ = hb >> 1, b_ = hb & 1;
    #pragma unroll
    for (int qs = 0; qs < 2; ++qs) {
      const float* cb = SLOT(qt, qs, 1);
      float m1 = cb[12], l1 = cb[13];
      float mn = fmaxf(m[qs], m1);
      float s0 = __builtin_amdgcn_exp2f(m[qs] - mn);
      float s1 = __builtin_amdgcn_exp2f(m1 - mn);
      float invl = 1.f / (l[qs] * s0 + l1 * s1);
      const int n = (tA + qs) * 16 + q;
      #pragma unroll
      for (int f = 0; f < 3; ++f) {
        float4 st4 = {(o[qs][f][0] * s0 + cb[f * 4 + 0] * s1) * invl,
                      (o[qs][f][1] * s0 + cb[f * 4 + 1] * s1) * invl,
                      (o[qs][f][2] * s0 + cb[f * 4 + 2] * s1) * invl,
                      (o[qs][f][3] * s0 + cb[f * 4 + 3] * s1) * invl};
        *(float4*)&Ob[(((size_t)(b_ * NN + n)) * 3 + f) * 128 + h_ * 16 + g * 4] = st4;
      }
    }
  }
  #undef SLOT
}

// ---------------------------------------------------------------------------
// out (MFMA): ev_nonlin(resi @ w_out). 16 tokens / 256 threads. (r17 good)
// ---------------------------------------------------------------------------
__global__ __launch_bounds__(256) void out_kernel(
    const float* __restrict__ Ob,
    const float* __restrict__ b1, const float* __restrict__ b2,
    const unsigned short* __restrict__ WB,
    float* __restrict__ out)
{
  const int t0 = blockIdx.x * TBP;
  const int tid = threadIdx.x;
  const int wv = tid >> 6, lane = tid & 63;
  const int col = lane & 15, kg = lane >> 4;
  const int nj0 = wv * 2;

  __shared__ __align__(16) char smem[38144];
  float* rs_lds   = (float*)smem;
  float* norm_lds = (float*)(smem + 25344);
  float* h_lds    = (float*)(smem + 33792);
  float* stage    = (float*)smem;

  {
    const float4* src = (const float4*)(Ob + (size_t)t0 * 384);
    #pragma unroll
    for (int i = 0; i < 6; ++i) {
      int idx = tid + i * 256;
      int tok = idx / 96, rem = idx % 96;
      int f = rem / 32, c4 = rem % 32;
      *(float4*)&rs_lds[f * 2112 + tok * 132 + c4 * 4] = src[idx];
    }
  }
  __syncthreads();

  f32x4 pacc[3][2];
  #pragma unroll
  for (int mf = 0; mf < 3; ++mf)
    #pragma unroll
    for (int njl = 0; njl < 2; ++njl) pacc[mf][njl] = (f32x4){0.f, 0.f, 0.f, 0.f};
  #pragma unroll
  for (int kk = 0; kk < 4; ++kk) {
    bf16x8 ah[3], al[3];
    #pragma unroll
    for (int mf = 0; mf < 3; ++mf) {
      const float* pa = &rs_lds[mf * 2112 + col * 132 + kk * 32 + kg * 8];
      uint4 hi, lo;
      pack8(*(const float4*)pa, *(const float4*)(pa + 4), hi, lo);
      ah[mf] = *(bf16x8*)&hi; al[mf] = *(bf16x8*)&lo;
    }
    #pragma unroll
    for (int njl = 0; njl < 2; ++njl) {
      const unsigned short* wb = WB + (size_t)(192 + kk * 8 + nj0 + njl) * 1024 + lane * 8;
      bf16x8 bh = *(const bf16x8*)wb, bl = *(const bf16x8*)(wb + 512);
      #pragma unroll
      for (int mf = 0; mf < 3; ++mf) {
        pacc[mf][njl] = __builtin_amdgcn_mfma_f32_16x16x32_bf16(ah[mf], bh, pacc[mf][njl], 0, 0, 0);
        pacc[mf][njl] = __builtin_amdgcn_mfma_f32_16x16x32_bf16(ah[mf], bl, pacc[mf][njl], 0, 0, 0);
        pacc[mf][njl] = __builtin_amdgcn_mfma_f32_16x16x32_bf16(al[mf], bh, pacc[mf][njl], 0, 0, 0);
      }
    }
  }

  f32x4 np4[2]; int zm = 0;
  #pragma unroll
  for (int njl = 0; njl < 2; ++njl) {
    f32x4 ss = pacc[0][njl] * pacc[0][njl] + pacc[1][njl] * pacc[1][njl] + pacc[2][njl] * pacc[2][njl];
    #pragma unroll
    for (int i = 0; i < 4; ++i) {
      float nn = sqrtf(ss[i]);
      if (nn <= EPSV) zm |= 1 << (njl * 4 + i);
      np4[njl][i] = nn + EPSV;
      norm_lds[(kg * 4 + i) * 132 + (nj0 + njl) * 16 + col] = np4[njl][i];
    }
  }
  __syncthreads();

  {
    f32x4 hacc = {0.f, 0.f, 0.f, 0.f};
    #pragma unroll
    for (int kk = 0; kk < 4; ++kk) {
      const float* pa = &norm_lds[col * 132 + kk * 32 + kg * 8];
      uint4 hi, lo;
      pack8(*(const float4*)pa, *(const float4*)(pa + 4), hi, lo);
      bf16x8 ah = *(bf16x8*)&hi, al = *(bf16x8*)&lo;
      const unsigned short* wb = WB + (size_t)(224 + kk * 4 + wv) * 1024 + lane * 8;
      bf16x8 bh = *(const bf16x8*)wb, bl = *(const bf16x8*)(wb + 512);
      hacc = __builtin_amdgcn_mfma_f32_16x16x32_bf16(ah, bh, hacc, 0, 0, 0);
      hacc = __builtin_amdgcn_mfma_f32_16x16x32_bf16(ah, bl, hacc, 0, 0, 0);
      hacc = __builtin_amdgcn_mfma_f32_16x16x32_bf16(al, bh, hacc, 0, 0, 0);
    }
    float b1v = b1[wv * 16 + col];
    #pragma unroll
    for (int i = 0; i < 4; ++i)
      h_lds[(kg * 4 + i) * 68 + wv * 16 + col] = leaky(hacc[i] + b1v);
  }
  __syncthreads();

  {
    f32x4 bna[2] = {{0.f, 0.f, 0.f, 0.f}, {0.f, 0.f, 0.f, 0.f}};
    #pragma unroll
    for (int kk = 0; kk < 2; ++kk) {
      const float* pa = &h_lds[col * 68 + kk * 32 + kg * 8];
      uint4 hi, lo;
      pack8(*(const float4*)pa, *(const float4*)(pa + 4), hi, lo);
      bf16x8 ah = *(bf16x8*)&hi, al = *(bf16x8*)&lo;
      #pragma unroll
      for (int njl = 0; njl < 2; ++njl) {
        const unsigned short* wb = WB + (size_t)(240 + kk * 8 + nj0 + njl) * 1024 + lane * 8;
        bf16x8 bh = *(const bf16x8*)wb, bl = *(const bf16x8*)(wb + 512);
        bna[njl] = __builtin_amdgcn_mfma_f32_16x16x32_bf16(ah, bh, bna[njl], 0, 0, 0);
        bna[njl] = __builtin_amdgcn_mfma_f32_16x16x32_bf16(ah, bl, bna[njl], 0, 0, 0);
        bna[njl] = __builtin_amdgcn_mfma_f32_16x16x32_bf16(al, bh, bna[njl], 0, 0, 0);
      }
    }
    __syncthreads();
    #pragma unroll
    for (int njl = 0; njl < 2; ++njl) {
      float b2v = b2[(nj0 + njl) * 16 + col];
      #pragma unroll
      for (int i = 0; i < 4; ++i) {
        float r = (zm >> (njl * 4 + i)) & 1 ? 1.f
                 : (bna[njl][i] + b2v + np4[njl][i]) / np4[njl][i];
        #pragma unroll
        for (int mf = 0; mf < 3; ++mf)
          stage[(kg * 4 + i) * 388 + mf * 128 + (nj0 + njl) * 16 + col] = pacc[mf][njl][i] * r;
      }
    }
  }
  __syncthreads();

  {
    float4* dst = (float4*)(out + (size_t)t0 * 384);
    #pragma unroll
    for (int i = 0; i < 6; ++i) {
      int idx = tid + i * 256;
      int tok = idx / 96, rem = idx % 96;
      dst[idx] = *(const float4*)&stage[tok * 388 + rem * 4];
    }
  }
}

// ---------------------------------------------------------------------------
extern "C" void kernel_launch(void* const* d_in, const int* in_sizes, int n_in,
                              void* d_out, int out_size, void* d_ws, size_t ws_size,
                              hipStream_t stream) {
  const float* qfts   = (const float*)d_in[0];
  const float* kvfts  = (const float*)d_in[1];
  const float* w_q_in = (const float*)d_in[2];
  const float* q_w1   = (const float*)d_in[3];
  const float* q_b1   = (const float*)d_in[4];
  const float* q_w2   = (const float*)d_in[5];
  const float* q_b2   = (const float*)d_in[6];
  const float* w_kv_in= (const float*)d_in[7];
  const float* kv_w1  = (const float*)d_in[8];
  const float* kv_b1  = (const float*)d_in[9];
  const float* kv_w2  = (const float*)d_in[10];
  const float* kv_b2  = (const float*)d_in[11];
  const float* w_q    = (const float*)d_in[12];
  const float* w_k    = (const float*)d_in[13];
  const float* w_v    = (const float*)d_in[14];
  const float* w_out  = (const float*)d_in[15];
  const float* o_w1   = (const float*)d_in[16];
  const float* o_b1   = (const float*)d_in[17];
  const float* o_w2   = (const float*)d_in[18];
  const float* o_b2   = (const float*)d_in[19];

  unsigned short* QW = (unsigned short*)d_ws;
  unsigned short* KW = QW + 3145728;
  unsigned short* VW = KW + 3145728;
  float* Obuf = (float*)(VW + 3145728);
  unsigned short* WB = (unsigned short*)(Obuf + 1572864);

  wconv_kernel<<<256, 64, 0, stream>>>(w_q_in, q_w1, q_w2, w_kv_in, kv_w1, kv_w2,
                                       w_q, w_k, w_v, w_out, o_w1, o_w2, WB);
  dim3 pg(BB * NN / TBP, 2);
  pre_kernel<<<pg, 256, 0, stream>>>(qfts, kvfts, q_b1, q_b2, kv_b1, kv_b2,
                                     WB, QW, KW, VW);
  dim3 ag(32, 16);
  attn_kernel<<<ag, 512, 0, stream>>>(QW, KW, VW, Obuf);
  out_kernel<<<BB * NN / TBP, 256, 0, stream>>>(Obuf, o_b1, o_b2, WB, (float*)d_out);
}